// Round 1
// baseline (1347.318 us; speedup 1.0000x reference)
//
#include <hip/hip_runtime.h>
#include <stdint.h>

typedef unsigned short u16;
typedef __attribute__((ext_vector_type(8))) __bf16 bf16x8;
typedef __attribute__((ext_vector_type(4))) float f32x4;

#define DEV __device__ __forceinline__

DEV u16 f2b(float f) {
  union { float f; uint32_t u; } v; v.f = f;
  uint32_t u = v.u;
  return (u16)((u + 0x7fffu + ((u >> 16) & 1u)) >> 16);
}
DEV float b2f(u16 h) {
  union { uint32_t u; float f; } v; v.u = ((uint32_t)h) << 16;
  return v.f;
}

// ---------------- weight convert + transpose: Wsrc (768 x N) f32 -> Wt (Npad x 768) bf16
__global__ void wconv_kernel(const float* __restrict__ Wsrc, u16* __restrict__ Wt,
                             int N, int Npad) {
  int idx = blockIdx.x * 256 + threadIdx.x;
  if (idx >= Npad * 768) return;
  int n = idx / 768, k = idx - n * 768;
  Wt[idx] = (n < N) ? f2b(Wsrc[(size_t)k * N + n]) : (u16)0;
}

// ---------------- layernorm (row of 768), writes bf16 ----------------
DEV void ln_row(const float* __restrict__ x, const float* __restrict__ g,
                const float* __restrict__ b, u16* __restrict__ o, int t, float* red) {
  float v0 = x[t], v1 = x[t + 256], v2 = x[t + 512];
  float s = v0 + v1 + v2;
  float s2 = v0 * v0 + v1 * v1 + v2 * v2;
  #pragma unroll
  for (int m = 1; m < 64; m <<= 1) { s += __shfl_xor(s, m); s2 += __shfl_xor(s2, m); }
  if ((t & 63) == 0) { red[t >> 6] = s; red[4 + (t >> 6)] = s2; }
  __syncthreads();
  float S = red[0] + red[1] + red[2] + red[3];
  float S2 = red[4] + red[5] + red[6] + red[7];
  float mean = S * (1.0f / 768.0f);
  float var = S2 * (1.0f / 768.0f) - mean * mean;
  float rstd = rsqrtf(var + 1e-6f);
  o[t]       = f2b((v0 - mean) * rstd * g[t]       + b[t]);
  o[t + 256] = f2b((v1 - mean) * rstd * g[t + 256] + b[t + 256]);
  o[t + 512] = f2b((v2 - mean) * rstd * g[t + 512] + b[t + 512]);
}

__global__ __launch_bounds__(256) void ln_rows_kernel(const float* __restrict__ in,
    const float* __restrict__ g, const float* __restrict__ b, u16* __restrict__ out) {
  __shared__ float red[8];
  size_t row = blockIdx.x;
  ln_row(in + row * 768, g, b, out + row * 768, threadIdx.x, red);
}

__global__ __launch_bounds__(256) void ln_feat_kernel(const float* __restrict__ s0,
    const float* __restrict__ s1, const float* __restrict__ s2, const float* __restrict__ s3,
    const float* __restrict__ g, const float* __restrict__ b, u16* __restrict__ out) {
  __shared__ float red[8];
  int row = blockIdx.x;
  int bb = row / 14592, pos = row - bb * 14592;
  const float* x;
  if (pos < 256)       x = s0 + ((size_t)bb * 256  + pos) * 768;
  else if (pos < 1280) x = s1 + ((size_t)bb * 1024 + (pos - 256)) * 768;
  else if (pos < 5376) x = s2 + ((size_t)bb * 4096 + (pos - 1280)) * 768;
  else                 x = s3 + ((size_t)bb * 9216 + (pos - 5376)) * 768;
  ln_row(x, g, b, out + (size_t)row * 768, threadIdx.x, red);
}

// ---------------- bf16 MFMA GEMM: C(MxN) = A(Mx768)bf16 @ Wt(Nx768)^T bf16 + bias
enum { MODE_F32 = 0, MODE_BF16 = 1, MODE_FINAL = 2 };

template <int MODE>
__global__ __launch_bounds__(256) void gemm_kernel(
    const u16* __restrict__ A, const u16* __restrict__ Wt,
    const float* __restrict__ bias, int nbias, void* __restrict__ Cout, int N,
    const float* __restrict__ attn, const float* __restrict__ resid,
    const float* __restrict__ g1, const float* __restrict__ g2) {
  constexpr int K = 768;
  __shared__ u16 sA[128 * 64];
  __shared__ u16 sB[128 * 64];
  const int t = threadIdx.x;
  const int lane = t & 63;
  const int w = t >> 6;
  const int wr = w >> 1, wc = w & 1;
  const size_t m0 = (size_t)blockIdx.x * 128;
  const int n0 = blockIdx.y * 128;

  f32x4 acc[4][4] = {};

  for (int kt = 0; kt < K; kt += 64) {
    // stage A,B tiles: linear LDS dest (wave-uniform base + lane*16),
    // XOR-swizzle applied by permuting the GLOBAL k-chunk per (row,c8)
    #pragma unroll
    for (int i = 0; i < 4; ++i) {
      int ci = i * 256 + t;
      int row = ci >> 3, c8 = ci & 7;
      int kc = c8 ^ (row & 7);
      const u16* ga = A + (m0 + row) * K + kt + kc * 8;
      const u16* gb = Wt + ((size_t)n0 + row) * K + kt + kc * 8;
      __builtin_amdgcn_global_load_lds((const __attribute__((address_space(1))) void*)ga,
          (__attribute__((address_space(3))) void*)(sA + ci * 8), 16, 0, 0);
      __builtin_amdgcn_global_load_lds((const __attribute__((address_space(1))) void*)gb,
          (__attribute__((address_space(3))) void*)(sB + ci * 8), 16, 0, 0);
    }
    __syncthreads();
    #pragma unroll
    for (int ks = 0; ks < 2; ++ks) {
      bf16x8 af[4], bfr[4];
      #pragma unroll
      for (int m = 0; m < 4; ++m) {
        int row = wr * 64 + m * 16 + (lane & 15);
        int pc = (ks * 4 + (lane >> 4)) ^ (row & 7);
        af[m] = *(const bf16x8*)(sA + row * 64 + pc * 8);
      }
      #pragma unroll
      for (int n = 0; n < 4; ++n) {
        int row = wc * 64 + n * 16 + (lane & 15);
        int pc = (ks * 4 + (lane >> 4)) ^ (row & 7);
        bfr[n] = *(const bf16x8*)(sB + row * 64 + pc * 8);
      }
      #pragma unroll
      for (int m = 0; m < 4; ++m)
        #pragma unroll
        for (int n = 0; n < 4; ++n)
          acc[m][n] = __builtin_amdgcn_mfma_f32_16x16x32_bf16(af[m], bfr[n], acc[m][n], 0, 0, 0);
    }
    __syncthreads();
  }

  #pragma unroll
  for (int m = 0; m < 4; ++m) {
    #pragma unroll
    for (int n = 0; n < 4; ++n) {
      int col = n0 + wc * 64 + n * 16 + (lane & 15);
      float bv = (col < nbias) ? bias[col] : 0.0f;
      #pragma unroll
      for (int r = 0; r < 4; ++r) {
        size_t grow = m0 + (size_t)(wr * 64 + m * 16 + (lane >> 4) * 4 + r);
        float v = acc[m][n][r] + bv;
        size_t idx = grow * (size_t)N + col;
        if constexpr (MODE == MODE_F32) {
          ((float*)Cout)[idx] = v;
        } else if constexpr (MODE == MODE_BF16) {
          ((u16*)Cout)[idx] = f2b(v);
        } else {
          ((float*)Cout)[idx] = resid[idx] + g1[col] * (attn[idx] + g2[col] * v);
        }
      }
    }
  }
}

// ---------------- deformable sampling ----------------
DEV float corner(const u16* __restrict__ vb, int x, int y, int W, int H, float w) {
  if ((unsigned)x < (unsigned)W && (unsigned)y < (unsigned)H)
    return w * b2f(vb[(size_t)(y * W + x) * 768]);
  return 0.0f;
}

__global__ __launch_bounds__(768) void samp_c_kernel(const u16* __restrict__ value,
    const float* __restrict__ off, const float* __restrict__ aw, u16* __restrict__ out) {
  __shared__ float s_off[512];
  __shared__ float s_a[256];
  const int bq = blockIdx.x;
  const int b = bq / 9216, q = bq - b * 9216;
  const int t = threadIdx.x;
  if (t < 512) s_off[t] = off[(size_t)bq * 512 + t];
  else         s_a[t - 512] = aw[(size_t)bq * 256 + (t - 512)];
  __syncthreads();
  const int h = t / 48, d = t - h * 48;
  float mx = -1e30f;
  #pragma unroll
  for (int i = 0; i < 16; ++i) mx = fmaxf(mx, s_a[h * 16 + i]);
  float e[16], sum = 0.0f;
  #pragma unroll
  for (int i = 0; i < 16; ++i) { e[i] = __expf(s_a[h * 16 + i] - mx); sum += e[i]; }
  const float rs = 1.0f / sum;
  const float rx = ((q % 96) + 0.5f) * (1.0f / 96.0f);
  const float ry = ((q / 96) + 0.5f) * (1.0f / 96.0f);
  float acc = 0.0f;
  const int WL[4] = {16, 32, 64, 96};
  const int ST[4] = {0, 256, 1280, 5376};
  #pragma unroll
  for (int l = 0; l < 4; ++l) {
    const int Wd = WL[l];
    const float fW = (float)Wd;
    const u16* vb = value + ((size_t)b * 14592 + ST[l]) * 768 + h * 48 + d;
    #pragma unroll
    for (int p = 0; p < 4; ++p) {
      float ox = s_off[h * 32 + l * 8 + p * 2];
      float oy = s_off[h * 32 + l * 8 + p * 2 + 1];
      float px = (rx + ox / fW) * fW - 0.5f;
      float py = (ry + oy / fW) * fW - 0.5f;
      float wgt = e[l * 4 + p] * rs;
      float x0f = floorf(px), y0f = floorf(py);
      float lx = px - x0f, ly = py - y0f;
      int x0 = (int)x0f, y0 = (int)y0f;
      acc += corner(vb, x0,     y0,     Wd, Wd, (1.0f-lx)*(1.0f-ly)*wgt);
      acc += corner(vb, x0 + 1, y0,     Wd, Wd, lx*(1.0f-ly)*wgt);
      acc += corner(vb, x0,     y0 + 1, Wd, Wd, (1.0f-lx)*ly*wgt);
      acc += corner(vb, x0 + 1, y0 + 1, Wd, Wd, lx*ly*wgt);
    }
  }
  out[(size_t)bq * 768 + h * 48 + d] = f2b(acc);
}

__global__ __launch_bounds__(768) void samp_s_kernel(const u16* __restrict__ value,
    const float* __restrict__ off, const float* __restrict__ aw, u16* __restrict__ out) {
  __shared__ float s_off[128];
  __shared__ float s_a[64];
  const int bq = blockIdx.x;
  const int b = bq / 9216, q = bq - b * 9216;
  const int t = threadIdx.x;
  if (t < 128)      s_off[t] = off[(size_t)bq * 128 + t];
  else if (t < 192) s_a[t - 128] = aw[(size_t)bq * 128 + (t - 128)];
  __syncthreads();
  const int h = t / 48, d = t - h * 48;
  float mx = -1e30f;
  #pragma unroll
  for (int i = 0; i < 4; ++i) mx = fmaxf(mx, s_a[h * 4 + i]);
  float e[4], sum = 0.0f;
  #pragma unroll
  for (int i = 0; i < 4; ++i) { e[i] = __expf(s_a[h * 4 + i] - mx); sum += e[i]; }
  const float rs = 1.0f / sum;
  const float rx = ((q % 96) + 0.5f) * (1.0f / 96.0f);
  const float ry = ((q / 96) + 0.5f) * (1.0f / 96.0f);
  float acc = 0.0f;
  const u16* vb = value + (size_t)b * 9216 * 768 + h * 48 + d;
  #pragma unroll
  for (int p = 0; p < 4; ++p) {
    float ox = s_off[h * 8 + p * 2], oy = s_off[h * 8 + p * 2 + 1];
    float px = (rx + ox * (1.0f / 96.0f)) * 96.0f - 0.5f;
    float py = (ry + oy * (1.0f / 96.0f)) * 96.0f - 0.5f;
    float wgt = e[p] * rs;
    float x0f = floorf(px), y0f = floorf(py);
    float lx = px - x0f, ly = py - y0f;
    int x0 = (int)x0f, y0 = (int)y0f;
    acc += corner(vb, x0,     y0,     96, 96, (1.0f-lx)*(1.0f-ly)*wgt);
    acc += corner(vb, x0 + 1, y0,     96, 96, lx*(1.0f-ly)*wgt);
    acc += corner(vb, x0,     y0 + 1, 96, 96, (1.0f-lx)*ly*wgt);
    acc += corner(vb, x0 + 1, y0 + 1, 96, 96, lx*ly*wgt);
  }
  out[(size_t)bq * 768 + h * 48 + d] = f2b(acc);
}

// ---------------- launch ----------------
extern "C" void kernel_launch(void* const* d_in, const int* in_sizes, int n_in,
                              void* d_out, int out_size, void* d_ws, size_t ws_size,
                              hipStream_t stream) {
  (void)in_sizes; (void)n_in; (void)out_size; (void)ws_size;
  const float* src0 = (const float*)d_in[0];
  const float* src1 = (const float*)d_in[1];
  const float* src2 = (const float*)d_in[2];
  const float* src3 = (const float*)d_in[3];
  const float* qn_g = (const float*)d_in[4];
  const float* qn_b = (const float*)d_in[5];
  const float* fn_g = (const float*)d_in[6];
  const float* fn_b = (const float*)d_in[7];
  const float* n1_g = (const float*)d_in[8];
  const float* n1_b = (const float*)d_in[9];
  const float* gamma1 = (const float*)d_in[10];
  const float* gamma2 = (const float*)d_in[11];
  const float* c_Wv  = (const float*)d_in[12]; const float* c_bv   = (const float*)d_in[13];
  const float* c_Woff= (const float*)d_in[14]; const float* c_boff = (const float*)d_in[15];
  const float* c_Wa  = (const float*)d_in[16]; const float* c_ba   = (const float*)d_in[17];
  const float* c_Wo  = (const float*)d_in[18]; const float* c_bo   = (const float*)d_in[19];
  const float* s_Wv  = (const float*)d_in[20]; const float* s_bv   = (const float*)d_in[21];
  const float* s_Woff= (const float*)d_in[22]; const float* s_boff = (const float*)d_in[23];
  const float* s_Wa  = (const float*)d_in[24]; const float* s_ba   = (const float*)d_in[25];
  const float* s_Wo  = (const float*)d_in[26]; const float* s_bo   = (const float*)d_in[27];

  constexpr int Lq = 9216, Lin = 14592;
  constexpr int Mq = 2 * Lq;    // 18432
  constexpr int Mf = 2 * Lin;   // 29184

  // weight region (bf16, transposed, s_Wa padded to 128 rows)
  constexpr size_t O_cWv   = 0;
  constexpr size_t O_cWoff = O_cWv   + (size_t)768 * 768 * 2;
  constexpr size_t O_cWa   = O_cWoff + (size_t)512 * 768 * 2;
  constexpr size_t O_cWo   = O_cWa   + (size_t)256 * 768 * 2;
  constexpr size_t O_sWv   = O_cWo   + (size_t)768 * 768 * 2;
  constexpr size_t O_sWoff = O_sWv   + (size_t)768 * 768 * 2;
  constexpr size_t O_sWa   = O_sWoff + (size_t)128 * 768 * 2;
  constexpr size_t O_sWo   = O_sWa   + (size_t)128 * 768 * 2;
  // arena (with lifetime-based reuse)
  constexpr size_t O_qln   = 8u << 20;
  constexpr size_t O_fln   = O_qln   + (size_t)Mq * 768 * 2;
  constexpr size_t O_valc  = O_fln   + (size_t)Mf * 768 * 2;  // bf16
  constexpr size_t O_offc  = O_valc  + (size_t)Mf * 768 * 2;
  constexpr size_t O_ac    = O_offc  + (size_t)Mq * 512 * 4;
  constexpr size_t O_sampc = O_qln;                           // reuse (q_ln dead)
  constexpr size_t O_attn  = O_fln;                           // reuse (f_ln/val_c dead)
  constexpr size_t O_attn1 = O_attn  + (size_t)Mq * 768 * 4;
  constexpr size_t O_vals  = O_attn1 + (size_t)Mq * 768 * 2;  // bf16
  constexpr size_t O_offs  = O_vals  + (size_t)Mq * 768 * 2;
  constexpr size_t O_as    = O_offs  + (size_t)Mq * 128 * 4;
  constexpr size_t O_samps = O_as    + (size_t)Mq * 128 * 4;

  uint8_t* ws = (uint8_t*)d_ws;
  auto Wp = [&](size_t o) { return (u16*)(ws + o); };
  auto Fp = [&](size_t o) { return (float*)(ws + o); };

  // 1) weight transposes (bf16)
  wconv_kernel<<<(768 * 768 + 255) / 256, 256, 0, stream>>>(c_Wv,  Wp(O_cWv),  768, 768);
  wconv_kernel<<<(512 * 768 + 255) / 256, 256, 0, stream>>>(c_Woff,Wp(O_cWoff),512, 512);
  wconv_kernel<<<(256 * 768 + 255) / 256, 256, 0, stream>>>(c_Wa,  Wp(O_cWa),  256, 256);
  wconv_kernel<<<(768 * 768 + 255) / 256, 256, 0, stream>>>(c_Wo,  Wp(O_cWo),  768, 768);
  wconv_kernel<<<(768 * 768 + 255) / 256, 256, 0, stream>>>(s_Wv,  Wp(O_sWv),  768, 768);
  wconv_kernel<<<(128 * 768 + 255) / 256, 256, 0, stream>>>(s_Woff,Wp(O_sWoff),128, 128);
  wconv_kernel<<<(128 * 768 + 255) / 256, 256, 0, stream>>>(s_Wa,  Wp(O_sWa),  64,  128);
  wconv_kernel<<<(768 * 768 + 255) / 256, 256, 0, stream>>>(s_Wo,  Wp(O_sWo),  768, 768);

  // 2) layernorms of query and feat
  ln_rows_kernel<<<Mq, 256, 0, stream>>>(src3, qn_g, qn_b, Wp(O_qln));
  ln_feat_kernel<<<Mf, 256, 0, stream>>>(src0, src1, src2, src3, fn_g, fn_b, Wp(O_fln));

  // 3) cross-attn GEMMs
  gemm_kernel<MODE_BF16><<<dim3(Mf / 128, 6), 256, 0, stream>>>(
      Wp(O_fln), Wp(O_cWv), c_bv, 768, Wp(O_valc), 768, nullptr, nullptr, nullptr, nullptr);
  gemm_kernel<MODE_F32><<<dim3(Mq / 128, 4), 256, 0, stream>>>(
      Wp(O_qln), Wp(O_cWoff), c_boff, 512, Fp(O_offc), 512, nullptr, nullptr, nullptr, nullptr);
  gemm_kernel<MODE_F32><<<dim3(Mq / 128, 2), 256, 0, stream>>>(
      Wp(O_qln), Wp(O_cWa), c_ba, 256, Fp(O_ac), 256, nullptr, nullptr, nullptr, nullptr);

  // 4) deformable sampling (4 levels)
  samp_c_kernel<<<Mq, 768, 0, stream>>>(Wp(O_valc), Fp(O_offc), Fp(O_ac), Wp(O_sampc));

  // 5) output proj -> attn (f32)
  gemm_kernel<MODE_F32><<<dim3(Mq / 128, 6), 256, 0, stream>>>(
      Wp(O_sampc), Wp(O_cWo), c_bo, 768, Fp(O_attn), 768, nullptr, nullptr, nullptr, nullptr);

  // 6) LN -> attn1 (bf16)
  ln_rows_kernel<<<Mq, 256, 0, stream>>>(Fp(O_attn), n1_g, n1_b, Wp(O_attn1));

  // 7) self-attn GEMMs
  gemm_kernel<MODE_BF16><<<dim3(Mq / 128, 6), 256, 0, stream>>>(
      Wp(O_attn1), Wp(O_sWv), s_bv, 768, Wp(O_vals), 768, nullptr, nullptr, nullptr, nullptr);
  gemm_kernel<MODE_F32><<<dim3(Mq / 128, 1), 256, 0, stream>>>(
      Wp(O_attn1), Wp(O_sWoff), s_boff, 128, Fp(O_offs), 128, nullptr, nullptr, nullptr, nullptr);
  gemm_kernel<MODE_F32><<<dim3(Mq / 128, 1), 256, 0, stream>>>(
      Wp(O_attn1), Wp(O_sWa), s_ba, 64, Fp(O_as), 128, nullptr, nullptr, nullptr, nullptr);

  // 8) sampling (1 level) + final fused GEMM:
  //    out = src3 + g1*(attn + g2*(samp_s @ s_Wo + s_bo))
  samp_s_kernel<<<Mq, 768, 0, stream>>>(Wp(O_vals), Fp(O_offs), Fp(O_as), Wp(O_samps));
  gemm_kernel<MODE_FINAL><<<dim3(Mq / 128, 6), 256, 0, stream>>>(
      Wp(O_samps), Wp(O_sWo), s_bo, 768, (float*)d_out, 768, Fp(O_attn), src3, gamma1, gamma2);
}

// Round 2
// 569.010 us; speedup vs baseline: 2.3678x; 2.3678x over previous
//
#include <hip/hip_runtime.h>
#include <stdint.h>

typedef unsigned short u16;
typedef __attribute__((ext_vector_type(8))) __bf16 bf16x8;
typedef __attribute__((ext_vector_type(4))) float f32x4;
typedef __attribute__((ext_vector_type(8))) u16 u16x8;

#define DEV __device__ __forceinline__

DEV u16 f2b(float f) {
  union { float f; uint32_t u; } v; v.f = f;
  uint32_t u = v.u;
  return (u16)((u + 0x7fffu + ((u >> 16) & 1u)) >> 16);
}
DEV float b2f(u16 h) {
  union { uint32_t u; float f; } v; v.u = ((uint32_t)h) << 16;
  return v.f;
}
DEV float u2f(uint32_t u) {
  union { uint32_t u; float f; } v; v.u = u;
  return v.f;
}

// fused gather-convert-FMA of 8 bf16 channels
DEV void fma8(float acc[8], const u16* __restrict__ p, float w) {
  uint4 v = *(const uint4*)p;
  const uint32_t* pv = (const uint32_t*)&v;
  #pragma unroll
  for (int j = 0; j < 4; ++j) {
    uint32_t u = pv[j];
    acc[2 * j]     += w * u2f(u << 16);
    acc[2 * j + 1] += w * u2f(u & 0xffff0000u);
  }
}

// ---------------- weight convert + transpose: Wsrc (768 x N) f32 -> Wt (Npad x 768) bf16
__global__ void wconv_kernel(const float* __restrict__ Wsrc, u16* __restrict__ Wt,
                             int N, int Npad) {
  int idx = blockIdx.x * 256 + threadIdx.x;
  if (idx >= Npad * 768) return;
  int n = idx / 768, k = idx - n * 768;
  Wt[idx] = (n < N) ? f2b(Wsrc[(size_t)k * N + n]) : (u16)0;
}

// ---------------- layernorm (row of 768), writes bf16 ----------------
DEV void ln_row(const float* __restrict__ x, const float* __restrict__ g,
                const float* __restrict__ b, u16* __restrict__ o, int t, float* red) {
  float v0 = x[t], v1 = x[t + 256], v2 = x[t + 512];
  float s = v0 + v1 + v2;
  float s2 = v0 * v0 + v1 * v1 + v2 * v2;
  #pragma unroll
  for (int m = 1; m < 64; m <<= 1) { s += __shfl_xor(s, m); s2 += __shfl_xor(s2, m); }
  if ((t & 63) == 0) { red[t >> 6] = s; red[4 + (t >> 6)] = s2; }
  __syncthreads();
  float S = red[0] + red[1] + red[2] + red[3];
  float S2 = red[4] + red[5] + red[6] + red[7];
  float mean = S * (1.0f / 768.0f);
  float var = S2 * (1.0f / 768.0f) - mean * mean;
  float rstd = rsqrtf(var + 1e-6f);
  o[t]       = f2b((v0 - mean) * rstd * g[t]       + b[t]);
  o[t + 256] = f2b((v1 - mean) * rstd * g[t + 256] + b[t + 256]);
  o[t + 512] = f2b((v2 - mean) * rstd * g[t + 512] + b[t + 512]);
}

__global__ __launch_bounds__(256) void ln_rows_kernel(const float* __restrict__ in,
    const float* __restrict__ g, const float* __restrict__ b, u16* __restrict__ out) {
  __shared__ float red[8];
  size_t row = blockIdx.x;
  ln_row(in + row * 768, g, b, out + row * 768, threadIdx.x, red);
}

__global__ __launch_bounds__(256) void ln_feat_kernel(const float* __restrict__ s0,
    const float* __restrict__ s1, const float* __restrict__ s2, const float* __restrict__ s3,
    const float* __restrict__ g, const float* __restrict__ b, u16* __restrict__ out) {
  __shared__ float red[8];
  int row = blockIdx.x;
  int bb = row / 14592, pos = row - bb * 14592;
  const float* x;
  if (pos < 256)       x = s0 + ((size_t)bb * 256  + pos) * 768;
  else if (pos < 1280) x = s1 + ((size_t)bb * 1024 + (pos - 256)) * 768;
  else if (pos < 5376) x = s2 + ((size_t)bb * 4096 + (pos - 1280)) * 768;
  else                 x = s3 + ((size_t)bb * 9216 + (pos - 5376)) * 768;
  ln_row(x, g, b, out + (size_t)row * 768, threadIdx.x, red);
}

// ---------------- bf16 MFMA GEMM: C(MxN) = A(Mx768)bf16 @ Wt(Nx768)^T bf16 + bias
enum { MODE_F32 = 0, MODE_BF16 = 1, MODE_FINAL = 2 };

template <int MODE>
__global__ __launch_bounds__(256) void gemm_kernel(
    const u16* __restrict__ A, const u16* __restrict__ Wt,
    const float* __restrict__ bias, int nbias, void* __restrict__ Cout, int N,
    const float* __restrict__ attn, const float* __restrict__ resid,
    const float* __restrict__ g1, const float* __restrict__ g2) {
  constexpr int K = 768;
  __shared__ u16 sA[128 * 64];
  __shared__ u16 sB[128 * 64];
  const int t = threadIdx.x;
  const int lane = t & 63;
  const int w = t >> 6;
  const int wr = w >> 1, wc = w & 1;
  const size_t m0 = (size_t)blockIdx.x * 128;
  const int n0 = blockIdx.y * 128;

  f32x4 acc[4][4] = {};

  for (int kt = 0; kt < K; kt += 64) {
    #pragma unroll
    for (int i = 0; i < 4; ++i) {
      int ci = i * 256 + t;
      int row = ci >> 3, c8 = ci & 7;
      int kc = c8 ^ (row & 7);
      const u16* ga = A + (m0 + row) * K + kt + kc * 8;
      const u16* gb = Wt + ((size_t)n0 + row) * K + kt + kc * 8;
      __builtin_amdgcn_global_load_lds((const __attribute__((address_space(1))) void*)ga,
          (__attribute__((address_space(3))) void*)(sA + ci * 8), 16, 0, 0);
      __builtin_amdgcn_global_load_lds((const __attribute__((address_space(1))) void*)gb,
          (__attribute__((address_space(3))) void*)(sB + ci * 8), 16, 0, 0);
    }
    __syncthreads();
    #pragma unroll
    for (int ks = 0; ks < 2; ++ks) {
      bf16x8 af[4], bfr[4];
      #pragma unroll
      for (int m = 0; m < 4; ++m) {
        int row = wr * 64 + m * 16 + (lane & 15);
        int pc = (ks * 4 + (lane >> 4)) ^ (row & 7);
        af[m] = *(const bf16x8*)(sA + row * 64 + pc * 8);
      }
      #pragma unroll
      for (int n = 0; n < 4; ++n) {
        int row = wc * 64 + n * 16 + (lane & 15);
        int pc = (ks * 4 + (lane >> 4)) ^ (row & 7);
        bfr[n] = *(const bf16x8*)(sB + row * 64 + pc * 8);
      }
      #pragma unroll
      for (int m = 0; m < 4; ++m)
        #pragma unroll
        for (int n = 0; n < 4; ++n)
          acc[m][n] = __builtin_amdgcn_mfma_f32_16x16x32_bf16(af[m], bfr[n], acc[m][n], 0, 0, 0);
    }
    __syncthreads();
  }

  #pragma unroll
  for (int m = 0; m < 4; ++m) {
    #pragma unroll
    for (int n = 0; n < 4; ++n) {
      int col = n0 + wc * 64 + n * 16 + (lane & 15);
      float bv = (col < nbias) ? bias[col] : 0.0f;
      #pragma unroll
      for (int r = 0; r < 4; ++r) {
        size_t grow = m0 + (size_t)(wr * 64 + m * 16 + (lane >> 4) * 4 + r);
        float v = acc[m][n][r] + bv;
        size_t idx = grow * (size_t)N + col;
        if constexpr (MODE == MODE_F32) {
          ((float*)Cout)[idx] = v;
        } else if constexpr (MODE == MODE_BF16) {
          ((u16*)Cout)[idx] = f2b(v);
        } else {
          ((float*)Cout)[idx] = resid[idx] + g1[col] * (attn[idx] + g2[col] * v);
        }
      }
    }
  }
}

// ---------------- deformable sampling (vectorized: thread = (query, head, d8)) ----
// 4 queries/block, 384 threads: tid -> qi = tid/96, r = tid%96, h = r/6, d8 = r%6.
// Each thread accumulates 8 consecutive channels via 16B bf16x8 gathers.
__global__ __launch_bounds__(384) void samp_c_kernel(const u16* __restrict__ value,
    const float* __restrict__ off, const float* __restrict__ aw, u16* __restrict__ out) {
  __shared__ float s_off[2048];   // 4 queries x 512
  __shared__ float s_a[1024];     // 4 queries x 256
  // XCD-chunked swizzle (gridDim.x = 4608, divisible by 8): contiguous query
  // bands per XCD so each XCD's sampled value rows stay in its private L2.
  const int orig = blockIdx.x;
  const int cpx = gridDim.x >> 3;
  const int bq0 = ((orig & 7) * cpx + (orig >> 3)) * 4;
  const int t = threadIdx.x;
  const float4* o4 = (const float4*)(off + (size_t)bq0 * 512);
  const float4* a4 = (const float4*)(aw + (size_t)bq0 * 256);
  for (int i = t; i < 512; i += 384) ((float4*)s_off)[i] = o4[i];
  if (t < 256) ((float4*)s_a)[t] = a4[t];
  __syncthreads();

  const int qi = t / 96, r = t - qi * 96;
  const int h = r / 6, d8 = r - h * 6;
  const int bq = bq0 + qi;
  const int b = bq / 9216, q = bq - b * 9216;

  // softmax over this head's 16 logits (redundant across the 6 d8 lanes)
  const float* sa = s_a + qi * 256 + h * 16;
  float mx = -1e30f;
  #pragma unroll
  for (int i = 0; i < 16; ++i) mx = fmaxf(mx, sa[i]);
  float e[16], sum = 0.0f;
  #pragma unroll
  for (int i = 0; i < 16; ++i) { e[i] = __expf(sa[i] - mx); sum += e[i]; }
  const float rs = 1.0f / sum;

  const float rx = ((q % 96) + 0.5f) * (1.0f / 96.0f);
  const float ry = ((q / 96) + 0.5f) * (1.0f / 96.0f);
  const float* so = s_off + qi * 512 + h * 32;

  float acc[8] = {};
  const int WL[4] = {16, 32, 64, 96};
  const int ST[4] = {0, 256, 1280, 5376};
  #pragma unroll
  for (int l = 0; l < 4; ++l) {
    const int Wd = WL[l];
    const float fW = (float)Wd;
    const u16* vb = value + ((size_t)b * 14592 + ST[l]) * 768 + h * 48 + d8 * 8;
    #pragma unroll
    for (int p = 0; p < 4; ++p) {
      float ox = so[l * 8 + p * 2];
      float oy = so[l * 8 + p * 2 + 1];
      float px = (rx + ox / fW) * fW - 0.5f;
      float py = (ry + oy / fW) * fW - 0.5f;
      float wgt = e[l * 4 + p] * rs;
      float x0f = floorf(px), y0f = floorf(py);
      float lx = px - x0f, ly = py - y0f;
      int x0 = (int)x0f, y0 = (int)y0f;
      bool vx0 = (unsigned)x0 < (unsigned)Wd, vx1 = (unsigned)(x0 + 1) < (unsigned)Wd;
      bool vy0 = (unsigned)y0 < (unsigned)Wd, vy1 = (unsigned)(y0 + 1) < (unsigned)Wd;
      if (vx0 & vy0) fma8(acc, vb + (size_t)(y0 * Wd + x0) * 768,       (1.0f-lx)*(1.0f-ly)*wgt);
      if (vx1 & vy0) fma8(acc, vb + (size_t)(y0 * Wd + x0 + 1) * 768,   lx*(1.0f-ly)*wgt);
      if (vx0 & vy1) fma8(acc, vb + (size_t)((y0+1) * Wd + x0) * 768,   (1.0f-lx)*ly*wgt);
      if (vx1 & vy1) fma8(acc, vb + (size_t)((y0+1) * Wd + x0 + 1) * 768, lx*ly*wgt);
    }
  }
  u16x8 o;
  #pragma unroll
  for (int j = 0; j < 8; ++j) o[j] = f2b(acc[j]);
  *(u16x8*)(out + (size_t)bq * 768 + h * 48 + d8 * 8) = o;
}

__global__ __launch_bounds__(384) void samp_s_kernel(const u16* __restrict__ value,
    const float* __restrict__ off, const float* __restrict__ aw, u16* __restrict__ out) {
  __shared__ float s_off[512];    // 4 x 128
  __shared__ float s_a[256];      // 4 x 64
  const int orig = blockIdx.x;
  const int cpx = gridDim.x >> 3;
  const int bq0 = ((orig & 7) * cpx + (orig >> 3)) * 4;
  const int t = threadIdx.x;
  const float4* o4 = (const float4*)(off + (size_t)bq0 * 128);
  const float4* a4 = (const float4*)(aw + (size_t)bq0 * 64);
  if (t < 128)      ((float4*)s_off)[t] = o4[t];
  else if (t < 192) ((float4*)s_a)[t - 128] = a4[t - 128];
  __syncthreads();

  const int qi = t / 96, r = t - qi * 96;
  const int h = r / 6, d8 = r - h * 6;
  const int bq = bq0 + qi;
  const int b = bq / 9216, q = bq - b * 9216;

  const float* sa = s_a + qi * 64 + h * 4;
  float mx = -1e30f;
  #pragma unroll
  for (int i = 0; i < 4; ++i) mx = fmaxf(mx, sa[i]);
  float e[4], sum = 0.0f;
  #pragma unroll
  for (int i = 0; i < 4; ++i) { e[i] = __expf(sa[i] - mx); sum += e[i]; }
  const float rs = 1.0f / sum;

  const float rx = ((q % 96) + 0.5f) * (1.0f / 96.0f);
  const float ry = ((q / 96) + 0.5f) * (1.0f / 96.0f);
  const float* so = s_off + qi * 128 + h * 8;

  float acc[8] = {};
  const u16* vb = value + (size_t)b * 9216 * 768 + h * 48 + d8 * 8;
  #pragma unroll
  for (int p = 0; p < 4; ++p) {
    float ox = so[p * 2], oy = so[p * 2 + 1];
    float px = (rx + ox * (1.0f / 96.0f)) * 96.0f - 0.5f;
    float py = (ry + oy * (1.0f / 96.0f)) * 96.0f - 0.5f;
    float wgt = e[p] * rs;
    float x0f = floorf(px), y0f = floorf(py);
    float lx = px - x0f, ly = py - y0f;
    int x0 = (int)x0f, y0 = (int)y0f;
    bool vx0 = (unsigned)x0 < 96u, vx1 = (unsigned)(x0 + 1) < 96u;
    bool vy0 = (unsigned)y0 < 96u, vy1 = (unsigned)(y0 + 1) < 96u;
    if (vx0 & vy0) fma8(acc, vb + (size_t)(y0 * 96 + x0) * 768,        (1.0f-lx)*(1.0f-ly)*wgt);
    if (vx1 & vy0) fma8(acc, vb + (size_t)(y0 * 96 + x0 + 1) * 768,    lx*(1.0f-ly)*wgt);
    if (vx0 & vy1) fma8(acc, vb + (size_t)((y0+1) * 96 + x0) * 768,    (1.0f-lx)*ly*wgt);
    if (vx1 & vy1) fma8(acc, vb + (size_t)((y0+1) * 96 + x0 + 1) * 768, lx*ly*wgt);
  }
  u16x8 o;
  #pragma unroll
  for (int j = 0; j < 8; ++j) o[j] = f2b(acc[j]);
  *(u16x8*)(out + (size_t)bq * 768 + h * 48 + d8 * 8) = o;
}

// ---------------- launch ----------------
extern "C" void kernel_launch(void* const* d_in, const int* in_sizes, int n_in,
                              void* d_out, int out_size, void* d_ws, size_t ws_size,
                              hipStream_t stream) {
  (void)in_sizes; (void)n_in; (void)out_size; (void)ws_size;
  const float* src0 = (const float*)d_in[0];
  const float* src1 = (const float*)d_in[1];
  const float* src2 = (const float*)d_in[2];
  const float* src3 = (const float*)d_in[3];
  const float* qn_g = (const float*)d_in[4];
  const float* qn_b = (const float*)d_in[5];
  const float* fn_g = (const float*)d_in[6];
  const float* fn_b = (const float*)d_in[7];
  const float* n1_g = (const float*)d_in[8];
  const float* n1_b = (const float*)d_in[9];
  const float* gamma1 = (const float*)d_in[10];
  const float* gamma2 = (const float*)d_in[11];
  const float* c_Wv  = (const float*)d_in[12]; const float* c_bv   = (const float*)d_in[13];
  const float* c_Woff= (const float*)d_in[14]; const float* c_boff = (const float*)d_in[15];
  const float* c_Wa  = (const float*)d_in[16]; const float* c_ba   = (const float*)d_in[17];
  const float* c_Wo  = (const float*)d_in[18]; const float* c_bo   = (const float*)d_in[19];
  const float* s_Wv  = (const float*)d_in[20]; const float* s_bv   = (const float*)d_in[21];
  const float* s_Woff= (const float*)d_in[22]; const float* s_boff = (const float*)d_in[23];
  const float* s_Wa  = (const float*)d_in[24]; const float* s_ba   = (const float*)d_in[25];
  const float* s_Wo  = (const float*)d_in[26]; const float* s_bo   = (const float*)d_in[27];

  constexpr int Lq = 9216, Lin = 14592;
  constexpr int Mq = 2 * Lq;    // 18432
  constexpr int Mf = 2 * Lin;   // 29184

  constexpr size_t O_cWv   = 0;
  constexpr size_t O_cWoff = O_cWv   + (size_t)768 * 768 * 2;
  constexpr size_t O_cWa   = O_cWoff + (size_t)512 * 768 * 2;
  constexpr size_t O_cWo   = O_cWa   + (size_t)256 * 768 * 2;
  constexpr size_t O_sWv   = O_cWo   + (size_t)768 * 768 * 2;
  constexpr size_t O_sWoff = O_sWv   + (size_t)768 * 768 * 2;
  constexpr size_t O_sWa   = O_sWoff + (size_t)128 * 768 * 2;
  constexpr size_t O_sWo   = O_sWa   + (size_t)128 * 768 * 2;
  constexpr size_t O_qln   = 8u << 20;
  constexpr size_t O_fln   = O_qln   + (size_t)Mq * 768 * 2;
  constexpr size_t O_valc  = O_fln   + (size_t)Mf * 768 * 2;  // bf16
  constexpr size_t O_offc  = O_valc  + (size_t)Mf * 768 * 2;
  constexpr size_t O_ac    = O_offc  + (size_t)Mq * 512 * 4;
  constexpr size_t O_sampc = O_qln;                           // reuse
  constexpr size_t O_attn  = O_fln;                           // reuse
  constexpr size_t O_attn1 = O_attn  + (size_t)Mq * 768 * 4;
  constexpr size_t O_vals  = O_attn1 + (size_t)Mq * 768 * 2;  // bf16
  constexpr size_t O_offs  = O_vals  + (size_t)Mq * 768 * 2;
  constexpr size_t O_as    = O_offs  + (size_t)Mq * 128 * 4;
  constexpr size_t O_samps = O_as    + (size_t)Mq * 128 * 4;

  uint8_t* ws = (uint8_t*)d_ws;
  auto Wp = [&](size_t o) { return (u16*)(ws + o); };
  auto Fp = [&](size_t o) { return (float*)(ws + o); };

  wconv_kernel<<<(768 * 768 + 255) / 256, 256, 0, stream>>>(c_Wv,  Wp(O_cWv),  768, 768);
  wconv_kernel<<<(512 * 768 + 255) / 256, 256, 0, stream>>>(c_Woff,Wp(O_cWoff),512, 512);
  wconv_kernel<<<(256 * 768 + 255) / 256, 256, 0, stream>>>(c_Wa,  Wp(O_cWa),  256, 256);
  wconv_kernel<<<(768 * 768 + 255) / 256, 256, 0, stream>>>(c_Wo,  Wp(O_cWo),  768, 768);
  wconv_kernel<<<(768 * 768 + 255) / 256, 256, 0, stream>>>(s_Wv,  Wp(O_sWv),  768, 768);
  wconv_kernel<<<(128 * 768 + 255) / 256, 256, 0, stream>>>(s_Woff,Wp(O_sWoff),128, 128);
  wconv_kernel<<<(128 * 768 + 255) / 256, 256, 0, stream>>>(s_Wa,  Wp(O_sWa),  64,  128);
  wconv_kernel<<<(768 * 768 + 255) / 256, 256, 0, stream>>>(s_Wo,  Wp(O_sWo),  768, 768);

  ln_rows_kernel<<<Mq, 256, 0, stream>>>(src3, qn_g, qn_b, Wp(O_qln));
  ln_feat_kernel<<<Mf, 256, 0, stream>>>(src0, src1, src2, src3, fn_g, fn_b, Wp(O_fln));

  gemm_kernel<MODE_BF16><<<dim3(Mf / 128, 6), 256, 0, stream>>>(
      Wp(O_fln), Wp(O_cWv), c_bv, 768, Wp(O_valc), 768, nullptr, nullptr, nullptr, nullptr);
  gemm_kernel<MODE_F32><<<dim3(Mq / 128, 4), 256, 0, stream>>>(
      Wp(O_qln), Wp(O_cWoff), c_boff, 512, Fp(O_offc), 512, nullptr, nullptr, nullptr, nullptr);
  gemm_kernel<MODE_F32><<<dim3(Mq / 128, 2), 256, 0, stream>>>(
      Wp(O_qln), Wp(O_cWa), c_ba, 256, Fp(O_ac), 256, nullptr, nullptr, nullptr, nullptr);

  samp_c_kernel<<<Mq / 4, 384, 0, stream>>>(Wp(O_valc), Fp(O_offc), Fp(O_ac), Wp(O_sampc));

  gemm_kernel<MODE_F32><<<dim3(Mq / 128, 6), 256, 0, stream>>>(
      Wp(O_sampc), Wp(O_cWo), c_bo, 768, Fp(O_attn), 768, nullptr, nullptr, nullptr, nullptr);

  ln_rows_kernel<<<Mq, 256, 0, stream>>>(Fp(O_attn), n1_g, n1_b, Wp(O_attn1));

  gemm_kernel<MODE_BF16><<<dim3(Mq / 128, 6), 256, 0, stream>>>(
      Wp(O_attn1), Wp(O_sWv), s_bv, 768, Wp(O_vals), 768, nullptr, nullptr, nullptr, nullptr);
  gemm_kernel<MODE_F32><<<dim3(Mq / 128, 1), 256, 0, stream>>>(
      Wp(O_attn1), Wp(O_sWoff), s_boff, 128, Fp(O_offs), 128, nullptr, nullptr, nullptr, nullptr);
  gemm_kernel<MODE_F32><<<dim3(Mq / 128, 1), 256, 0, stream>>>(
      Wp(O_attn1), Wp(O_sWa), s_ba, 64, Fp(O_as), 128, nullptr, nullptr, nullptr, nullptr);

  samp_s_kernel<<<Mq / 4, 384, 0, stream>>>(Wp(O_vals), Fp(O_offs), Fp(O_as), Wp(O_samps));
  gemm_kernel<MODE_FINAL><<<dim3(Mq / 128, 6), 256, 0, stream>>>(
      Wp(O_samps), Wp(O_sWo), s_bo, 768, (float*)d_out, 768, Fp(O_attn), src3, gamma1, gamma2);
}

// Round 3
// 487.763 us; speedup vs baseline: 2.7622x; 1.1666x over previous
//
#include <hip/hip_runtime.h>
#include <stdint.h>

typedef unsigned short u16;
typedef __attribute__((ext_vector_type(8))) __bf16 bf16x8;
typedef __attribute__((ext_vector_type(4))) float f32x4;
typedef __attribute__((ext_vector_type(8))) u16 u16x8;
typedef __attribute__((ext_vector_type(4))) u16 u16x4;

#define DEV __device__ __forceinline__

DEV u16 f2b(float f) {
  union { float f; uint32_t u; } v; v.f = f;
  uint32_t u = v.u;
  return (u16)((u + 0x7fffu + ((u >> 16) & 1u)) >> 16);
}
DEV float u2f(uint32_t u) {
  union { uint32_t u; float f; } v; v.u = u;
  return v.f;
}

// fused gather-convert-FMA of 8 bf16 channels from a 16B vector
DEV void fma8u(float acc[8], uint4 v, float w) {
  const uint32_t* pv = (const uint32_t*)&v;
  #pragma unroll
  for (int j = 0; j < 4; ++j) {
    uint32_t u = pv[j];
    acc[2 * j]     += w * u2f(u << 16);
    acc[2 * j + 1] += w * u2f(u & 0xffff0000u);
  }
}

// ---------------- fused weight transpose: 8 regions, tiled 32x32 via LDS ----
// dst rows (Npad each): cWv 768 | cWoff 512 | cWa 256 | cWo 768 | sWv 768 |
// sWoff 128 | sWa 128(real 64) | sWo 768  => 4096 rows x 768 cols bf16
__global__ __launch_bounds__(256) void wconv_kernel(
    const float* __restrict__ W0, const float* __restrict__ W1,
    const float* __restrict__ W2, const float* __restrict__ W3,
    const float* __restrict__ W4, const float* __restrict__ W5,
    const float* __restrict__ W6, const float* __restrict__ W7,
    u16* __restrict__ dst) {
  __shared__ float s[32][33];
  int bx = blockIdx.x;            // 0..3071
  int ct = bx / 24;               // column-tile 0..127
  int kt = bx - ct * 24;          // k-tile 0..23
  const float* Wsrc; int N; int rowbase; int c0;
  if (ct < 24)       { Wsrc = W0; N = 768; rowbase = 0;    c0 = ct; }
  else if (ct < 40)  { Wsrc = W1; N = 512; rowbase = 768;  c0 = ct - 24; }
  else if (ct < 48)  { Wsrc = W2; N = 256; rowbase = 1280; c0 = ct - 40; }
  else if (ct < 72)  { Wsrc = W3; N = 768; rowbase = 1536; c0 = ct - 48; }
  else if (ct < 96)  { Wsrc = W4; N = 768; rowbase = 2304; c0 = ct - 72; }
  else if (ct < 100) { Wsrc = W5; N = 128; rowbase = 3072; c0 = ct - 96; }
  else if (ct < 104) { Wsrc = W6; N = 64;  rowbase = 3200; c0 = ct - 100; }
  else               { Wsrc = W7; N = 768; rowbase = 3328; c0 = ct - 104; }
  const int tx = threadIdx.x & 31, ty = threadIdx.x >> 5;
  const int n = c0 * 32 + tx;
  const int k0 = kt * 32;
  #pragma unroll
  for (int j = 0; j < 4; ++j) {
    int k = k0 + ty + j * 8;
    s[ty + j * 8][tx] = (n < N) ? Wsrc[(size_t)k * N + n] : 0.0f;
  }
  __syncthreads();
  #pragma unroll
  for (int j = 0; j < 4; ++j) {
    int nr = c0 * 32 + ty + j * 8;
    dst[(size_t)(rowbase + nr) * 768 + k0 + tx] = f2b(s[tx][ty + j * 8]);
  }
}

// ---------------- layernorm (row of 768), 192 threads, float4 ----------------
DEV void ln_row4(const float* __restrict__ x, const float* __restrict__ g,
                 const float* __restrict__ b, u16* __restrict__ o, int t, float* red) {
  float4 v = ((const float4*)x)[t];
  float s = v.x + v.y + v.z + v.w;
  float s2 = v.x * v.x + v.y * v.y + v.z * v.z + v.w * v.w;
  #pragma unroll
  for (int m = 1; m < 64; m <<= 1) { s += __shfl_xor(s, m); s2 += __shfl_xor(s2, m); }
  if ((t & 63) == 0) { red[t >> 6] = s; red[3 + (t >> 6)] = s2; }
  __syncthreads();
  float S = red[0] + red[1] + red[2];
  float S2 = red[3] + red[4] + red[5];
  float mean = S * (1.0f / 768.0f);
  float var = S2 * (1.0f / 768.0f) - mean * mean;
  float rstd = rsqrtf(var + 1e-6f);
  float4 gv = ((const float4*)g)[t], bv = ((const float4*)b)[t];
  u16x4 ov;
  ov[0] = f2b((v.x - mean) * rstd * gv.x + bv.x);
  ov[1] = f2b((v.y - mean) * rstd * gv.y + bv.y);
  ov[2] = f2b((v.z - mean) * rstd * gv.z + bv.z);
  ov[3] = f2b((v.w - mean) * rstd * gv.w + bv.w);
  *(u16x4*)(o + t * 4) = ov;
}

__global__ __launch_bounds__(192) void ln_rows_kernel(const float* __restrict__ in,
    const float* __restrict__ g, const float* __restrict__ b, u16* __restrict__ out) {
  __shared__ float red[6];
  size_t row = blockIdx.x;
  ln_row4(in + row * 768, g, b, out + row * 768, threadIdx.x, red);
}

__global__ __launch_bounds__(192) void ln_feat_kernel(const float* __restrict__ s0,
    const float* __restrict__ s1, const float* __restrict__ s2, const float* __restrict__ s3,
    const float* __restrict__ g, const float* __restrict__ b, u16* __restrict__ out) {
  __shared__ float red[6];
  int row = blockIdx.x;
  int bb = row / 14592, pos = row - bb * 14592;
  const float* x;
  if (pos < 256)       x = s0 + ((size_t)bb * 256  + pos) * 768;
  else if (pos < 1280) x = s1 + ((size_t)bb * 1024 + (pos - 256)) * 768;
  else if (pos < 5376) x = s2 + ((size_t)bb * 4096 + (pos - 1280)) * 768;
  else                 x = s3 + ((size_t)bb * 9216 + (pos - 5376)) * 768;
  ln_row4(x, g, b, out + (size_t)row * 768, threadIdx.x, red);
}

// ---------------- bf16 MFMA GEMM, XCD-chunked 1D tile map ----------------
// tile = (bid&7)*chunk + bid>>3; tn innermost -> A-tile L2-resident per XCD.
enum { MODE_F32 = 0, MODE_BF16 = 1, MODE_FINAL = 2 };

template <int MODE, int NT>
__global__ __launch_bounds__(256) void gemm_kernel(
    const u16* __restrict__ A, const u16* __restrict__ Wt,
    const float* __restrict__ bias1, const float* __restrict__ bias2,
    int split, int nb, void* __restrict__ Cout, int N,
    const float* __restrict__ attn, const float* __restrict__ resid,
    const float* __restrict__ g1, const float* __restrict__ g2) {
  constexpr int K = 768;
  __shared__ u16 sA[128 * 64];
  __shared__ u16 sB[128 * 64];
  const int t = threadIdx.x;
  const int lane = t & 63;
  const int w = t >> 6;
  const int wr = w >> 1, wc = w & 1;
  const int chunk = gridDim.x >> 3;
  const int tile = (blockIdx.x & 7) * chunk + (blockIdx.x >> 3);
  const int tm = tile / NT, tn = tile - tm * NT;
  const size_t m0 = (size_t)tm * 128;
  const int n0 = tn * 128;

  f32x4 acc[4][4] = {};

  for (int kt = 0; kt < K; kt += 64) {
    #pragma unroll
    for (int i = 0; i < 4; ++i) {
      int ci = i * 256 + t;
      int row = ci >> 3, c8 = ci & 7;
      int kc = c8 ^ (row & 7);
      const u16* ga = A + (m0 + row) * K + kt + kc * 8;
      const u16* gb = Wt + ((size_t)n0 + row) * K + kt + kc * 8;
      __builtin_amdgcn_global_load_lds((const __attribute__((address_space(1))) void*)ga,
          (__attribute__((address_space(3))) void*)(sA + ci * 8), 16, 0, 0);
      __builtin_amdgcn_global_load_lds((const __attribute__((address_space(1))) void*)gb,
          (__attribute__((address_space(3))) void*)(sB + ci * 8), 16, 0, 0);
    }
    __syncthreads();
    #pragma unroll
    for (int ks = 0; ks < 2; ++ks) {
      bf16x8 af[4], bfr[4];
      #pragma unroll
      for (int m = 0; m < 4; ++m) {
        int row = wr * 64 + m * 16 + (lane & 15);
        int pc = (ks * 4 + (lane >> 4)) ^ (row & 7);
        af[m] = *(const bf16x8*)(sA + row * 64 + pc * 8);
      }
      #pragma unroll
      for (int n = 0; n < 4; ++n) {
        int row = wc * 64 + n * 16 + (lane & 15);
        int pc = (ks * 4 + (lane >> 4)) ^ (row & 7);
        bfr[n] = *(const bf16x8*)(sB + row * 64 + pc * 8);
      }
      #pragma unroll
      for (int m = 0; m < 4; ++m)
        #pragma unroll
        for (int n = 0; n < 4; ++n)
          acc[m][n] = __builtin_amdgcn_mfma_f32_16x16x32_bf16(af[m], bfr[n], acc[m][n], 0, 0, 0);
    }
    __syncthreads();
  }

  #pragma unroll
  for (int m = 0; m < 4; ++m) {
    #pragma unroll
    for (int n = 0; n < 4; ++n) {
      int col = n0 + wc * 64 + n * 16 + (lane & 15);
      float bv = (col < split) ? bias1[col] : ((col < nb) ? bias2[col - split] : 0.0f);
      #pragma unroll
      for (int r = 0; r < 4; ++r) {
        size_t grow = m0 + (size_t)(wr * 64 + m * 16 + (lane >> 4) * 4 + r);
        float v = acc[m][n][r] + bv;
        size_t idx = grow * (size_t)N + col;
        if constexpr (MODE == MODE_F32) {
          ((float*)Cout)[idx] = v;
        } else if constexpr (MODE == MODE_BF16) {
          ((u16*)Cout)[idx] = f2b(v);
        } else {
          ((float*)Cout)[idx] = resid[idx] + g1[col] * (attn[idx] + g2[col] * v);
        }
      }
    }
  }
}

// ---------------- deformable sampling ----------------
// thread = (query, head, d8); 4 queries/block, 384 threads.
// offa row layout (cross): [512 offsets | 256 attn logits], stride 768.
__global__ __launch_bounds__(384) void samp_c_kernel(const u16* __restrict__ value,
    const float* __restrict__ offa, u16* __restrict__ out) {
  __shared__ float sbuf[3072];
  const int orig = blockIdx.x;
  const int cpx = gridDim.x >> 3;
  const int bq0 = ((orig & 7) * cpx + (orig >> 3)) * 4;
  const int t = threadIdx.x;
  const float4* g4 = (const float4*)(offa + (size_t)bq0 * 768);
  ((float4*)sbuf)[t] = g4[t];
  ((float4*)sbuf)[t + 384] = g4[t + 384];
  __syncthreads();
  if (t < 64) {  // softmax once per (query, head)
    float* sa = sbuf + (t >> 4) * 768 + 512 + (t & 15) * 16;
    float mx = sa[0];
    #pragma unroll
    for (int i = 1; i < 16; ++i) mx = fmaxf(mx, sa[i]);
    float e[16], sum = 0.0f;
    #pragma unroll
    for (int i = 0; i < 16; ++i) { e[i] = __expf(sa[i] - mx); sum += e[i]; }
    float rs = 1.0f / sum;
    #pragma unroll
    for (int i = 0; i < 16; ++i) sa[i] = e[i] * rs;
  }
  __syncthreads();

  const int qi = t / 96, r = t - qi * 96;
  const int h = r / 6, d8 = r - h * 6;
  const int bq = bq0 + qi;
  const int b = bq / 9216, q = bq - b * 9216;
  const float rx = ((q % 96) + 0.5f) * (1.0f / 96.0f);
  const float ry = ((q / 96) + 0.5f) * (1.0f / 96.0f);
  const float* so = sbuf + qi * 768 + h * 32;
  const float* sw = sbuf + qi * 768 + 512 + h * 16;

  float acc[8] = {};
  const int WL[4] = {16, 32, 64, 96};
  const int ST[4] = {0, 256, 1280, 5376};
  #pragma unroll
  for (int l = 0; l < 4; ++l) {
    const int Wd = WL[l];
    const float fW = (float)Wd;
    const float rW = 1.0f / fW;
    const u16* vb = value + ((size_t)b * 14592 + ST[l]) * 768 + h * 48 + d8 * 8;
    #pragma unroll
    for (int p = 0; p < 4; ++p) {
      float ox = so[l * 8 + p * 2];
      float oy = so[l * 8 + p * 2 + 1];
      float px = (rx + ox * rW) * fW - 0.5f;
      float py = (ry + oy * rW) * fW - 0.5f;
      float wgt = sw[l * 4 + p];
      float x0f = floorf(px), y0f = floorf(py);
      float lx = px - x0f, ly = py - y0f;
      int x0 = (int)x0f, y0 = (int)y0f;
      // branchless: clamp address, zero weight when out of bounds
      int xc0 = min(max(x0, 0), Wd - 1), xc1 = min(max(x0 + 1, 0), Wd - 1);
      int yc0 = min(max(y0, 0), Wd - 1), yc1 = min(max(y0 + 1, 0), Wd - 1);
      float wx0 = ((unsigned)x0       < (unsigned)Wd) ? (1.0f - lx) : 0.0f;
      float wx1 = ((unsigned)(x0 + 1) < (unsigned)Wd) ? lx          : 0.0f;
      float wy0 = (((unsigned)y0       < (unsigned)Wd) ? (1.0f - ly) : 0.0f) * wgt;
      float wy1 = (((unsigned)(y0 + 1) < (unsigned)Wd) ? ly          : 0.0f) * wgt;
      uint4 u00 = *(const uint4*)(vb + (size_t)(yc0 * Wd + xc0) * 768);
      uint4 u01 = *(const uint4*)(vb + (size_t)(yc0 * Wd + xc1) * 768);
      uint4 u10 = *(const uint4*)(vb + (size_t)(yc1 * Wd + xc0) * 768);
      uint4 u11 = *(const uint4*)(vb + (size_t)(yc1 * Wd + xc1) * 768);
      fma8u(acc, u00, wx0 * wy0);
      fma8u(acc, u01, wx1 * wy0);
      fma8u(acc, u10, wx0 * wy1);
      fma8u(acc, u11, wx1 * wy1);
    }
  }
  u16x8 o;
  #pragma unroll
  for (int j = 0; j < 8; ++j) o[j] = f2b(acc[j]);
  *(u16x8*)(out + (size_t)bq * 768 + h * 48 + d8 * 8) = o;
}

// offa row layout (self): [128 offsets | 64 logits | 64 pad], stride 256.
__global__ __launch_bounds__(384) void samp_s_kernel(const u16* __restrict__ value,
    const float* __restrict__ offa, u16* __restrict__ out) {
  __shared__ float sbuf[1024];
  const int orig = blockIdx.x;
  const int cpx = gridDim.x >> 3;
  const int bq0 = ((orig & 7) * cpx + (orig >> 3)) * 4;
  const int t = threadIdx.x;
  const float4* g4 = (const float4*)(offa + (size_t)bq0 * 256);
  if (t < 256) ((float4*)sbuf)[t] = g4[t];
  __syncthreads();
  if (t < 64) {
    float* sa = sbuf + (t >> 4) * 256 + 128 + (t & 15) * 4;
    float mx = fmaxf(fmaxf(sa[0], sa[1]), fmaxf(sa[2], sa[3]));
    float e[4], sum = 0.0f;
    #pragma unroll
    for (int i = 0; i < 4; ++i) { e[i] = __expf(sa[i] - mx); sum += e[i]; }
    float rs = 1.0f / sum;
    #pragma unroll
    for (int i = 0; i < 4; ++i) sa[i] = e[i] * rs;
  }
  __syncthreads();

  const int qi = t / 96, r = t - qi * 96;
  const int h = r / 6, d8 = r - h * 6;
  const int bq = bq0 + qi;
  const int b = bq / 9216, q = bq - b * 9216;
  const float rx = ((q % 96) + 0.5f) * (1.0f / 96.0f);
  const float ry = ((q / 96) + 0.5f) * (1.0f / 96.0f);
  const float* so = sbuf + qi * 256 + h * 8;
  const float* sw = sbuf + qi * 256 + 128 + h * 4;

  float acc[8] = {};
  const u16* vb = value + (size_t)b * 9216 * 768 + h * 48 + d8 * 8;
  #pragma unroll
  for (int p = 0; p < 4; ++p) {
    float ox = so[p * 2], oy = so[p * 2 + 1];
    float px = (rx + ox * (1.0f / 96.0f)) * 96.0f - 0.5f;
    float py = (ry + oy * (1.0f / 96.0f)) * 96.0f - 0.5f;
    float wgt = sw[p];
    float x0f = floorf(px), y0f = floorf(py);
    float lx = px - x0f, ly = py - y0f;
    int x0 = (int)x0f, y0 = (int)y0f;
    int xc0 = min(max(x0, 0), 95), xc1 = min(max(x0 + 1, 0), 95);
    int yc0 = min(max(y0, 0), 95), yc1 = min(max(y0 + 1, 0), 95);
    float wx0 = ((unsigned)x0       < 96u) ? (1.0f - lx) : 0.0f;
    float wx1 = ((unsigned)(x0 + 1) < 96u) ? lx          : 0.0f;
    float wy0 = (((unsigned)y0       < 96u) ? (1.0f - ly) : 0.0f) * wgt;
    float wy1 = (((unsigned)(y0 + 1) < 96u) ? ly          : 0.0f) * wgt;
    uint4 u00 = *(const uint4*)(vb + (size_t)(yc0 * 96 + xc0) * 768);
    uint4 u01 = *(const uint4*)(vb + (size_t)(yc0 * 96 + xc1) * 768);
    uint4 u10 = *(const uint4*)(vb + (size_t)(yc1 * 96 + xc0) * 768);
    uint4 u11 = *(const uint4*)(vb + (size_t)(yc1 * 96 + xc1) * 768);
    fma8u(acc, u00, wx0 * wy0);
    fma8u(acc, u01, wx1 * wy0);
    fma8u(acc, u10, wx0 * wy1);
    fma8u(acc, u11, wx1 * wy1);
  }
  u16x8 o;
  #pragma unroll
  for (int j = 0; j < 8; ++j) o[j] = f2b(acc[j]);
  *(u16x8*)(out + (size_t)bq * 768 + h * 48 + d8 * 8) = o;
}

// ---------------- launch ----------------
extern "C" void kernel_launch(void* const* d_in, const int* in_sizes, int n_in,
                              void* d_out, int out_size, void* d_ws, size_t ws_size,
                              hipStream_t stream) {
  (void)in_sizes; (void)n_in; (void)out_size; (void)ws_size;
  const float* src0 = (const float*)d_in[0];
  const float* src1 = (const float*)d_in[1];
  const float* src2 = (const float*)d_in[2];
  const float* src3 = (const float*)d_in[3];
  const float* qn_g = (const float*)d_in[4];
  const float* qn_b = (const float*)d_in[5];
  const float* fn_g = (const float*)d_in[6];
  const float* fn_b = (const float*)d_in[7];
  const float* n1_g = (const float*)d_in[8];
  const float* n1_b = (const float*)d_in[9];
  const float* gamma1 = (const float*)d_in[10];
  const float* gamma2 = (const float*)d_in[11];
  const float* c_Wv  = (const float*)d_in[12]; const float* c_bv   = (const float*)d_in[13];
  const float* c_Woff= (const float*)d_in[14]; const float* c_boff = (const float*)d_in[15];
  const float* c_Wa  = (const float*)d_in[16]; const float* c_ba   = (const float*)d_in[17];
  const float* c_Wo  = (const float*)d_in[18]; const float* c_bo   = (const float*)d_in[19];
  const float* s_Wv  = (const float*)d_in[20]; const float* s_bv   = (const float*)d_in[21];
  const float* s_Woff= (const float*)d_in[22]; const float* s_boff = (const float*)d_in[23];
  const float* s_Wa  = (const float*)d_in[24]; const float* s_ba   = (const float*)d_in[25];
  const float* s_Wo  = (const float*)d_in[26]; const float* s_bo   = (const float*)d_in[27];

  constexpr int Lq = 9216;
  constexpr int Mq = 2 * Lq;      // 18432
  constexpr int Mf = 2 * 14592;   // 29184

  // weights: 4096 rows x 768 bf16, contiguous at ws[0]
  constexpr size_t O_qln   = 8u << 20;
  constexpr size_t O_fln   = O_qln   + (size_t)Mq * 768 * 2;
  constexpr size_t O_valc  = O_fln   + (size_t)Mf * 768 * 2;   // bf16
  constexpr size_t O_offac = O_valc  + (size_t)Mf * 768 * 2;   // f32 [Mq][768]
  constexpr size_t O_sampc = O_qln;                            // reuse
  constexpr size_t O_attn  = O_fln;                            // reuse
  constexpr size_t O_attn1 = O_attn  + (size_t)Mq * 768 * 4;
  constexpr size_t O_vals  = O_attn1 + (size_t)Mq * 768 * 2;   // bf16
  constexpr size_t O_offas = O_vals  + (size_t)Mq * 768 * 2;   // f32 [Mq][256]
  constexpr size_t O_samps = O_offas + (size_t)Mq * 256 * 4;   // bf16

  uint8_t* ws = (uint8_t*)d_ws;
  u16* Wbase = (u16*)ws;
  auto Wrow = [&](int r) { return Wbase + (size_t)r * 768; };
  auto Wp = [&](size_t o) { return (u16*)(ws + o); };
  auto Fp = [&](size_t o) { return (float*)(ws + o); };

  wconv_kernel<<<3072, 256, 0, stream>>>(c_Wv, c_Woff, c_Wa, c_Wo, s_Wv, s_Woff, s_Wa, s_Wo, Wbase);

  ln_rows_kernel<<<Mq, 192, 0, stream>>>(src3, qn_g, qn_b, Wp(O_qln));
  ln_feat_kernel<<<Mf, 192, 0, stream>>>(src0, src1, src2, src3, fn_g, fn_b, Wp(O_fln));

  // value projection (cross): Mf x 768
  gemm_kernel<MODE_BF16, 6><<<(Mf / 128) * 6, 256, 0, stream>>>(
      Wp(O_fln), Wrow(0), c_bv, nullptr, 768, 768, Wp(O_valc), 768,
      nullptr, nullptr, nullptr, nullptr);
  // offsets + attn logits (cross, merged): Mq x 768
  gemm_kernel<MODE_F32, 6><<<(Mq / 128) * 6, 256, 0, stream>>>(
      Wp(O_qln), Wrow(768), c_boff, c_ba, 512, 768, Fp(O_offac), 768,
      nullptr, nullptr, nullptr, nullptr);

  samp_c_kernel<<<Mq / 4, 384, 0, stream>>>(Wp(O_valc), Fp(O_offac), Wp(O_sampc));

  // output proj (cross) -> attn f32
  gemm_kernel<MODE_F32, 6><<<(Mq / 128) * 6, 256, 0, stream>>>(
      Wp(O_sampc), Wrow(1536), c_bo, nullptr, 768, 768, Fp(O_attn), 768,
      nullptr, nullptr, nullptr, nullptr);

  ln_rows_kernel<<<Mq, 192, 0, stream>>>(Fp(O_attn), n1_g, n1_b, Wp(O_attn1));

  // value projection (self)
  gemm_kernel<MODE_BF16, 6><<<(Mq / 128) * 6, 256, 0, stream>>>(
      Wp(O_attn1), Wrow(2304), s_bv, nullptr, 768, 768, Wp(O_vals), 768,
      nullptr, nullptr, nullptr, nullptr);
  // offsets + attn logits (self, merged): Mq x 256
  gemm_kernel<MODE_F32, 2><<<(Mq / 128) * 2, 256, 0, stream>>>(
      Wp(O_attn1), Wrow(3072), s_boff, s_ba, 128, 192, Fp(O_offas), 256,
      nullptr, nullptr, nullptr, nullptr);

  samp_s_kernel<<<Mq / 4, 384, 0, stream>>>(Wp(O_vals), Fp(O_offas), Wp(O_samps));

  // final: out = src3 + g1*(attn + g2*(samp_s @ s_Wo + s_bo))
  gemm_kernel<MODE_FINAL, 6><<<(Mq / 128) * 6, 256, 0, stream>>>(
      Wp(O_samps), Wrow(3328), s_bo, nullptr, 768, 768, (float*)d_out, 768,
      Fp(O_attn), src3, gamma1, gamma2);
}

// Round 4
// 452.710 us; speedup vs baseline: 2.9761x; 1.0774x over previous
//
#include <hip/hip_runtime.h>
#include <stdint.h>

typedef unsigned short u16;
typedef __attribute__((ext_vector_type(8))) __bf16 bf16x8;
typedef __attribute__((ext_vector_type(4))) float f32x4;
typedef __attribute__((ext_vector_type(2))) float f32x2;
typedef __attribute__((ext_vector_type(8))) u16 u16x8;
typedef __attribute__((ext_vector_type(4))) u16 u16x4;

#define DEV __device__ __forceinline__

DEV u16 f2b(float f) {
  union { float f; uint32_t u; } v; v.f = f;
  uint32_t u = v.u;
  return (u16)((u + 0x7fffu + ((u >> 16) & 1u)) >> 16);
}
DEV float b2f(u16 h) {
  union { uint32_t u; float f; } v; v.u = ((uint32_t)h) << 16;
  return v.f;
}
DEV float u2f(uint32_t u) {
  union { uint32_t u; float f; } v; v.u = u;
  return v.f;
}

// packed gather-convert-FMA of 8 bf16 channels (pairs -> f32x2, hope v_pk_fma_f32)
DEV void fma8p(f32x2 acc[4], uint4 v, float w) {
  const uint32_t* pv = (const uint32_t*)&v;
  f32x2 wv = {w, w};
  #pragma unroll
  for (int j = 0; j < 4; ++j) {
    uint32_t u = pv[j];
    f32x2 x = {u2f(u << 16), u2f(u & 0xffff0000u)};
    acc[j] += wv * x;
  }
}

// ---------------- fused weight transpose: 8 regions, tiled 32x32 via LDS ----
__global__ __launch_bounds__(256) void wconv_kernel(
    const float* __restrict__ W0, const float* __restrict__ W1,
    const float* __restrict__ W2, const float* __restrict__ W3,
    const float* __restrict__ W4, const float* __restrict__ W5,
    const float* __restrict__ W6, const float* __restrict__ W7,
    u16* __restrict__ dst) {
  __shared__ float s[32][33];
  int bx = blockIdx.x;            // 0..3071
  int ct = bx / 24;               // column-tile 0..127
  int kt = bx - ct * 24;          // k-tile 0..23
  const float* Wsrc; int N; int rowbase; int c0;
  if (ct < 24)       { Wsrc = W0; N = 768; rowbase = 0;    c0 = ct; }
  else if (ct < 40)  { Wsrc = W1; N = 512; rowbase = 768;  c0 = ct - 24; }
  else if (ct < 48)  { Wsrc = W2; N = 256; rowbase = 1280; c0 = ct - 40; }
  else if (ct < 72)  { Wsrc = W3; N = 768; rowbase = 1536; c0 = ct - 48; }
  else if (ct < 96)  { Wsrc = W4; N = 768; rowbase = 2304; c0 = ct - 72; }
  else if (ct < 100) { Wsrc = W5; N = 128; rowbase = 3072; c0 = ct - 96; }
  else if (ct < 104) { Wsrc = W6; N = 64;  rowbase = 3200; c0 = ct - 100; }
  else               { Wsrc = W7; N = 768; rowbase = 3328; c0 = ct - 104; }
  const int tx = threadIdx.x & 31, ty = threadIdx.x >> 5;
  const int n = c0 * 32 + tx;
  const int k0 = kt * 32;
  #pragma unroll
  for (int j = 0; j < 4; ++j) {
    int k = k0 + ty + j * 8;
    s[ty + j * 8][tx] = (n < N) ? Wsrc[(size_t)k * N + n] : 0.0f;
  }
  __syncthreads();
  #pragma unroll
  for (int j = 0; j < 4; ++j) {
    int nr = c0 * 32 + ty + j * 8;
    dst[(size_t)(rowbase + nr) * 768 + k0 + tx] = f2b(s[tx][ty + j * 8]);
  }
}

// ---------------- layernorm (row of 768), 192 threads, float4 ----------------
DEV void ln_core(float4 v, const float* __restrict__ g, const float* __restrict__ b,
                 u16* __restrict__ o, int t, float* red) {
  float s = v.x + v.y + v.z + v.w;
  float s2 = v.x * v.x + v.y * v.y + v.z * v.z + v.w * v.w;
  #pragma unroll
  for (int m = 1; m < 64; m <<= 1) { s += __shfl_xor(s, m); s2 += __shfl_xor(s2, m); }
  if ((t & 63) == 0) { red[t >> 6] = s; red[3 + (t >> 6)] = s2; }
  __syncthreads();
  float S = red[0] + red[1] + red[2];
  float S2 = red[3] + red[4] + red[5];
  float mean = S * (1.0f / 768.0f);
  float var = S2 * (1.0f / 768.0f) - mean * mean;
  float rstd = rsqrtf(var + 1e-6f);
  float4 gv = ((const float4*)g)[t], bv = ((const float4*)b)[t];
  u16x4 ov;
  ov[0] = f2b((v.x - mean) * rstd * gv.x + bv.x);
  ov[1] = f2b((v.y - mean) * rstd * gv.y + bv.y);
  ov[2] = f2b((v.z - mean) * rstd * gv.z + bv.z);
  ov[3] = f2b((v.w - mean) * rstd * gv.w + bv.w);
  *(u16x4*)(o + t * 4) = ov;
}

__global__ __launch_bounds__(192) void ln_rows_kernel(const float* __restrict__ in,
    const float* __restrict__ g, const float* __restrict__ b, u16* __restrict__ out) {
  __shared__ float red[6];
  size_t row = blockIdx.x;
  int t = threadIdx.x;
  ln_core(((const float4*)(in + row * 768))[t], g, b, out + row * 768, t, red);
}

__global__ __launch_bounds__(192) void ln_rows_b16_kernel(const u16* __restrict__ in,
    const float* __restrict__ g, const float* __restrict__ b, u16* __restrict__ out) {
  __shared__ float red[6];
  size_t row = blockIdx.x;
  int t = threadIdx.x;
  u16x4 r = *(const u16x4*)(in + row * 768 + t * 4);
  float4 v = {b2f(r[0]), b2f(r[1]), b2f(r[2]), b2f(r[3])};
  ln_core(v, g, b, out + row * 768, t, red);
}

__global__ __launch_bounds__(192) void ln_feat_kernel(const float* __restrict__ s0,
    const float* __restrict__ s1, const float* __restrict__ s2, const float* __restrict__ s3,
    const float* __restrict__ g, const float* __restrict__ b, u16* __restrict__ out) {
  __shared__ float red[6];
  int row = blockIdx.x;
  int bb = row / 14592, pos = row - bb * 14592;
  const float* x;
  if (pos < 256)       x = s0 + ((size_t)bb * 256  + pos) * 768;
  else if (pos < 1280) x = s1 + ((size_t)bb * 1024 + (pos - 256)) * 768;
  else if (pos < 5376) x = s2 + ((size_t)bb * 4096 + (pos - 1280)) * 768;
  else                 x = s3 + ((size_t)bb * 9216 + (pos - 5376)) * 768;
  int t = threadIdx.x;
  ln_core(((const float4*)x)[t], g, b, out + (size_t)row * 768, t, red);
}

// ---------------- bf16 MFMA GEMM, XCD-chunked 1D tile map ----------------
enum { MODE_F32 = 0, MODE_BF16 = 1, MODE_FINAL = 2 };

template <int MODE, int NT>
__global__ __launch_bounds__(256) void gemm_kernel(
    const u16* __restrict__ A, const u16* __restrict__ Wt,
    const float* __restrict__ bias1, const float* __restrict__ bias2,
    int split, int nb, void* __restrict__ Cout, int N,
    const u16* __restrict__ attnb, const float* __restrict__ resid,
    const float* __restrict__ g1, const float* __restrict__ g2) {
  constexpr int K = 768;
  __shared__ u16 sA[128 * 64];
  __shared__ u16 sB[128 * 64];
  const int t = threadIdx.x;
  const int lane = t & 63;
  const int w = t >> 6;
  const int wr = w >> 1, wc = w & 1;
  const int chunk = gridDim.x >> 3;
  const int tile = (blockIdx.x & 7) * chunk + (blockIdx.x >> 3);
  const int tm = tile / NT, tn = tile - tm * NT;
  const size_t m0 = (size_t)tm * 128;
  const int n0 = tn * 128;

  f32x4 acc[4][4] = {};

  for (int kt = 0; kt < K; kt += 64) {
    #pragma unroll
    for (int i = 0; i < 4; ++i) {
      int ci = i * 256 + t;
      int row = ci >> 3, c8 = ci & 7;
      int kc = c8 ^ (row & 7);
      const u16* ga = A + (m0 + row) * K + kt + kc * 8;
      const u16* gb = Wt + ((size_t)n0 + row) * K + kt + kc * 8;
      __builtin_amdgcn_global_load_lds((const __attribute__((address_space(1))) void*)ga,
          (__attribute__((address_space(3))) void*)(sA + ci * 8), 16, 0, 0);
      __builtin_amdgcn_global_load_lds((const __attribute__((address_space(1))) void*)gb,
          (__attribute__((address_space(3))) void*)(sB + ci * 8), 16, 0, 0);
    }
    __syncthreads();
    #pragma unroll
    for (int ks = 0; ks < 2; ++ks) {
      bf16x8 af[4], bfr[4];
      #pragma unroll
      for (int m = 0; m < 4; ++m) {
        int row = wr * 64 + m * 16 + (lane & 15);
        int pc = (ks * 4 + (lane >> 4)) ^ (row & 7);
        af[m] = *(const bf16x8*)(sA + row * 64 + pc * 8);
      }
      #pragma unroll
      for (int n = 0; n < 4; ++n) {
        int row = wc * 64 + n * 16 + (lane & 15);
        int pc = (ks * 4 + (lane >> 4)) ^ (row & 7);
        bfr[n] = *(const bf16x8*)(sB + row * 64 + pc * 8);
      }
      #pragma unroll
      for (int m = 0; m < 4; ++m)
        #pragma unroll
        for (int n = 0; n < 4; ++n)
          acc[m][n] = __builtin_amdgcn_mfma_f32_16x16x32_bf16(af[m], bfr[n], acc[m][n], 0, 0, 0);
    }
    __syncthreads();
  }

  #pragma unroll
  for (int m = 0; m < 4; ++m) {
    #pragma unroll
    for (int n = 0; n < 4; ++n) {
      int col = n0 + wc * 64 + n * 16 + (lane & 15);
      float bv = (col < split) ? bias1[col] : ((col < nb) ? bias2[col - split] : 0.0f);
      #pragma unroll
      for (int r = 0; r < 4; ++r) {
        size_t grow = m0 + (size_t)(wr * 64 + m * 16 + (lane >> 4) * 4 + r);
        float v = acc[m][n][r] + bv;
        size_t idx = grow * (size_t)N + col;
        if constexpr (MODE == MODE_F32) {
          ((float*)Cout)[idx] = v;
        } else if constexpr (MODE == MODE_BF16) {
          ((u16*)Cout)[idx] = f2b(v);
        } else {
          ((float*)Cout)[idx] = resid[idx] + g1[col] * (b2f(attnb[idx]) + g2[col] * v);
        }
      }
    }
  }
}

// ---------------- deformable sampling: 2-phase descriptor scheme ----------------
// Phase 1: per (query,head,level) compute per-point corner byte-offsets (absolute
// into value) + premultiplied weights -> LDS descriptors (528B row stride so
// phase-2 b128 reads spread across bank quads).
// Phase 2: per (query,head,d8): 16 points x {2 ds_read_b128, 4 gathers, packed FMA}.
__global__ __launch_bounds__(384, 6) void samp_c_kernel(const u16* __restrict__ value,
    const float* __restrict__ offa, u16* __restrict__ out) {
  __shared__ uint8_t sdesc[4 * 16 * 528];   // 33792 B
  const int orig = blockIdx.x;
  const int cpx = gridDim.x >> 3;
  const int bq0 = ((orig & 7) * cpx + (orig >> 3)) * 4;
  const int t = threadIdx.x;

  if (t < 256) {
    const int qi = t >> 6, h = (t >> 2) & 15, l = t & 3;
    const int bq = bq0 + qi;
    const int b = bq / 9216, q = bq - b * 9216;
    const float* row = offa + (size_t)bq * 768;
    // softmax over this head's 16 logits
    float lg[16];
    #pragma unroll
    for (int j = 0; j < 4; ++j) {
      float4 L = *(const float4*)(row + 512 + h * 16 + j * 4);
      lg[4*j] = L.x; lg[4*j+1] = L.y; lg[4*j+2] = L.z; lg[4*j+3] = L.w;
    }
    float mx = lg[0];
    #pragma unroll
    for (int i = 1; i < 16; ++i) mx = fmaxf(mx, lg[i]);
    float sum = 0.0f;
    #pragma unroll
    for (int i = 0; i < 16; ++i) { lg[i] = __expf(lg[i] - mx); sum += lg[i]; }
    const float rs = 1.0f / sum;

    const int WL[4] = {16, 32, 64, 96};
    const int ST[4] = {0, 256, 1280, 5376};
    const int Wd = WL[l];
    const float fW = (float)Wd;
    const float rx = ((q % 96) + 0.5f) * (1.0f / 96.0f);
    const float ry = ((q / 96) + 0.5f) * (1.0f / 96.0f);
    const int lvlbase = b * 14592 + ST[l];
    float4 o0 = *(const float4*)(row + h * 32 + l * 8);
    float4 o1 = *(const float4*)(row + h * 32 + l * 8 + 4);
    float oxs[4] = {o0.x, o0.z, o1.x, o1.z};
    float oys[4] = {o0.y, o0.w, o1.y, o1.w};
    uint8_t* dpb = sdesc + (qi * 16 + h) * 528 + l * 4 * 32;
    #pragma unroll
    for (int pt = 0; pt < 4; ++pt) {
      float px = rx * fW + oxs[pt] - 0.5f;
      float py = ry * fW + oys[pt] - 0.5f;
      float wgt = lg[l * 4 + pt] * rs;
      float x0f = floorf(px), y0f = floorf(py);
      float lx = px - x0f, ly = py - y0f;
      int x0 = (int)x0f, y0 = (int)y0f;
      int xc0 = min(max(x0, 0), Wd - 1), xc1 = min(max(x0 + 1, 0), Wd - 1);
      int yc0 = min(max(y0, 0), Wd - 1), yc1 = min(max(y0 + 1, 0), Wd - 1);
      float wx0 = ((unsigned)x0       < (unsigned)Wd) ? (1.0f - lx) : 0.0f;
      float wx1 = ((unsigned)(x0 + 1) < (unsigned)Wd) ? lx          : 0.0f;
      float wy0 = (((unsigned)y0       < (unsigned)Wd) ? (1.0f - ly) : 0.0f) * wgt;
      float wy1 = (((unsigned)(y0 + 1) < (unsigned)Wd) ? ly          : 0.0f) * wgt;
      int4 ii;
      ii.x = (lvlbase + yc0 * Wd + xc0) * 1536;
      ii.y = (lvlbase + yc0 * Wd + xc1) * 1536;
      ii.z = (lvlbase + yc1 * Wd + xc0) * 1536;
      ii.w = (lvlbase + yc1 * Wd + xc1) * 1536;
      float4 ww = {wx0 * wy0, wx1 * wy0, wx0 * wy1, wx1 * wy1};
      *(int4*)(dpb + pt * 32) = ii;
      *(float4*)(dpb + pt * 32 + 16) = ww;
    }
  }
  __syncthreads();

  const int qi = t / 96, r = t - qi * 96;
  const int h = r / 6, d8 = r - h * 6;
  const int bq = bq0 + qi;
  const int hd = h * 96 + d8 * 16;
  const uint8_t* vB = (const uint8_t*)value;
  const uint8_t* dp = sdesc + (qi * 16 + h) * 528;

  f32x2 acc[4] = {};
  #pragma unroll
  for (int p = 0; p < 16; ++p) {
    int4 ii = *(const int4*)(dp + p * 32);
    float4 ww = *(const float4*)(dp + p * 32 + 16);
    uint4 u00 = *(const uint4*)(vB + (ii.x + hd));
    uint4 u01 = *(const uint4*)(vB + (ii.y + hd));
    uint4 u10 = *(const uint4*)(vB + (ii.z + hd));
    uint4 u11 = *(const uint4*)(vB + (ii.w + hd));
    fma8p(acc, u00, ww.x);
    fma8p(acc, u01, ww.y);
    fma8p(acc, u10, ww.z);
    fma8p(acc, u11, ww.w);
  }
  u16x8 o;
  #pragma unroll
  for (int j = 0; j < 4; ++j) { o[2*j] = f2b(acc[j][0]); o[2*j+1] = f2b(acc[j][1]); }
  *(u16x8*)(out + (size_t)bq * 768 + h * 48 + d8 * 8) = o;
}

// self-attn sampling: offa row = [128 off | 64 logits | 64 pad], stride 256.
__global__ __launch_bounds__(384, 6) void samp_s_kernel(const u16* __restrict__ value,
    const float* __restrict__ offa, u16* __restrict__ out) {
  __shared__ uint8_t sdesc[4 * 16 * 144];   // 9216 B
  const int orig = blockIdx.x;
  const int cpx = gridDim.x >> 3;
  const int bq0 = ((orig & 7) * cpx + (orig >> 3)) * 4;
  const int t = threadIdx.x;

  if (t < 64) {
    const int qi = t >> 4, h = t & 15;
    const int bq = bq0 + qi;
    const int b = bq / 9216, q = bq - b * 9216;
    const float* row = offa + (size_t)bq * 256;
    float4 L = *(const float4*)(row + 128 + h * 4);
    float lg[4] = {L.x, L.y, L.z, L.w};
    float mx = fmaxf(fmaxf(lg[0], lg[1]), fmaxf(lg[2], lg[3]));
    float sum = 0.0f;
    #pragma unroll
    for (int i = 0; i < 4; ++i) { lg[i] = __expf(lg[i] - mx); sum += lg[i]; }
    const float rs = 1.0f / sum;
    const float rx = ((q % 96) + 0.5f) * (1.0f / 96.0f);
    const float ry = ((q / 96) + 0.5f) * (1.0f / 96.0f);
    const int base = b * 9216;
    float4 o0 = *(const float4*)(row + h * 8);
    float4 o1 = *(const float4*)(row + h * 8 + 4);
    float oxs[4] = {o0.x, o0.z, o1.x, o1.z};
    float oys[4] = {o0.y, o0.w, o1.y, o1.w};
    uint8_t* dpb = sdesc + (qi * 16 + h) * 144;
    #pragma unroll
    for (int pt = 0; pt < 4; ++pt) {
      float px = rx * 96.0f + oxs[pt] - 0.5f;
      float py = ry * 96.0f + oys[pt] - 0.5f;
      float wgt = lg[pt] * rs;
      float x0f = floorf(px), y0f = floorf(py);
      float lx = px - x0f, ly = py - y0f;
      int x0 = (int)x0f, y0 = (int)y0f;
      int xc0 = min(max(x0, 0), 95), xc1 = min(max(x0 + 1, 0), 95);
      int yc0 = min(max(y0, 0), 95), yc1 = min(max(y0 + 1, 0), 95);
      float wx0 = ((unsigned)x0       < 96u) ? (1.0f - lx) : 0.0f;
      float wx1 = ((unsigned)(x0 + 1) < 96u) ? lx          : 0.0f;
      float wy0 = (((unsigned)y0       < 96u) ? (1.0f - ly) : 0.0f) * wgt;
      float wy1 = (((unsigned)(y0 + 1) < 96u) ? ly          : 0.0f) * wgt;
      int4 ii;
      ii.x = (base + yc0 * 96 + xc0) * 1536;
      ii.y = (base + yc0 * 96 + xc1) * 1536;
      ii.z = (base + yc1 * 96 + xc0) * 1536;
      ii.w = (base + yc1 * 96 + xc1) * 1536;
      float4 ww = {wx0 * wy0, wx1 * wy0, wx0 * wy1, wx1 * wy1};
      *(int4*)(dpb + pt * 32) = ii;
      *(float4*)(dpb + pt * 32 + 16) = ww;
    }
  }
  __syncthreads();

  const int qi = t / 96, r = t - qi * 96;
  const int h = r / 6, d8 = r - h * 6;
  const int bq = bq0 + qi;
  const int hd = h * 96 + d8 * 16;
  const uint8_t* vB = (const uint8_t*)value;
  const uint8_t* dp = sdesc + (qi * 16 + h) * 144;

  f32x2 acc[4] = {};
  #pragma unroll
  for (int p = 0; p < 4; ++p) {
    int4 ii = *(const int4*)(dp + p * 32);
    float4 ww = *(const float4*)(dp + p * 32 + 16);
    uint4 u00 = *(const uint4*)(vB + (ii.x + hd));
    uint4 u01 = *(const uint4*)(vB + (ii.y + hd));
    uint4 u10 = *(const uint4*)(vB + (ii.z + hd));
    uint4 u11 = *(const uint4*)(vB + (ii.w + hd));
    fma8p(acc, u00, ww.x);
    fma8p(acc, u01, ww.y);
    fma8p(acc, u10, ww.z);
    fma8p(acc, u11, ww.w);
  }
  u16x8 o;
  #pragma unroll
  for (int j = 0; j < 4; ++j) { o[2*j] = f2b(acc[j][0]); o[2*j+1] = f2b(acc[j][1]); }
  *(u16x8*)(out + (size_t)bq * 768 + h * 48 + d8 * 8) = o;
}

// ---------------- launch ----------------
extern "C" void kernel_launch(void* const* d_in, const int* in_sizes, int n_in,
                              void* d_out, int out_size, void* d_ws, size_t ws_size,
                              hipStream_t stream) {
  (void)in_sizes; (void)n_in; (void)out_size; (void)ws_size;
  const float* src0 = (const float*)d_in[0];
  const float* src1 = (const float*)d_in[1];
  const float* src2 = (const float*)d_in[2];
  const float* src3 = (const float*)d_in[3];
  const float* qn_g = (const float*)d_in[4];
  const float* qn_b = (const float*)d_in[5];
  const float* fn_g = (const float*)d_in[6];
  const float* fn_b = (const float*)d_in[7];
  const float* n1_g = (const float*)d_in[8];
  const float* n1_b = (const float*)d_in[9];
  const float* gamma1 = (const float*)d_in[10];
  const float* gamma2 = (const float*)d_in[11];
  const float* c_Wv  = (const float*)d_in[12]; const float* c_bv   = (const float*)d_in[13];
  const float* c_Woff= (const float*)d_in[14]; const float* c_boff = (const float*)d_in[15];
  const float* c_Wa  = (const float*)d_in[16]; const float* c_ba   = (const float*)d_in[17];
  const float* c_Wo  = (const float*)d_in[18]; const float* c_bo   = (const float*)d_in[19];
  const float* s_Wv  = (const float*)d_in[20]; const float* s_bv   = (const float*)d_in[21];
  const float* s_Woff= (const float*)d_in[22]; const float* s_boff = (const float*)d_in[23];
  const float* s_Wa  = (const float*)d_in[24]; const float* s_ba   = (const float*)d_in[25];
  const float* s_Wo  = (const float*)d_in[26]; const float* s_bo   = (const float*)d_in[27];

  constexpr int Lq = 9216;
  constexpr int Mq = 2 * Lq;      // 18432
  constexpr int Mf = 2 * 14592;   // 29184

  constexpr size_t O_qln   = 8u << 20;
  constexpr size_t O_fln   = O_qln   + (size_t)Mq * 768 * 2;
  constexpr size_t O_valc  = O_fln   + (size_t)Mf * 768 * 2;   // bf16
  constexpr size_t O_offac = O_valc  + (size_t)Mf * 768 * 2;   // f32 [Mq][768]
  constexpr size_t O_sampc = O_qln;                            // reuse
  constexpr size_t O_attn  = O_fln;                            // reuse, bf16
  constexpr size_t O_attn1 = O_attn  + (size_t)Mq * 768 * 2;   // bf16
  constexpr size_t O_vals  = O_attn1 + (size_t)Mq * 768 * 2;   // bf16
  constexpr size_t O_offas = O_vals  + (size_t)Mq * 768 * 2;   // f32 [Mq][256]
  constexpr size_t O_samps = O_offas + (size_t)Mq * 256 * 4;   // bf16

  uint8_t* ws = (uint8_t*)d_ws;
  u16* Wbase = (u16*)ws;
  auto Wrow = [&](int r) { return Wbase + (size_t)r * 768; };
  auto Wp = [&](size_t o) { return (u16*)(ws + o); };
  auto Fp = [&](size_t o) { return (float*)(ws + o); };

  wconv_kernel<<<3072, 256, 0, stream>>>(c_Wv, c_Woff, c_Wa, c_Wo, s_Wv, s_Woff, s_Wa, s_Wo, Wbase);

  ln_rows_kernel<<<Mq, 192, 0, stream>>>(src3, qn_g, qn_b, Wp(O_qln));
  ln_feat_kernel<<<Mf, 192, 0, stream>>>(src0, src1, src2, src3, fn_g, fn_b, Wp(O_fln));

  // value projection (cross): Mf x 768
  gemm_kernel<MODE_BF16, 6><<<(Mf / 128) * 6, 256, 0, stream>>>(
      Wp(O_fln), Wrow(0), c_bv, nullptr, 768, 768, Wp(O_valc), 768,
      nullptr, nullptr, nullptr, nullptr);
  // offsets + attn logits (cross, merged): Mq x 768
  gemm_kernel<MODE_F32, 6><<<(Mq / 128) * 6, 256, 0, stream>>>(
      Wp(O_qln), Wrow(768), c_boff, c_ba, 512, 768, Fp(O_offac), 768,
      nullptr, nullptr, nullptr, nullptr);

  samp_c_kernel<<<Mq / 4, 384, 0, stream>>>(Wp(O_valc), Fp(O_offac), Wp(O_sampc));

  // output proj (cross) -> attn (bf16)
  gemm_kernel<MODE_BF16, 6><<<(Mq / 128) * 6, 256, 0, stream>>>(
      Wp(O_sampc), Wrow(1536), c_bo, nullptr, 768, 768, Wp(O_attn), 768,
      nullptr, nullptr, nullptr, nullptr);

  ln_rows_b16_kernel<<<Mq, 192, 0, stream>>>(Wp(O_attn), n1_g, n1_b, Wp(O_attn1));

  // value projection (self)
  gemm_kernel<MODE_BF16, 6><<<(Mq / 128) * 6, 256, 0, stream>>>(
      Wp(O_attn1), Wrow(2304), s_bv, nullptr, 768, 768, Wp(O_vals), 768,
      nullptr, nullptr, nullptr, nullptr);
  // offsets + attn logits (self, merged): Mq x 256
  gemm_kernel<MODE_F32, 2><<<(Mq / 128) * 2, 256, 0, stream>>>(
      Wp(O_attn1), Wrow(3072), s_boff, s_ba, 128, 192, Fp(O_offas), 256,
      nullptr, nullptr, nullptr, nullptr);

  samp_s_kernel<<<Mq / 4, 384, 0, stream>>>(Wp(O_vals), Fp(O_offas), Wp(O_samps));

  // final: out = src3 + g1*(attn + g2*(samp_s @ s_Wo + s_bo))
  gemm_kernel<MODE_FINAL, 6><<<(Mq / 128) * 6, 256, 0, stream>>>(
      Wp(O_samps), Wrow(3328), s_bo, nullptr, 768, 768, (float*)d_out, 768,
      Wp(O_attn), src3, gamma1, gamma2);
}

// Round 5
// 438.092 us; speedup vs baseline: 3.0754x; 1.0334x over previous
//
#include <hip/hip_runtime.h>
#include <stdint.h>

typedef unsigned short u16;
typedef __attribute__((ext_vector_type(8))) __bf16 bf16x8;
typedef __attribute__((ext_vector_type(4))) float f32x4;
typedef __attribute__((ext_vector_type(2))) float f32x2;
typedef __attribute__((ext_vector_type(8))) u16 u16x8;
typedef __attribute__((ext_vector_type(4))) u16 u16x4;

#define DEV __device__ __forceinline__

DEV u16 f2b(float f) {
  union { float f; uint32_t u; } v; v.f = f;
  uint32_t u = v.u;
  return (u16)((u + 0x7fffu + ((u >> 16) & 1u)) >> 16);
}
DEV float b2f(u16 h) {
  union { uint32_t u; float f; } v; v.u = ((uint32_t)h) << 16;
  return v.f;
}
DEV float u2f(uint32_t u) {
  union { uint32_t u; float f; } v; v.u = u;
  return v.f;
}

// packed gather-convert-FMA of 8 bf16 channels
DEV void fma8p(f32x2 acc[4], uint4 v, float w) {
  const uint32_t* pv = (const uint32_t*)&v;
  f32x2 wv = {w, w};
  #pragma unroll
  for (int j = 0; j < 4; ++j) {
    uint32_t u = pv[j];
    f32x2 x = {u2f(u << 16), u2f(u & 0xffff0000u)};
    acc[j] += wv * x;
  }
}

// ---------------- fused weight transpose: 8 regions, tiled 32x32 via LDS ----
__global__ __launch_bounds__(256) void wconv_kernel(
    const float* __restrict__ W0, const float* __restrict__ W1,
    const float* __restrict__ W2, const float* __restrict__ W3,
    const float* __restrict__ W4, const float* __restrict__ W5,
    const float* __restrict__ W6, const float* __restrict__ W7,
    u16* __restrict__ dst) {
  __shared__ float s[32][33];
  int bx = blockIdx.x;            // 0..3071
  int ct = bx / 24;               // column-tile 0..127
  int kt = bx - ct * 24;          // k-tile 0..23
  const float* Wsrc; int N; int rowbase; int c0;
  if (ct < 24)       { Wsrc = W0; N = 768; rowbase = 0;    c0 = ct; }
  else if (ct < 40)  { Wsrc = W1; N = 512; rowbase = 768;  c0 = ct - 24; }
  else if (ct < 48)  { Wsrc = W2; N = 256; rowbase = 1280; c0 = ct - 40; }
  else if (ct < 72)  { Wsrc = W3; N = 768; rowbase = 1536; c0 = ct - 48; }
  else if (ct < 96)  { Wsrc = W4; N = 768; rowbase = 2304; c0 = ct - 72; }
  else if (ct < 100) { Wsrc = W5; N = 128; rowbase = 3072; c0 = ct - 96; }
  else if (ct < 104) { Wsrc = W6; N = 64;  rowbase = 3200; c0 = ct - 100; }
  else               { Wsrc = W7; N = 768; rowbase = 3328; c0 = ct - 104; }
  const int tx = threadIdx.x & 31, ty = threadIdx.x >> 5;
  const int n = c0 * 32 + tx;
  const int k0 = kt * 32;
  #pragma unroll
  for (int j = 0; j < 4; ++j) {
    int k = k0 + ty + j * 8;
    s[ty + j * 8][tx] = (n < N) ? Wsrc[(size_t)k * N + n] : 0.0f;
  }
  __syncthreads();
  #pragma unroll
  for (int j = 0; j < 4; ++j) {
    int nr = c0 * 32 + ty + j * 8;
    dst[(size_t)(rowbase + nr) * 768 + k0 + tx] = f2b(s[tx][ty + j * 8]);
  }
}

// ---------------- layernorm (row of 768), 192 threads, float4 ----------------
DEV void ln_core(float4 v, const float* __restrict__ g, const float* __restrict__ b,
                 u16* __restrict__ o, int t, float* red) {
  float s = v.x + v.y + v.z + v.w;
  float s2 = v.x * v.x + v.y * v.y + v.z * v.z + v.w * v.w;
  #pragma unroll
  for (int m = 1; m < 64; m <<= 1) { s += __shfl_xor(s, m); s2 += __shfl_xor(s2, m); }
  if ((t & 63) == 0) { red[t >> 6] = s; red[3 + (t >> 6)] = s2; }
  __syncthreads();
  float S = red[0] + red[1] + red[2];
  float S2 = red[3] + red[4] + red[5];
  float mean = S * (1.0f / 768.0f);
  float var = S2 * (1.0f / 768.0f) - mean * mean;
  float rstd = rsqrtf(var + 1e-6f);
  float4 gv = ((const float4*)g)[t], bv = ((const float4*)b)[t];
  u16x4 ov;
  ov[0] = f2b((v.x - mean) * rstd * gv.x + bv.x);
  ov[1] = f2b((v.y - mean) * rstd * gv.y + bv.y);
  ov[2] = f2b((v.z - mean) * rstd * gv.z + bv.z);
  ov[3] = f2b((v.w - mean) * rstd * gv.w + bv.w);
  *(u16x4*)(o + t * 4) = ov;
}

__global__ __launch_bounds__(192) void ln_rows_kernel(const float* __restrict__ in,
    const float* __restrict__ g, const float* __restrict__ b, u16* __restrict__ out) {
  __shared__ float red[6];
  size_t row = blockIdx.x;
  int t = threadIdx.x;
  ln_core(((const float4*)(in + row * 768))[t], g, b, out + row * 768, t, red);
}

__global__ __launch_bounds__(192) void ln_rows_b16_kernel(const u16* __restrict__ in,
    const float* __restrict__ g, const float* __restrict__ b, u16* __restrict__ out) {
  __shared__ float red[6];
  size_t row = blockIdx.x;
  int t = threadIdx.x;
  u16x4 r = *(const u16x4*)(in + row * 768 + t * 4);
  float4 v = {b2f(r[0]), b2f(r[1]), b2f(r[2]), b2f(r[3])};
  ln_core(v, g, b, out + row * 768, t, red);
}

__global__ __launch_bounds__(192) void ln_feat_kernel(const float* __restrict__ s0,
    const float* __restrict__ s1, const float* __restrict__ s2, const float* __restrict__ s3,
    const float* __restrict__ g, const float* __restrict__ b, u16* __restrict__ out) {
  __shared__ float red[6];
  int row = blockIdx.x;
  int bb = row / 14592, pos = row - bb * 14592;
  const float* x;
  if (pos < 256)       x = s0 + ((size_t)bb * 256  + pos) * 768;
  else if (pos < 1280) x = s1 + ((size_t)bb * 1024 + (pos - 256)) * 768;
  else if (pos < 5376) x = s2 + ((size_t)bb * 4096 + (pos - 1280)) * 768;
  else                 x = s3 + ((size_t)bb * 9216 + (pos - 5376)) * 768;
  int t = threadIdx.x;
  ln_core(((const float4*)x)[t], g, b, out + (size_t)row * 768, t, red);
}

// ---------------- bf16 MFMA GEMM, XCD-chunked 1D tile map ----------------
// MODE_BF16T writes C transposed into head-major value layout [b][16][LROW][48].
enum { MODE_F32 = 0, MODE_BF16 = 1, MODE_FINAL = 2, MODE_BF16T = 3 };

template <int MODE, int NT, int LROW = 1>
__global__ __launch_bounds__(256) void gemm_kernel(
    const u16* __restrict__ A, const u16* __restrict__ Wt,
    const float* __restrict__ bias1, const float* __restrict__ bias2,
    int split, int nb, void* __restrict__ Cout, int N,
    const u16* __restrict__ attnb, const float* __restrict__ resid,
    const float* __restrict__ g1, const float* __restrict__ g2) {
  constexpr int K = 768;
  __shared__ u16 sA[128 * 64];
  __shared__ u16 sB[128 * 64];
  const int t = threadIdx.x;
  const int lane = t & 63;
  const int w = t >> 6;
  const int wr = w >> 1, wc = w & 1;
  const int chunk = gridDim.x >> 3;
  const int tile = (blockIdx.x & 7) * chunk + (blockIdx.x >> 3);
  const int tm = tile / NT, tn = tile - tm * NT;
  const size_t m0 = (size_t)tm * 128;
  const int n0 = tn * 128;

  f32x4 acc[4][4] = {};

  for (int kt = 0; kt < K; kt += 64) {
    #pragma unroll
    for (int i = 0; i < 4; ++i) {
      int ci = i * 256 + t;
      int row = ci >> 3, c8 = ci & 7;
      int kc = c8 ^ (row & 7);
      const u16* ga = A + (m0 + row) * K + kt + kc * 8;
      const u16* gb = Wt + ((size_t)n0 + row) * K + kt + kc * 8;
      __builtin_amdgcn_global_load_lds((const __attribute__((address_space(1))) void*)ga,
          (__attribute__((address_space(3))) void*)(sA + ci * 8), 16, 0, 0);
      __builtin_amdgcn_global_load_lds((const __attribute__((address_space(1))) void*)gb,
          (__attribute__((address_space(3))) void*)(sB + ci * 8), 16, 0, 0);
    }
    __syncthreads();
    #pragma unroll
    for (int ks = 0; ks < 2; ++ks) {
      bf16x8 af[4], bfr[4];
      #pragma unroll
      for (int m = 0; m < 4; ++m) {
        int row = wr * 64 + m * 16 + (lane & 15);
        int pc = (ks * 4 + (lane >> 4)) ^ (row & 7);
        af[m] = *(const bf16x8*)(sA + row * 64 + pc * 8);
      }
      #pragma unroll
      for (int n = 0; n < 4; ++n) {
        int row = wc * 64 + n * 16 + (lane & 15);
        int pc = (ks * 4 + (lane >> 4)) ^ (row & 7);
        bfr[n] = *(const bf16x8*)(sB + row * 64 + pc * 8);
      }
      #pragma unroll
      for (int m = 0; m < 4; ++m)
        #pragma unroll
        for (int n = 0; n < 4; ++n)
          acc[m][n] = __builtin_amdgcn_mfma_f32_16x16x32_bf16(af[m], bfr[n], acc[m][n], 0, 0, 0);
    }
    __syncthreads();
  }

  #pragma unroll
  for (int m = 0; m < 4; ++m) {
    #pragma unroll
    for (int n = 0; n < 4; ++n) {
      int col = n0 + wc * 64 + n * 16 + (lane & 15);
      float bv = (col < split) ? bias1[col] : ((col < nb) ? bias2[col - split] : 0.0f);
      #pragma unroll
      for (int r = 0; r < 4; ++r) {
        size_t grow = m0 + (size_t)(wr * 64 + m * 16 + (lane >> 4) * 4 + r);
        float v = acc[m][n][r] + bv;
        if constexpr (MODE == MODE_BF16T) {
          int gi = (int)grow;
          int bb = gi / LROW, pos = gi - bb * LROW;
          int hh = col / 48, dd = col - hh * 48;
          ((u16*)Cout)[(((size_t)bb * 16 + hh) * LROW + pos) * 48 + dd] = f2b(v);
        } else {
          size_t idx = grow * (size_t)N + col;
          if constexpr (MODE == MODE_F32) {
            ((float*)Cout)[idx] = v;
          } else if constexpr (MODE == MODE_BF16) {
            ((u16*)Cout)[idx] = f2b(v);
          } else {
            ((float*)Cout)[idx] = resid[idx] + g1[col] * (b2f(attnb[idx]) + g2[col] * v);
          }
        }
      }
    }
  }
}

// ---------------- deformable sampling: 2-phase descriptor scheme -------------
// value layout: [b][16 heads][LROW][48] bf16 (head-major; corners contiguous).
// Phase 1 (thread = (query,head,level)): corner byte-offsets + premultiplied
// weights -> LDS descriptors. No runtime-indexed arrays (scratch-free).
// Phase 2 (thread = (query,head,d8)): 16 pts x {2 ds_read_b128, 4x16B gather}.
__global__ __launch_bounds__(384, 6) void samp_c_kernel(const u16* __restrict__ value,
    const float* __restrict__ offa, u16* __restrict__ out) {
  __shared__ uint8_t sdesc[4 * 16 * 528];   // 33792 B
  const int orig = blockIdx.x;
  const int cpx = gridDim.x >> 3;
  const int bq0 = ((orig & 7) * cpx + (orig >> 3)) * 4;
  const int t = threadIdx.x;

  if (t < 256) {
    const int qi = t >> 6, h = (t >> 2) & 15, l = t & 3;
    const int bq = bq0 + qi;
    const int b = bq / 9216, q = bq - b * 9216;
    const float* row = offa + (size_t)bq * 768;
    float4 L0 = *(const float4*)(row + 512 + h * 16);
    float4 L1 = *(const float4*)(row + 512 + h * 16 + 4);
    float4 L2 = *(const float4*)(row + 512 + h * 16 + 8);
    float4 L3 = *(const float4*)(row + 512 + h * 16 + 12);
    float mx = fmaxf(fmaxf(fmaxf(fmaxf(L0.x, L0.y), fmaxf(L0.z, L0.w)),
                           fmaxf(fmaxf(L1.x, L1.y), fmaxf(L1.z, L1.w))),
                     fmaxf(fmaxf(fmaxf(L2.x, L2.y), fmaxf(L2.z, L2.w)),
                           fmaxf(fmaxf(L3.x, L3.y), fmaxf(L3.z, L3.w))));
    float sum = __expf(L0.x - mx) + __expf(L0.y - mx) + __expf(L0.z - mx) + __expf(L0.w - mx)
              + __expf(L1.x - mx) + __expf(L1.y - mx) + __expf(L1.z - mx) + __expf(L1.w - mx)
              + __expf(L2.x - mx) + __expf(L2.y - mx) + __expf(L2.z - mx) + __expf(L2.w - mx)
              + __expf(L3.x - mx) + __expf(L3.y - mx) + __expf(L3.z - mx) + __expf(L3.w - mx);
    const float rs = 1.0f / sum;
    float4 Lm = (l == 0) ? L0 : ((l == 1) ? L1 : ((l == 2) ? L2 : L3));

    const int Wd = (l == 3) ? 96 : (16 << l);
    const int STl = (l == 0) ? 0 : ((l == 1) ? 256 : ((l == 2) ? 1280 : 5376));
    const float fW = (float)Wd;
    const float rx = ((q % 96) + 0.5f) * (1.0f / 96.0f);
    const float ry = ((q / 96) + 0.5f) * (1.0f / 96.0f);
    const int headbase = (b * 16 + h) * 14592 + STl;

    float4 o0 = *(const float4*)(row + h * 32 + l * 8);
    float4 o1 = *(const float4*)(row + h * 32 + l * 8 + 4);
    float oxs[4] = {o0.x, o0.z, o1.x, o1.z};
    float oys[4] = {o0.y, o0.w, o1.y, o1.w};
    float wgs[4] = {Lm.x, Lm.y, Lm.z, Lm.w};
    uint8_t* dpb = sdesc + (qi * 16 + h) * 528 + l * 4 * 32;
    #pragma unroll
    for (int pt = 0; pt < 4; ++pt) {
      float px = rx * fW + oxs[pt] - 0.5f;
      float py = ry * fW + oys[pt] - 0.5f;
      float wgt = __expf(wgs[pt] - mx) * rs;
      float x0f = floorf(px), y0f = floorf(py);
      float lx = px - x0f, ly = py - y0f;
      int x0 = (int)x0f, y0 = (int)y0f;
      int xc0 = min(max(x0, 0), Wd - 1), xc1 = min(max(x0 + 1, 0), Wd - 1);
      int yc0 = min(max(y0, 0), Wd - 1), yc1 = min(max(y0 + 1, 0), Wd - 1);
      float wx0 = ((unsigned)x0       < (unsigned)Wd) ? (1.0f - lx) : 0.0f;
      float wx1 = ((unsigned)(x0 + 1) < (unsigned)Wd) ? lx          : 0.0f;
      float wy0 = (((unsigned)y0       < (unsigned)Wd) ? (1.0f - ly) : 0.0f) * wgt;
      float wy1 = (((unsigned)(y0 + 1) < (unsigned)Wd) ? ly          : 0.0f) * wgt;
      int4 ii;
      ii.x = (headbase + yc0 * Wd + xc0) * 96;
      ii.y = (headbase + yc0 * Wd + xc1) * 96;
      ii.z = (headbase + yc1 * Wd + xc0) * 96;
      ii.w = (headbase + yc1 * Wd + xc1) * 96;
      float4 ww = {wx0 * wy0, wx1 * wy0, wx0 * wy1, wx1 * wy1};
      *(int4*)(dpb + pt * 32) = ii;
      *(float4*)(dpb + pt * 32 + 16) = ww;
    }
  }
  __syncthreads();

  const int qi = t / 96, r = t - qi * 96;
  const int h = r / 6, d8 = r - h * 6;
  const int bq = bq0 + qi;
  const int hd = d8 * 16;
  const uint8_t* vB = (const uint8_t*)value;
  const uint8_t* dp = sdesc + (qi * 16 + h) * 528;

  f32x2 acc[4] = {};
  #pragma unroll
  for (int p = 0; p < 16; ++p) {
    int4 ii = *(const int4*)(dp + p * 32);
    float4 ww = *(const float4*)(dp + p * 32 + 16);
    uint4 u00 = *(const uint4*)(vB + (ii.x + hd));
    uint4 u01 = *(const uint4*)(vB + (ii.y + hd));
    uint4 u10 = *(const uint4*)(vB + (ii.z + hd));
    uint4 u11 = *(const uint4*)(vB + (ii.w + hd));
    fma8p(acc, u00, ww.x);
    fma8p(acc, u01, ww.y);
    fma8p(acc, u10, ww.z);
    fma8p(acc, u11, ww.w);
  }
  u16x8 o;
  #pragma unroll
  for (int j = 0; j < 4; ++j) { o[2*j] = f2b(acc[j][0]); o[2*j+1] = f2b(acc[j][1]); }
  *(u16x8*)(out + (size_t)bq * 768 + h * 48 + d8 * 8) = o;
}

// self-attn sampling: offa row = [128 off | 64 logits | 64 pad], stride 256.
// value layout: [b][16][9216][48].
__global__ __launch_bounds__(384, 6) void samp_s_kernel(const u16* __restrict__ value,
    const float* __restrict__ offa, u16* __restrict__ out) {
  __shared__ uint8_t sdesc[4 * 16 * 144];   // 9216 B
  const int orig = blockIdx.x;
  const int cpx = gridDim.x >> 3;
  const int bq0 = ((orig & 7) * cpx + (orig >> 3)) * 4;
  const int t = threadIdx.x;

  if (t < 64) {
    const int qi = t >> 4, h = t & 15;
    const int bq = bq0 + qi;
    const int b = bq / 9216, q = bq - b * 9216;
    const float* row = offa + (size_t)bq * 256;
    float4 L = *(const float4*)(row + 128 + h * 4);
    float mx = fmaxf(fmaxf(L.x, L.y), fmaxf(L.z, L.w));
    float sum = __expf(L.x - mx) + __expf(L.y - mx) + __expf(L.z - mx) + __expf(L.w - mx);
    const float rs = 1.0f / sum;
    const float rx = ((q % 96) + 0.5f) * (1.0f / 96.0f);
    const float ry = ((q / 96) + 0.5f) * (1.0f / 96.0f);
    const int headbase = (b * 16 + h) * 9216;
    float4 o0 = *(const float4*)(row + h * 8);
    float4 o1 = *(const float4*)(row + h * 8 + 4);
    float oxs[4] = {o0.x, o0.z, o1.x, o1.z};
    float oys[4] = {o0.y, o0.w, o1.y, o1.w};
    float wgs[4] = {L.x, L.y, L.z, L.w};
    uint8_t* dpb = sdesc + (qi * 16 + h) * 144;
    #pragma unroll
    for (int pt = 0; pt < 4; ++pt) {
      float px = rx * 96.0f + oxs[pt] - 0.5f;
      float py = ry * 96.0f + oys[pt] - 0.5f;
      float wgt = __expf(wgs[pt] - mx) * rs;
      float x0f = floorf(px), y0f = floorf(py);
      float lx = px - x0f, ly = py - y0f;
      int x0 = (int)x0f, y0 = (int)y0f;
      int xc0 = min(max(x0, 0), 95), xc1 = min(max(x0 + 1, 0), 95);
      int yc0 = min(max(y0, 0), 95), yc1 = min(max(y0 + 1, 0), 95);
      float wx0 = ((unsigned)x0       < 96u) ? (1.0f - lx) : 0.0f;
      float wx1 = ((unsigned)(x0 + 1) < 96u) ? lx          : 0.0f;
      float wy0 = (((unsigned)y0       < 96u) ? (1.0f - ly) : 0.0f) * wgt;
      float wy1 = (((unsigned)(y0 + 1) < 96u) ? ly          : 0.0f) * wgt;
      int4 ii;
      ii.x = (headbase + yc0 * 96 + xc0) * 96;
      ii.y = (headbase + yc0 * 96 + xc1) * 96;
      ii.z = (headbase + yc1 * 96 + xc0) * 96;
      ii.w = (headbase + yc1 * 96 + xc1) * 96;
      float4 ww = {wx0 * wy0, wx1 * wy0, wx0 * wy1, wx1 * wy1};
      *(int4*)(dpb + pt * 32) = ii;
      *(float4*)(dpb + pt * 32 + 16) = ww;
    }
  }
  __syncthreads();

  const int qi = t / 96, r = t - qi * 96;
  const int h = r / 6, d8 = r - h * 6;
  const int bq = bq0 + qi;
  const int hd = d8 * 16;
  const uint8_t* vB = (const uint8_t*)value;
  const uint8_t* dp = sdesc + (qi * 16 + h) * 144;

  f32x2 acc[4] = {};
  #pragma unroll
  for (int p = 0; p < 4; ++p) {
    int4 ii = *(const int4*)(dp + p * 32);
    float4 ww = *(const float4*)(dp + p * 32 + 16);
    uint4 u00 = *(const uint4*)(vB + (ii.x + hd));
    uint4 u01 = *(const uint4*)(vB + (ii.y + hd));
    uint4 u10 = *(const uint4*)(vB + (ii.z + hd));
    uint4 u11 = *(const uint4*)(vB + (ii.w + hd));
    fma8p(acc, u00, ww.x);
    fma8p(acc, u01, ww.y);
    fma8p(acc, u10, ww.z);
    fma8p(acc, u11, ww.w);
  }
  u16x8 o;
  #pragma unroll
  for (int j = 0; j < 4; ++j) { o[2*j] = f2b(acc[j][0]); o[2*j+1] = f2b(acc[j][1]); }
  *(u16x8*)(out + (size_t)bq * 768 + h * 48 + d8 * 8) = o;
}

// ---------------- launch ----------------
extern "C" void kernel_launch(void* const* d_in, const int* in_sizes, int n_in,
                              void* d_out, int out_size, void* d_ws, size_t ws_size,
                              hipStream_t stream) {
  (void)in_sizes; (void)n_in; (void)out_size; (void)ws_size;
  const float* src0 = (const float*)d_in[0];
  const float* src1 = (const float*)d_in[1];
  const float* src2 = (const float*)d_in[2];
  const float* src3 = (const float*)d_in[3];
  const float* qn_g = (const float*)d_in[4];
  const float* qn_b = (const float*)d_in[5];
  const float* fn_g = (const float*)d_in[6];
  const float* fn_b = (const float*)d_in[7];
  const float* n1_g = (const float*)d_in[8];
  const float* n1_b = (const float*)d_in[9];
  const float* gamma1 = (const float*)d_in[10];
  const float* gamma2 = (const float*)d_in[11];
  const float* c_Wv  = (const float*)d_in[12]; const float* c_bv   = (const float*)d_in[13];
  const float* c_Woff= (const float*)d_in[14]; const float* c_boff = (const float*)d_in[15];
  const float* c_Wa  = (const float*)d_in[16]; const float* c_ba   = (const float*)d_in[17];
  const float* c_Wo  = (const float*)d_in[18]; const float* c_bo   = (const float*)d_in[19];
  const float* s_Wv  = (const float*)d_in[20]; const float* s_bv   = (const float*)d_in[21];
  const float* s_Woff= (const float*)d_in[22]; const float* s_boff = (const float*)d_in[23];
  const float* s_Wa  = (const float*)d_in[24]; const float* s_ba   = (const float*)d_in[25];
  const float* s_Wo  = (const float*)d_in[26]; const float* s_bo   = (const float*)d_in[27];

  constexpr int Lq = 9216;
  constexpr int Mq = 2 * Lq;      // 18432
  constexpr int Mf = 2 * 14592;   // 29184

  constexpr size_t O_qln   = 8u << 20;
  constexpr size_t O_fln   = O_qln   + (size_t)Mq * 768 * 2;
  constexpr size_t O_valc  = O_fln   + (size_t)Mf * 768 * 2;   // bf16, head-major
  constexpr size_t O_offac = O_valc  + (size_t)Mf * 768 * 2;   // f32 [Mq][768]
  constexpr size_t O_sampc = O_qln;                            // reuse
  constexpr size_t O_attn  = O_fln;                            // reuse, bf16
  constexpr size_t O_attn1 = O_attn  + (size_t)Mq * 768 * 2;   // bf16
  constexpr size_t O_vals  = O_attn1 + (size_t)Mq * 768 * 2;   // bf16, head-major
  constexpr size_t O_offas = O_vals  + (size_t)Mq * 768 * 2;   // f32 [Mq][256]
  constexpr size_t O_samps = O_offas + (size_t)Mq * 256 * 4;   // bf16

  uint8_t* ws = (uint8_t*)d_ws;
  u16* Wbase = (u16*)ws;
  auto Wrow = [&](int r) { return Wbase + (size_t)r * 768; };
  auto Wp = [&](size_t o) { return (u16*)(ws + o); };
  auto Fp = [&](size_t o) { return (float*)(ws + o); };

  wconv_kernel<<<3072, 256, 0, stream>>>(c_Wv, c_Woff, c_Wa, c_Wo, s_Wv, s_Woff, s_Wa, s_Wo, Wbase);

  ln_rows_kernel<<<Mq, 192, 0, stream>>>(src3, qn_g, qn_b, Wp(O_qln));
  ln_feat_kernel<<<Mf, 192, 0, stream>>>(src0, src1, src2, src3, fn_g, fn_b, Wp(O_fln));

  // value projection (cross): Mf x 768 -> head-major [b][16][14592][48]
  gemm_kernel<MODE_BF16T, 6, 14592><<<(Mf / 128) * 6, 256, 0, stream>>>(
      Wp(O_fln), Wrow(0), c_bv, nullptr, 768, 768, Wp(O_valc), 768,
      nullptr, nullptr, nullptr, nullptr);
  // offsets + attn logits (cross, merged): Mq x 768 f32
  gemm_kernel<MODE_F32, 6><<<(Mq / 128) * 6, 256, 0, stream>>>(
      Wp(O_qln), Wrow(768), c_boff, c_ba, 512, 768, Fp(O_offac), 768,
      nullptr, nullptr, nullptr, nullptr);

  samp_c_kernel<<<Mq / 4, 384, 0, stream>>>(Wp(O_valc), Fp(O_offac), Wp(O_sampc));

  // output proj (cross) -> attn (bf16)
  gemm_kernel<MODE_BF16, 6><<<(Mq / 128) * 6, 256, 0, stream>>>(
      Wp(O_sampc), Wrow(1536), c_bo, nullptr, 768, 768, Wp(O_attn), 768,
      nullptr, nullptr, nullptr, nullptr);

  ln_rows_b16_kernel<<<Mq, 192, 0, stream>>>(Wp(O_attn), n1_g, n1_b, Wp(O_attn1));

  // value projection (self) -> head-major [b][16][9216][48]
  gemm_kernel<MODE_BF16T, 6, 9216><<<(Mq / 128) * 6, 256, 0, stream>>>(
      Wp(O_attn1), Wrow(2304), s_bv, nullptr, 768, 768, Wp(O_vals), 768,
      nullptr, nullptr, nullptr, nullptr);
  // offsets + attn logits (self, merged): Mq x 256 f32
  gemm_kernel<MODE_F32, 2><<<(Mq / 128) * 2, 256, 0, stream>>>(
      Wp(O_attn1), Wrow(3072), s_boff, s_ba, 128, 192, Fp(O_offas), 256,
      nullptr, nullptr, nullptr, nullptr);

  samp_s_kernel<<<Mq / 4, 384, 0, stream>>>(Wp(O_vals), Fp(O_offas), Wp(O_samps));

  // final: out = src3 + g1*(attn + g2*(samp_s @ s_Wo + s_bo))
  gemm_kernel<MODE_FINAL, 6><<<(Mq / 128) * 6, 256, 0, stream>>>(
      Wp(O_samps), Wrow(3328), s_bo, nullptr, 768, 768, (float*)d_out, 768,
      Wp(O_attn), src3, gamma1, gamma2);
}

// Round 6
// 435.447 us; speedup vs baseline: 3.0941x; 1.0061x over previous
//
#include <hip/hip_runtime.h>
#include <stdint.h>

typedef unsigned short u16;
typedef __attribute__((ext_vector_type(8))) __bf16 bf16x8;
typedef __attribute__((ext_vector_type(4))) float f32x4;
typedef __attribute__((ext_vector_type(2))) float f32x2;
typedef __attribute__((ext_vector_type(8))) u16 u16x8;
typedef __attribute__((ext_vector_type(4))) u16 u16x4;

#define DEV __device__ __forceinline__

DEV u16 f2b(float f) {
  union { float f; uint32_t u; } v; v.f = f;
  uint32_t u = v.u;
  return (u16)((u + 0x7fffu + ((u >> 16) & 1u)) >> 16);
}
DEV float b2f(u16 h) {
  union { uint32_t u; float f; } v; v.u = ((uint32_t)h) << 16;
  return v.f;
}
DEV float u2f(uint32_t u) {
  union { uint32_t u; float f; } v; v.u = u;
  return v.f;
}

// packed gather-convert-FMA of 8 bf16 channels
DEV void fma8p(f32x2* acc, uint4 v, float w) {
  const uint32_t* pv = (const uint32_t*)&v;
  f32x2 wv = {w, w};
  #pragma unroll
  for (int j = 0; j < 4; ++j) {
    uint32_t u = pv[j];
    f32x2 x = {u2f(u << 16), u2f(u & 0xffff0000u)};
    acc[j] += wv * x;
  }
}

// ---------------- fused weight transpose: 8 regions, tiled 32x32 via LDS ----
__global__ __launch_bounds__(256) void wconv_kernel(
    const float* __restrict__ W0, const float* __restrict__ W1,
    const float* __restrict__ W2, const float* __restrict__ W3,
    const float* __restrict__ W4, const float* __restrict__ W5,
    const float* __restrict__ W6, const float* __restrict__ W7,
    u16* __restrict__ dst) {
  __shared__ float s[32][33];
  int bx = blockIdx.x;            // 0..3071
  int ct = bx / 24;               // column-tile 0..127
  int kt = bx - ct * 24;          // k-tile 0..23
  const float* Wsrc; int N; int rowbase; int c0;
  if (ct < 24)       { Wsrc = W0; N = 768; rowbase = 0;    c0 = ct; }
  else if (ct < 40)  { Wsrc = W1; N = 512; rowbase = 768;  c0 = ct - 24; }
  else if (ct < 48)  { Wsrc = W2; N = 256; rowbase = 1280; c0 = ct - 40; }
  else if (ct < 72)  { Wsrc = W3; N = 768; rowbase = 1536; c0 = ct - 48; }
  else if (ct < 96)  { Wsrc = W4; N = 768; rowbase = 2304; c0 = ct - 72; }
  else if (ct < 100) { Wsrc = W5; N = 128; rowbase = 3072; c0 = ct - 96; }
  else if (ct < 104) { Wsrc = W6; N = 64;  rowbase = 3200; c0 = ct - 100; }
  else               { Wsrc = W7; N = 768; rowbase = 3328; c0 = ct - 104; }
  const int tx = threadIdx.x & 31, ty = threadIdx.x >> 5;
  const int n = c0 * 32 + tx;
  const int k0 = kt * 32;
  #pragma unroll
  for (int j = 0; j < 4; ++j) {
    int k = k0 + ty + j * 8;
    s[ty + j * 8][tx] = (n < N) ? Wsrc[(size_t)k * N + n] : 0.0f;
  }
  __syncthreads();
  #pragma unroll
  for (int j = 0; j < 4; ++j) {
    int nr = c0 * 32 + ty + j * 8;
    dst[(size_t)(rowbase + nr) * 768 + k0 + tx] = f2b(s[tx][ty + j * 8]);
  }
}

// ---------------- layernorm (row of 768), 192 threads, float4 ----------------
DEV void ln_core(float4 v, const float* __restrict__ g, const float* __restrict__ b,
                 u16* __restrict__ o, int t, float* red) {
  float s = v.x + v.y + v.z + v.w;
  float s2 = v.x * v.x + v.y * v.y + v.z * v.z + v.w * v.w;
  #pragma unroll
  for (int m = 1; m < 64; m <<= 1) { s += __shfl_xor(s, m); s2 += __shfl_xor(s2, m); }
  if ((t & 63) == 0) { red[t >> 6] = s; red[3 + (t >> 6)] = s2; }
  __syncthreads();
  float S = red[0] + red[1] + red[2];
  float S2 = red[3] + red[4] + red[5];
  float mean = S * (1.0f / 768.0f);
  float var = S2 * (1.0f / 768.0f) - mean * mean;
  float rstd = rsqrtf(var + 1e-6f);
  float4 gv = ((const float4*)g)[t], bv = ((const float4*)b)[t];
  u16x4 ov;
  ov[0] = f2b((v.x - mean) * rstd * gv.x + bv.x);
  ov[1] = f2b((v.y - mean) * rstd * gv.y + bv.y);
  ov[2] = f2b((v.z - mean) * rstd * gv.z + bv.z);
  ov[3] = f2b((v.w - mean) * rstd * gv.w + bv.w);
  *(u16x4*)(o + t * 4) = ov;
}

__global__ __launch_bounds__(192) void ln_rows_kernel(const float* __restrict__ in,
    const float* __restrict__ g, const float* __restrict__ b, u16* __restrict__ out) {
  __shared__ float red[6];
  size_t row = blockIdx.x;
  int t = threadIdx.x;
  ln_core(((const float4*)(in + row * 768))[t], g, b, out + row * 768, t, red);
}

__global__ __launch_bounds__(192) void ln_rows_b16_kernel(const u16* __restrict__ in,
    const float* __restrict__ g, const float* __restrict__ b, u16* __restrict__ out) {
  __shared__ float red[6];
  size_t row = blockIdx.x;
  int t = threadIdx.x;
  u16x4 r = *(const u16x4*)(in + row * 768 + t * 4);
  float4 v = {b2f(r[0]), b2f(r[1]), b2f(r[2]), b2f(r[3])};
  ln_core(v, g, b, out + row * 768, t, red);
}

__global__ __launch_bounds__(192) void ln_feat_kernel(const float* __restrict__ s0,
    const float* __restrict__ s1, const float* __restrict__ s2, const float* __restrict__ s3,
    const float* __restrict__ g, const float* __restrict__ b, u16* __restrict__ out) {
  __shared__ float red[6];
  int row = blockIdx.x;
  int bb = row / 14592, pos = row - bb * 14592;
  const float* x;
  if (pos < 256)       x = s0 + ((size_t)bb * 256  + pos) * 768;
  else if (pos < 1280) x = s1 + ((size_t)bb * 1024 + (pos - 256)) * 768;
  else if (pos < 5376) x = s2 + ((size_t)bb * 4096 + (pos - 1280)) * 768;
  else                 x = s3 + ((size_t)bb * 9216 + (pos - 5376)) * 768;
  int t = threadIdx.x;
  ln_core(((const float4*)x)[t], g, b, out + (size_t)row * 768, t, red);
}

// ---------------- bf16 MFMA GEMM, XCD-chunked 1D tile map ----------------
// MODE_BF16T writes C transposed into head-major value layout [b][16][LROW][48].
// bf16 outputs go through an LDS pack (stride 136 u16) -> 16B vector stores.
enum { MODE_F32 = 0, MODE_BF16 = 1, MODE_FINAL = 2, MODE_BF16T = 3 };

template <int MODE, int NT, int LROW = 1>
__global__ __launch_bounds__(256) void gemm_kernel(
    const u16* __restrict__ A, const u16* __restrict__ Wt,
    const float* __restrict__ bias1, const float* __restrict__ bias2,
    int split, int nb, void* __restrict__ Cout, int N,
    const u16* __restrict__ attnb, const float* __restrict__ resid,
    const float* __restrict__ g1, const float* __restrict__ g2) {
  constexpr int K = 768;
  __shared__ u16 smem[128 * 136];   // staging (2x 128x64) + C-pack reuse
  u16* sA = smem;
  u16* sB = smem + 128 * 64;
  const int t = threadIdx.x;
  const int lane = t & 63;
  const int w = t >> 6;
  const int wr = w >> 1, wc = w & 1;
  const int chunk = gridDim.x >> 3;
  const int tile = (blockIdx.x & 7) * chunk + (blockIdx.x >> 3);
  const int tm = tile / NT, tn = tile - tm * NT;
  const size_t m0 = (size_t)tm * 128;
  const int n0 = tn * 128;

  f32x4 acc[4][4] = {};

  for (int kt = 0; kt < K; kt += 64) {
    #pragma unroll
    for (int i = 0; i < 4; ++i) {
      int ci = i * 256 + t;
      int row = ci >> 3, c8 = ci & 7;
      int kc = c8 ^ (row & 7);
      const u16* ga = A + (m0 + row) * K + kt + kc * 8;
      const u16* gb = Wt + ((size_t)n0 + row) * K + kt + kc * 8;
      __builtin_amdgcn_global_load_lds((const __attribute__((address_space(1))) void*)ga,
          (__attribute__((address_space(3))) void*)(sA + ci * 8), 16, 0, 0);
      __builtin_amdgcn_global_load_lds((const __attribute__((address_space(1))) void*)gb,
          (__attribute__((address_space(3))) void*)(sB + ci * 8), 16, 0, 0);
    }
    __syncthreads();
    #pragma unroll
    for (int ks = 0; ks < 2; ++ks) {
      bf16x8 af[4], bfr[4];
      #pragma unroll
      for (int m = 0; m < 4; ++m) {
        int row = wr * 64 + m * 16 + (lane & 15);
        int pc = (ks * 4 + (lane >> 4)) ^ (row & 7);
        af[m] = *(const bf16x8*)(sA + row * 64 + pc * 8);
      }
      #pragma unroll
      for (int n = 0; n < 4; ++n) {
        int row = wc * 64 + n * 16 + (lane & 15);
        int pc = (ks * 4 + (lane >> 4)) ^ (row & 7);
        bfr[n] = *(const bf16x8*)(sB + row * 64 + pc * 8);
      }
      #pragma unroll
      for (int m = 0; m < 4; ++m)
        #pragma unroll
        for (int n = 0; n < 4; ++n)
          acc[m][n] = __builtin_amdgcn_mfma_f32_16x16x32_bf16(af[m], bfr[n], acc[m][n], 0, 0, 0);
    }
    __syncthreads();
  }

  if constexpr (MODE == MODE_BF16 || MODE == MODE_BF16T) {
    // pack into LDS (u16, row stride 136 -> conflict-free writes, aligned reads)
    #pragma unroll
    for (int m = 0; m < 4; ++m) {
      #pragma unroll
      for (int n = 0; n < 4; ++n) {
        int lcol = wc * 64 + n * 16 + (lane & 15);
        int gcol = n0 + lcol;
        float bv = (gcol < split) ? bias1[gcol] : ((gcol < nb) ? bias2[gcol - split] : 0.0f);
        #pragma unroll
        for (int r = 0; r < 4; ++r) {
          int lrow = wr * 64 + m * 16 + (lane >> 4) * 4 + r;
          smem[lrow * 136 + lcol] = f2b(acc[m][n][r] + bv);
        }
      }
    }
    __syncthreads();
    #pragma unroll
    for (int i = 0; i < 8; ++i) {
      int c = t + 256 * i;                 // 0..2047
      int lrow = c >> 4, col8 = (c & 15) * 8;
      u16x8 vv = *(const u16x8*)(smem + lrow * 136 + col8);
      int gcol = n0 + col8;
      size_t grow = m0 + (size_t)lrow;
      if constexpr (MODE == MODE_BF16T) {
        int gi = (int)grow;
        int bb = gi / LROW, pos = gi - bb * LROW;
        int hh = gcol / 48, dd = gcol - hh * 48;
        *(u16x8*)((u16*)Cout + (((size_t)bb * 16 + hh) * LROW + pos) * 48 + dd) = vv;
      } else {
        *(u16x8*)((u16*)Cout + grow * (size_t)N + gcol) = vv;
      }
    }
  } else {
    #pragma unroll
    for (int m = 0; m < 4; ++m) {
      #pragma unroll
      for (int n = 0; n < 4; ++n) {
        int col = n0 + wc * 64 + n * 16 + (lane & 15);
        float bv = (col < split) ? bias1[col] : ((col < nb) ? bias2[col - split] : 0.0f);
        #pragma unroll
        for (int r = 0; r < 4; ++r) {
          size_t grow = m0 + (size_t)(wr * 64 + m * 16 + (lane >> 4) * 4 + r);
          float v = acc[m][n][r] + bv;
          size_t idx = grow * (size_t)N + col;
          if constexpr (MODE == MODE_F32) {
            ((float*)Cout)[idx] = v;
          } else {
            ((float*)Cout)[idx] = resid[idx] + g1[col] * (b2f(attnb[idx]) + g2[col] * v);
          }
        }
      }
    }
  }
}

// ---------------- deformable sampling: 2-phase descriptor scheme -------------
// value layout: [b][16 heads][LROW][48] bf16 (head-major; corners contiguous).
// Phase 1 (thread = (q,h,l)): corner byte-offsets + premultiplied weights ->
// LDS descriptors, slot = pt*4+l (interleave puts l in the bank index).
// Phase 2 (thread = (q,h,d8)): 16 slots, 2-deep software-pipelined gathers,
// dual accumulator banks.
__global__ __launch_bounds__(384, 4) void samp_c_kernel(const u16* __restrict__ value,
    const float* __restrict__ offa, u16* __restrict__ out) {
  __shared__ uint8_t sdesc[4 * 16 * 528];   // 33792 B
  const int orig = blockIdx.x;
  const int cpx = gridDim.x >> 3;
  const int bq0 = ((orig & 7) * cpx + (orig >> 3)) * 4;
  const int t = threadIdx.x;

  if (t < 256) {
    const int qi = t >> 6, h = (t >> 2) & 15, l = t & 3;
    const int bq = bq0 + qi;
    const int b = bq / 9216, q = bq - b * 9216;
    const float* row = offa + (size_t)bq * 768;
    float4 L0 = *(const float4*)(row + 512 + h * 16);
    float4 L1 = *(const float4*)(row + 512 + h * 16 + 4);
    float4 L2 = *(const float4*)(row + 512 + h * 16 + 8);
    float4 L3 = *(const float4*)(row + 512 + h * 16 + 12);
    float mx = fmaxf(fmaxf(fmaxf(fmaxf(L0.x, L0.y), fmaxf(L0.z, L0.w)),
                           fmaxf(fmaxf(L1.x, L1.y), fmaxf(L1.z, L1.w))),
                     fmaxf(fmaxf(fmaxf(L2.x, L2.y), fmaxf(L2.z, L2.w)),
                           fmaxf(fmaxf(L3.x, L3.y), fmaxf(L3.z, L3.w))));
    float sum = __expf(L0.x - mx) + __expf(L0.y - mx) + __expf(L0.z - mx) + __expf(L0.w - mx)
              + __expf(L1.x - mx) + __expf(L1.y - mx) + __expf(L1.z - mx) + __expf(L1.w - mx)
              + __expf(L2.x - mx) + __expf(L2.y - mx) + __expf(L2.z - mx) + __expf(L2.w - mx)
              + __expf(L3.x - mx) + __expf(L3.y - mx) + __expf(L3.z - mx) + __expf(L3.w - mx);
    const float rs = 1.0f / sum;
    float4 Lm = (l == 0) ? L0 : ((l == 1) ? L1 : ((l == 2) ? L2 : L3));

    const int Wd = (l == 3) ? 96 : (16 << l);
    const int STl = (l == 0) ? 0 : ((l == 1) ? 256 : ((l == 2) ? 1280 : 5376));
    const float fW = (float)Wd;
    const float rx = ((q % 96) + 0.5f) * (1.0f / 96.0f);
    const float ry = ((q / 96) + 0.5f) * (1.0f / 96.0f);
    const int headbase = (b * 16 + h) * 14592 + STl;

    float4 o0 = *(const float4*)(row + h * 32 + l * 8);
    float4 o1 = *(const float4*)(row + h * 32 + l * 8 + 4);
    float oxs[4] = {o0.x, o0.z, o1.x, o1.z};
    float oys[4] = {o0.y, o0.w, o1.y, o1.w};
    float wgs[4] = {Lm.x, Lm.y, Lm.z, Lm.w};
    uint8_t* dpb = sdesc + (qi * 16 + h) * 528 + l * 32;   // slot = pt*4 + l
    #pragma unroll
    for (int pt = 0; pt < 4; ++pt) {
      float px = rx * fW + oxs[pt] - 0.5f;
      float py = ry * fW + oys[pt] - 0.5f;
      float wgt = __expf(wgs[pt] - mx) * rs;
      float x0f = floorf(px), y0f = floorf(py);
      float lx = px - x0f, ly = py - y0f;
      int x0 = (int)x0f, y0 = (int)y0f;
      int xc0 = min(max(x0, 0), Wd - 1), xc1 = min(max(x0 + 1, 0), Wd - 1);
      int yc0 = min(max(y0, 0), Wd - 1), yc1 = min(max(y0 + 1, 0), Wd - 1);
      float wx0 = ((unsigned)x0       < (unsigned)Wd) ? (1.0f - lx) : 0.0f;
      float wx1 = ((unsigned)(x0 + 1) < (unsigned)Wd) ? lx          : 0.0f;
      float wy0 = (((unsigned)y0       < (unsigned)Wd) ? (1.0f - ly) : 0.0f) * wgt;
      float wy1 = (((unsigned)(y0 + 1) < (unsigned)Wd) ? ly          : 0.0f) * wgt;
      int4 ii;
      ii.x = (headbase + yc0 * Wd + xc0) * 96;
      ii.y = (headbase + yc0 * Wd + xc1) * 96;
      ii.z = (headbase + yc1 * Wd + xc0) * 96;
      ii.w = (headbase + yc1 * Wd + xc1) * 96;
      float4 ww = {wx0 * wy0, wx1 * wy0, wx0 * wy1, wx1 * wy1};
      *(int4*)(dpb + pt * 128) = ii;
      *(float4*)(dpb + pt * 128 + 16) = ww;
    }
  }
  __syncthreads();

  const int qi = t / 96, r = t - qi * 96;
  const int h = r / 6, d8 = r - h * 6;
  const int bq = bq0 + qi;
  const int hd = d8 * 16;
  const uint8_t* vB = (const uint8_t*)value;
  const uint8_t* dp = sdesc + (qi * 16 + h) * 528;

  f32x2 acc0[4] = {}, acc1[4] = {};
  int4 ii = *(const int4*)(dp);
  float4 ww = *(const float4*)(dp + 16);
  uint4 a0 = *(const uint4*)(vB + (ii.x + hd));
  uint4 a1 = *(const uint4*)(vB + (ii.y + hd));
  uint4 a2 = *(const uint4*)(vB + (ii.z + hd));
  uint4 a3 = *(const uint4*)(vB + (ii.w + hd));
  #pragma unroll
  for (int p = 0; p < 16; ++p) {
    int pn = (p + 1) & 15;
    int4 ii2 = *(const int4*)(dp + pn * 32);
    float4 ww2 = *(const float4*)(dp + pn * 32 + 16);
    uint4 b0 = *(const uint4*)(vB + (ii2.x + hd));
    uint4 b1 = *(const uint4*)(vB + (ii2.y + hd));
    uint4 b2 = *(const uint4*)(vB + (ii2.z + hd));
    uint4 b3 = *(const uint4*)(vB + (ii2.w + hd));
    fma8p(acc0, a0, ww.x);
    fma8p(acc1, a1, ww.y);
    fma8p(acc0, a2, ww.z);
    fma8p(acc1, a3, ww.w);
    ii = ii2; ww = ww2; a0 = b0; a1 = b1; a2 = b2; a3 = b3;
  }
  u16x8 o;
  #pragma unroll
  for (int j = 0; j < 4; ++j) {
    o[2*j]   = f2b(acc0[j][0] + acc1[j][0]);
    o[2*j+1] = f2b(acc0[j][1] + acc1[j][1]);
  }
  *(u16x8*)(out + (size_t)bq * 768 + h * 48 + d8 * 8) = o;
}

// self-attn sampling: offa row = [128 off | 64 logits | 64 pad], stride 256.
// value layout: [b][16][9216][48].
__global__ __launch_bounds__(384, 4) void samp_s_kernel(const u16* __restrict__ value,
    const float* __restrict__ offa, u16* __restrict__ out) {
  __shared__ uint8_t sdesc[4 * 16 * 144];   // 9216 B
  const int orig = blockIdx.x;
  const int cpx = gridDim.x >> 3;
  const int bq0 = ((orig & 7) * cpx + (orig >> 3)) * 4;
  const int t = threadIdx.x;

  if (t < 64) {
    const int qi = t >> 4, h = t & 15;
    const int bq = bq0 + qi;
    const int b = bq / 9216, q = bq - b * 9216;
    const float* row = offa + (size_t)bq * 256;
    float4 L = *(const float4*)(row + 128 + h * 4);
    float mx = fmaxf(fmaxf(L.x, L.y), fmaxf(L.z, L.w));
    float sum = __expf(L.x - mx) + __expf(L.y - mx) + __expf(L.z - mx) + __expf(L.w - mx);
    const float rs = 1.0f / sum;
    const float rx = ((q % 96) + 0.5f) * (1.0f / 96.0f);
    const float ry = ((q / 96) + 0.5f) * (1.0f / 96.0f);
    const int headbase = (b * 16 + h) * 9216;
    float4 o0 = *(const float4*)(row + h * 8);
    float4 o1 = *(const float4*)(row + h * 8 + 4);
    float oxs[4] = {o0.x, o0.z, o1.x, o1.z};
    float oys[4] = {o0.y, o0.w, o1.y, o1.w};
    float wgs[4] = {L.x, L.y, L.z, L.w};
    uint8_t* dpb = sdesc + (qi * 16 + h) * 144;
    #pragma unroll
    for (int pt = 0; pt < 4; ++pt) {
      float px = rx * 96.0f + oxs[pt] - 0.5f;
      float py = ry * 96.0f + oys[pt] - 0.5f;
      float wgt = __expf(wgs[pt] - mx) * rs;
      float x0f = floorf(px), y0f = floorf(py);
      float lx = px - x0f, ly = py - y0f;
      int x0 = (int)x0f, y0 = (int)y0f;
      int xc0 = min(max(x0, 0), 95), xc1 = min(max(x0 + 1, 0), 95);
      int yc0 = min(max(y0, 0), 95), yc1 = min(max(y0 + 1, 0), 95);
      float wx0 = ((unsigned)x0       < 96u) ? (1.0f - lx) : 0.0f;
      float wx1 = ((unsigned)(x0 + 1) < 96u) ? lx          : 0.0f;
      float wy0 = (((unsigned)y0       < 96u) ? (1.0f - ly) : 0.0f) * wgt;
      float wy1 = (((unsigned)(y0 + 1) < 96u) ? ly          : 0.0f) * wgt;
      int4 ii;
      ii.x = (headbase + yc0 * 96 + xc0) * 96;
      ii.y = (headbase + yc0 * 96 + xc1) * 96;
      ii.z = (headbase + yc1 * 96 + xc0) * 96;
      ii.w = (headbase + yc1 * 96 + xc1) * 96;
      float4 ww = {wx0 * wy0, wx1 * wy0, wx0 * wy1, wx1 * wy1};
      *(int4*)(dpb + pt * 32) = ii;
      *(float4*)(dpb + pt * 32 + 16) = ww;
    }
  }
  __syncthreads();

  const int qi = t / 96, r = t - qi * 96;
  const int h = r / 6, d8 = r - h * 6;
  const int bq = bq0 + qi;
  const int hd = d8 * 16;
  const uint8_t* vB = (const uint8_t*)value;
  const uint8_t* dp = sdesc + (qi * 16 + h) * 144;

  f32x2 acc0[4] = {}, acc1[4] = {};
  int4 ii = *(const int4*)(dp);
  float4 ww = *(const float4*)(dp + 16);
  uint4 a0 = *(const uint4*)(vB + (ii.x + hd));
  uint4 a1 = *(const uint4*)(vB + (ii.y + hd));
  uint4 a2 = *(const uint4*)(vB + (ii.z + hd));
  uint4 a3 = *(const uint4*)(vB + (ii.w + hd));
  #pragma unroll
  for (int p = 0; p < 4; ++p) {
    int pn = (p + 1) & 3;
    int4 ii2 = *(const int4*)(dp + pn * 32);
    float4 ww2 = *(const float4*)(dp + pn * 32 + 16);
    uint4 b0 = *(const uint4*)(vB + (ii2.x + hd));
    uint4 b1 = *(const uint4*)(vB + (ii2.y + hd));
    uint4 b2 = *(const uint4*)(vB + (ii2.z + hd));
    uint4 b3 = *(const uint4*)(vB + (ii2.w + hd));
    fma8p(acc0, a0, ww.x);
    fma8p(acc1, a1, ww.y);
    fma8p(acc0, a2, ww.z);
    fma8p(acc1, a3, ww.w);
    ii = ii2; ww = ww2; a0 = b0; a1 = b1; a2 = b2; a3 = b3;
  }
  u16x8 o;
  #pragma unroll
  for (int j = 0; j < 4; ++j) {
    o[2*j]   = f2b(acc0[j][0] + acc1[j][0]);
    o[2*j+1] = f2b(acc0[j][1] + acc1[j][1]);
  }
  *(u16x8*)(out + (size_t)bq * 768 + h * 48 + d8 * 8) = o;
}

// ---------------- launch ----------------
extern "C" void kernel_launch(void* const* d_in, const int* in_sizes, int n_in,
                              void* d_out, int out_size, void* d_ws, size_t ws_size,
                              hipStream_t stream) {
  (void)in_sizes; (void)n_in; (void)out_size; (void)ws_size;
  const float* src0 = (const float*)d_in[0];
  const float* src1 = (const float*)d_in[1];
  const float* src2 = (const float*)d_in[2];
  const float* src3 = (const float*)d_in[3];
  const float* qn_g = (const float*)d_in[4];
  const float* qn_b = (const float*)d_in[5];
  const float* fn_g = (const float*)d_in[6];
  const float* fn_b = (const float*)d_in[7];
  const float* n1_g = (const float*)d_in[8];
  const float* n1_b = (const float*)d_in[9];
  const float* gamma1 = (const float*)d_in[10];
  const float* gamma2 = (const float*)d_in[11];
  const float* c_Wv  = (const float*)d_in[12]; const float* c_bv   = (const float*)d_in[13];
  const float* c_Woff= (const float*)d_in[14]; const float* c_boff = (const float*)d_in[15];
  const float* c_Wa  = (const float*)d_in[16]; const float* c_ba   = (const float*)d_in[17];
  const float* c_Wo  = (const float*)d_in[18]; const float* c_bo   = (const float*)d_in[19];
  const float* s_Wv  = (const float*)d_in[20]; const float* s_bv   = (const float*)d_in[21];
  const float* s_Woff= (const float*)d_in[22]; const float* s_boff = (const float*)d_in[23];
  const float* s_Wa  = (const float*)d_in[24]; const float* s_ba   = (const float*)d_in[25];
  const float* s_Wo  = (const float*)d_in[26]; const float* s_bo   = (const float*)d_in[27];

  constexpr int Lq = 9216;
  constexpr int Mq = 2 * Lq;      // 18432
  constexpr int Mf = 2 * 14592;   // 29184

  constexpr size_t O_qln   = 8u << 20;
  constexpr size_t O_fln   = O_qln   + (size_t)Mq * 768 * 2;
  constexpr size_t O_valc  = O_fln   + (size_t)Mf * 768 * 2;   // bf16, head-major
  constexpr size_t O_offac = O_valc  + (size_t)Mf * 768 * 2;   // f32 [Mq][768]
  constexpr size_t O_sampc = O_qln;                            // reuse
  constexpr size_t O_attn  = O_fln;                            // reuse, bf16
  constexpr size_t O_attn1 = O_attn  + (size_t)Mq * 768 * 2;   // bf16
  constexpr size_t O_vals  = O_attn1 + (size_t)Mq * 768 * 2;   // bf16, head-major
  constexpr size_t O_offas = O_vals  + (size_t)Mq * 768 * 2;   // f32 [Mq][256]
  constexpr size_t O_samps = O_offas + (size_t)Mq * 256 * 4;   // bf16

  uint8_t* ws = (uint8_t*)d_ws;
  u16* Wbase = (u16*)ws;
  auto Wrow = [&](int r) { return Wbase + (size_t)r * 768; };
  auto Wp = [&](size_t o) { return (u16*)(ws + o); };
  auto Fp = [&](size_t o) { return (float*)(ws + o); };

  wconv_kernel<<<3072, 256, 0, stream>>>(c_Wv, c_Woff, c_Wa, c_Wo, s_Wv, s_Woff, s_Wa, s_Wo, Wbase);

  ln_rows_kernel<<<Mq, 192, 0, stream>>>(src3, qn_g, qn_b, Wp(O_qln));
  ln_feat_kernel<<<Mf, 192, 0, stream>>>(src0, src1, src2, src3, fn_g, fn_b, Wp(O_fln));

  // value projection (cross): Mf x 768 -> head-major [b][16][14592][48]
  gemm_kernel<MODE_BF16T, 6, 14592><<<(Mf / 128) * 6, 256, 0, stream>>>(
      Wp(O_fln), Wrow(0), c_bv, nullptr, 768, 768, Wp(O_valc), 768,
      nullptr, nullptr, nullptr, nullptr);
  // offsets + attn logits (cross, merged): Mq x 768 f32
  gemm_kernel<MODE_F32, 6><<<(Mq / 128) * 6, 256, 0, stream>>>(
      Wp(O_qln), Wrow(768), c_boff, c_ba, 512, 768, Fp(O_offac), 768,
      nullptr, nullptr, nullptr, nullptr);

  samp_c_kernel<<<Mq / 4, 384, 0, stream>>>(Wp(O_valc), Fp(O_offac), Wp(O_sampc));

  // output proj (cross) -> attn (bf16)
  gemm_kernel<MODE_BF16, 6><<<(Mq / 128) * 6, 256, 0, stream>>>(
      Wp(O_sampc), Wrow(1536), c_bo, nullptr, 768, 768, Wp(O_attn), 768,
      nullptr, nullptr, nullptr, nullptr);

  ln_rows_b16_kernel<<<Mq, 192, 0, stream>>>(Wp(O_attn), n1_g, n1_b, Wp(O_attn1));

  // value projection (self) -> head-major [b][16][9216][48]
  gemm_kernel<MODE_BF16T, 6, 9216><<<(Mq / 128) * 6, 256, 0, stream>>>(
      Wp(O_attn1), Wrow(2304), s_bv, nullptr, 768, 768, Wp(O_vals), 768,
      nullptr, nullptr, nullptr, nullptr);
  // offsets + attn logits (self, merged): Mq x 256 f32
  gemm_kernel<MODE_F32, 2><<<(Mq / 128) * 2, 256, 0, stream>>>(
      Wp(O_attn1), Wrow(3072), s_boff, s_ba, 128, 192, Fp(O_offas), 256,
      nullptr, nullptr, nullptr, nullptr);

  samp_s_kernel<<<Mq / 4, 384, 0, stream>>>(Wp(O_vals), Fp(O_offas), Wp(O_samps));

  // final: out = src3 + g1*(attn + g2*(samp_s @ s_Wo + s_bo))
  gemm_kernel<MODE_FINAL, 6><<<(Mq / 128) * 6, 256, 0, stream>>>(
      Wp(O_samps), Wrow(3328), s_bo, nullptr, 768, 768, (float*)d_out, 768,
      Wp(O_attn), src3, gamma1, gamma2);
}

// Round 7
// 379.197 us; speedup vs baseline: 3.5531x; 1.1483x over previous
//
#include <hip/hip_runtime.h>
#include <stdint.h>

typedef unsigned short u16;
typedef __attribute__((ext_vector_type(8))) __bf16 bf16x8;
typedef __attribute__((ext_vector_type(4))) float f32x4;
typedef __attribute__((ext_vector_type(2))) float f32x2;
typedef __attribute__((ext_vector_type(8))) u16 u16x8;
typedef __attribute__((ext_vector_type(4))) u16 u16x4;

#define DEV __device__ __forceinline__

DEV u16 f2b(float f) {
  union { float f; uint32_t u; } v; v.f = f;
  uint32_t u = v.u;
  return (u16)((u + 0x7fffu + ((u >> 16) & 1u)) >> 16);
}
DEV float b2f(u16 h) {
  union { uint32_t u; float f; } v; v.u = ((uint32_t)h) << 16;
  return v.f;
}
DEV float u2f(uint32_t u) {
  union { uint32_t u; float f; } v; v.u = u;
  return v.f;
}

// packed gather-convert-FMA of 8 bf16 channels
DEV void fma8p(f32x2* acc, uint4 v, float w) {
  const uint32_t* pv = (const uint32_t*)&v;
  f32x2 wv = {w, w};
  #pragma unroll
  for (int j = 0; j < 4; ++j) {
    uint32_t u = pv[j];
    f32x2 x = {u2f(u << 16), u2f(u & 0xffff0000u)};
    acc[j] += wv * x;
  }
}

// ---------------- fused weight transpose: 8 regions, tiled 32x32 via LDS ----
__global__ __launch_bounds__(256) void wconv_kernel(
    const float* __restrict__ W0, const float* __restrict__ W1,
    const float* __restrict__ W2, const float* __restrict__ W3,
    const float* __restrict__ W4, const float* __restrict__ W5,
    const float* __restrict__ W6, const float* __restrict__ W7,
    u16* __restrict__ dst) {
  __shared__ float s[32][33];
  int bx = blockIdx.x;            // 0..3071
  int ct = bx / 24;               // column-tile 0..127
  int kt = bx - ct * 24;          // k-tile 0..23
  const float* Wsrc; int N; int rowbase; int c0;
  if (ct < 24)       { Wsrc = W0; N = 768; rowbase = 0;    c0 = ct; }
  else if (ct < 40)  { Wsrc = W1; N = 512; rowbase = 768;  c0 = ct - 24; }
  else if (ct < 48)  { Wsrc = W2; N = 256; rowbase = 1280; c0 = ct - 40; }
  else if (ct < 72)  { Wsrc = W3; N = 768; rowbase = 1536; c0 = ct - 48; }
  else if (ct < 96)  { Wsrc = W4; N = 768; rowbase = 2304; c0 = ct - 72; }
  else if (ct < 100) { Wsrc = W5; N = 128; rowbase = 3072; c0 = ct - 96; }
  else if (ct < 104) { Wsrc = W6; N = 64;  rowbase = 3200; c0 = ct - 100; }
  else               { Wsrc = W7; N = 768; rowbase = 3328; c0 = ct - 104; }
  const int tx = threadIdx.x & 31, ty = threadIdx.x >> 5;
  const int n = c0 * 32 + tx;
  const int k0 = kt * 32;
  #pragma unroll
  for (int j = 0; j < 4; ++j) {
    int k = k0 + ty + j * 8;
    s[ty + j * 8][tx] = (n < N) ? Wsrc[(size_t)k * N + n] : 0.0f;
  }
  __syncthreads();
  #pragma unroll
  for (int j = 0; j < 4; ++j) {
    int nr = c0 * 32 + ty + j * 8;
    dst[(size_t)(rowbase + nr) * 768 + k0 + tx] = f2b(s[tx][ty + j * 8]);
  }
}

// ---------------- layernorm (row of 768), 192 threads, float4 ----------------
DEV void ln_core(float4 v, const float* __restrict__ g, const float* __restrict__ b,
                 u16* __restrict__ o, int t, float* red) {
  float s = v.x + v.y + v.z + v.w;
  float s2 = v.x * v.x + v.y * v.y + v.z * v.z + v.w * v.w;
  #pragma unroll
  for (int m = 1; m < 64; m <<= 1) { s += __shfl_xor(s, m); s2 += __shfl_xor(s2, m); }
  if ((t & 63) == 0) { red[t >> 6] = s; red[3 + (t >> 6)] = s2; }
  __syncthreads();
  float S = red[0] + red[1] + red[2];
  float S2 = red[3] + red[4] + red[5];
  float mean = S * (1.0f / 768.0f);
  float var = S2 * (1.0f / 768.0f) - mean * mean;
  float rstd = rsqrtf(var + 1e-6f);
  float4 gv = ((const float4*)g)[t], bv = ((const float4*)b)[t];
  u16x4 ov;
  ov[0] = f2b((v.x - mean) * rstd * gv.x + bv.x);
  ov[1] = f2b((v.y - mean) * rstd * gv.y + bv.y);
  ov[2] = f2b((v.z - mean) * rstd * gv.z + bv.z);
  ov[3] = f2b((v.w - mean) * rstd * gv.w + bv.w);
  *(u16x4*)(o + t * 4) = ov;
}

__global__ __launch_bounds__(192) void ln_rows_kernel(const float* __restrict__ in,
    const float* __restrict__ g, const float* __restrict__ b, u16* __restrict__ out) {
  __shared__ float red[6];
  size_t row = blockIdx.x;
  int t = threadIdx.x;
  ln_core(((const float4*)(in + row * 768))[t], g, b, out + row * 768, t, red);
}

__global__ __launch_bounds__(192) void ln_rows_b16_kernel(const u16* __restrict__ in,
    const float* __restrict__ g, const float* __restrict__ b, u16* __restrict__ out) {
  __shared__ float red[6];
  size_t row = blockIdx.x;
  int t = threadIdx.x;
  u16x4 r = *(const u16x4*)(in + row * 768 + t * 4);
  float4 v = {b2f(r[0]), b2f(r[1]), b2f(r[2]), b2f(r[3])};
  ln_core(v, g, b, out + row * 768, t, red);
}

__global__ __launch_bounds__(192) void ln_feat_kernel(const float* __restrict__ s0,
    const float* __restrict__ s1, const float* __restrict__ s2, const float* __restrict__ s3,
    const float* __restrict__ g, const float* __restrict__ b, u16* __restrict__ out) {
  __shared__ float red[6];
  int row = blockIdx.x;
  int bb = row / 14592, pos = row - bb * 14592;
  const float* x;
  if (pos < 256)       x = s0 + ((size_t)bb * 256  + pos) * 768;
  else if (pos < 1280) x = s1 + ((size_t)bb * 1024 + (pos - 256)) * 768;
  else if (pos < 5376) x = s2 + ((size_t)bb * 4096 + (pos - 1280)) * 768;
  else                 x = s3 + ((size_t)bb * 9216 + (pos - 5376)) * 768;
  int t = threadIdx.x;
  ln_core(((const float4*)x)[t], g, b, out + (size_t)row * 768, t, red);
}

// ---------------- bf16 MFMA GEMM, 2-phase double-buffered prefetch ----------
// STAGE(t+1) issued BEFORE ds_read+MFMA of tile t; one barrier per K-step.
// MODE_BF16T writes C transposed into head-major value layout [b][16][LROW][48].
enum { MODE_F32 = 0, MODE_BF16 = 1, MODE_FINAL = 2, MODE_BF16T = 3 };

template <int MODE, int NT, int LROW = 1>
__global__ __launch_bounds__(256) void gemm_kernel(
    const u16* __restrict__ A, const u16* __restrict__ Wt,
    const float* __restrict__ bias1, const float* __restrict__ bias2,
    int split, int nb, void* __restrict__ Cout, int N,
    const u16* __restrict__ attnb, const float* __restrict__ resid,
    const float* __restrict__ g1, const float* __restrict__ g2) {
  constexpr int K = 768;
  __shared__ u16 smem[4 * 128 * 64];   // 2 buffers x (A 128x64 + B 128x64); C-pack overlays
  const int t = threadIdx.x;
  const int lane = t & 63;
  const int w = t >> 6;
  const int wr = w >> 1, wc = w & 1;
  const int chunk = gridDim.x >> 3;
  const int tile = (blockIdx.x & 7) * chunk + (blockIdx.x >> 3);
  const int tm = tile / NT, tn = tile - tm * NT;
  const size_t m0 = (size_t)tm * 128;
  const int n0 = tn * 128;

  f32x4 acc[4][4] = {};

  auto STAGE = [&](int buf, int kt) {
    u16* sA = smem + buf * 16384;
    u16* sB = sA + 8192;
    #pragma unroll
    for (int i = 0; i < 4; ++i) {
      int ci = i * 256 + t;
      int row = ci >> 3, c8 = ci & 7;
      int kc = c8 ^ (row & 7);
      const u16* ga = A + (m0 + row) * K + kt + kc * 8;
      const u16* gb = Wt + ((size_t)n0 + row) * K + kt + kc * 8;
      __builtin_amdgcn_global_load_lds((const __attribute__((address_space(1))) void*)ga,
          (__attribute__((address_space(3))) void*)(sA + ci * 8), 16, 0, 0);
      __builtin_amdgcn_global_load_lds((const __attribute__((address_space(1))) void*)gb,
          (__attribute__((address_space(3))) void*)(sB + ci * 8), 16, 0, 0);
    }
  };

  STAGE(0, 0);
  __syncthreads();
  int cur = 0;
  for (int kt = 0; kt < K; kt += 64) {
    if (kt + 64 < K) STAGE(cur ^ 1, kt + 64);   // prefetch flies under compute
    const u16* sA = smem + cur * 16384;
    const u16* sB = sA + 8192;
    #pragma unroll
    for (int ks = 0; ks < 2; ++ks) {
      bf16x8 af[4], bfr[4];
      #pragma unroll
      for (int m = 0; m < 4; ++m) {
        int row = wr * 64 + m * 16 + (lane & 15);
        int pc = (ks * 4 + (lane >> 4)) ^ (row & 7);
        af[m] = *(const bf16x8*)(sA + row * 64 + pc * 8);
      }
      #pragma unroll
      for (int n = 0; n < 4; ++n) {
        int row = wc * 64 + n * 16 + (lane & 15);
        int pc = (ks * 4 + (lane >> 4)) ^ (row & 7);
        bfr[n] = *(const bf16x8*)(sB + row * 64 + pc * 8);
      }
      #pragma unroll
      for (int m = 0; m < 4; ++m)
        #pragma unroll
        for (int n = 0; n < 4; ++n)
          acc[m][n] = __builtin_amdgcn_mfma_f32_16x16x32_bf16(af[m], bfr[n], acc[m][n], 0, 0, 0);
    }
    __syncthreads();   // drains prefetch (vmcnt 0) + protects buffer swap
    cur ^= 1;
  }

  if constexpr (MODE == MODE_BF16 || MODE == MODE_BF16T) {
    // pack into LDS (u16, row stride 136) -> 16B vector stores
    #pragma unroll
    for (int m = 0; m < 4; ++m) {
      #pragma unroll
      for (int n = 0; n < 4; ++n) {
        int lcol = wc * 64 + n * 16 + (lane & 15);
        int gcol = n0 + lcol;
        float bv = (gcol < split) ? bias1[gcol] : ((gcol < nb) ? bias2[gcol - split] : 0.0f);
        #pragma unroll
        for (int r = 0; r < 4; ++r) {
          int lrow = wr * 64 + m * 16 + (lane >> 4) * 4 + r;
          smem[lrow * 136 + lcol] = f2b(acc[m][n][r] + bv);
        }
      }
    }
    __syncthreads();
    #pragma unroll
    for (int i = 0; i < 8; ++i) {
      int c = t + 256 * i;                 // 0..2047
      int lrow = c >> 4, col8 = (c & 15) * 8;
      u16x8 vv = *(const u16x8*)(smem + lrow * 136 + col8);
      int gcol = n0 + col8;
      size_t grow = m0 + (size_t)lrow;
      if constexpr (MODE == MODE_BF16T) {
        int gi = (int)grow;
        int bb = gi / LROW, pos = gi - bb * LROW;
        int hh = gcol / 48, dd = gcol - hh * 48;
        *(u16x8*)((u16*)Cout + (((size_t)bb * 16 + hh) * LROW + pos) * 48 + dd) = vv;
      } else {
        *(u16x8*)((u16*)Cout + grow * (size_t)N + gcol) = vv;
      }
    }
  } else {
    #pragma unroll
    for (int m = 0; m < 4; ++m) {
      #pragma unroll
      for (int n = 0; n < 4; ++n) {
        int col = n0 + wc * 64 + n * 16 + (lane & 15);
        float bv = (col < split) ? bias1[col] : ((col < nb) ? bias2[col - split] : 0.0f);
        #pragma unroll
        for (int r = 0; r < 4; ++r) {
          size_t grow = m0 + (size_t)(wr * 64 + m * 16 + (lane >> 4) * 4 + r);
          float v = acc[m][n][r] + bv;
          size_t idx = grow * (size_t)N + col;
          if constexpr (MODE == MODE_F32) {
            ((float*)Cout)[idx] = v;
          } else {
            ((float*)Cout)[idx] = resid[idx] + g1[col] * (b2f(attnb[idx]) + g2[col] * v);
          }
        }
      }
    }
  }
}

// ---------------- deformable sampling: 2-phase descriptor scheme -------------
// value: [b][16 heads][LROW][48] bf16 head-major. offa is bf16 now.
// 2 queries/block, 192 threads -> 16.9KB LDS -> ~9 blocks/CU (TLP hides latency).
// Phase 1 (thread=(q,h,l)): corner byte-offsets + premult weights -> LDS desc,
// slot = pt*4+l (l in bank index). Phase 2 (thread=(q,h,d8)): 16 x 4 gathers.
__global__ __launch_bounds__(192, 6) void samp_c_kernel(const u16* __restrict__ value,
    const u16* __restrict__ offa, u16* __restrict__ out) {
  __shared__ uint8_t sdesc[2 * 16 * 528];   // 16896 B
  const int orig = blockIdx.x;
  const int cpx = gridDim.x >> 3;
  const int bq0 = ((orig & 7) * cpx + (orig >> 3)) * 2;
  const int t = threadIdx.x;

  if (t < 128) {
    const int qi = t >> 6, h = (t >> 2) & 15, l = t & 3;
    const int bq = bq0 + qi;
    const int b = bq / 9216, q = bq - b * 9216;
    const u16* rw = offa + (size_t)bq * 768;
    u16x8 A0 = *(const u16x8*)(rw + 512 + h * 16);
    u16x8 A1 = *(const u16x8*)(rw + 512 + h * 16 + 8);
    float lg[16];
    #pragma unroll
    for (int i = 0; i < 8; ++i) { lg[i] = b2f(A0[i]); lg[8 + i] = b2f(A1[i]); }
    float mx = lg[0];
    #pragma unroll
    for (int i = 1; i < 16; ++i) mx = fmaxf(mx, lg[i]);
    float sum = 0.0f;
    #pragma unroll
    for (int i = 0; i < 16; ++i) sum += __expf(lg[i] - mx);
    const float rs = 1.0f / sum;
    float w0 = (l == 0) ? lg[0] : ((l == 1) ? lg[4] : ((l == 2) ? lg[8]  : lg[12]));
    float w1 = (l == 0) ? lg[1] : ((l == 1) ? lg[5] : ((l == 2) ? lg[9]  : lg[13]));
    float w2 = (l == 0) ? lg[2] : ((l == 1) ? lg[6] : ((l == 2) ? lg[10] : lg[14]));
    float w3 = (l == 0) ? lg[3] : ((l == 1) ? lg[7] : ((l == 2) ? lg[11] : lg[15]));

    const int Wd = (l == 3) ? 96 : (16 << l);
    const int STl = (l == 0) ? 0 : ((l == 1) ? 256 : ((l == 2) ? 1280 : 5376));
    const float fW = (float)Wd;
    const float rx = ((q % 96) + 0.5f) * (1.0f / 96.0f);
    const float ry = ((q / 96) + 0.5f) * (1.0f / 96.0f);
    const int headbase = (b * 16 + h) * 14592 + STl;

    u16x8 O = *(const u16x8*)(rw + h * 32 + l * 8);
    float oxs[4] = {b2f(O[0]), b2f(O[2]), b2f(O[4]), b2f(O[6])};
    float oys[4] = {b2f(O[1]), b2f(O[3]), b2f(O[5]), b2f(O[7])};
    float wgs[4] = {w0, w1, w2, w3};
    uint8_t* dpb = sdesc + (qi * 16 + h) * 528 + l * 32;   // slot = pt*4 + l
    #pragma unroll
    for (int pt = 0; pt < 4; ++pt) {
      float px = rx * fW + oxs[pt] - 0.5f;
      float py = ry * fW + oys[pt] - 0.5f;
      float wgt = __expf(wgs[pt] - mx) * rs;
      float x0f = floorf(px), y0f = floorf(py);
      float lx = px - x0f, ly = py - y0f;
      int x0 = (int)x0f, y0 = (int)y0f;
      int xc0 = min(max(x0, 0), Wd - 1), xc1 = min(max(x0 + 1, 0), Wd - 1);
      int yc0 = min(max(y0, 0), Wd - 1), yc1 = min(max(y0 + 1, 0), Wd - 1);
      float wx0 = ((unsigned)x0       < (unsigned)Wd) ? (1.0f - lx) : 0.0f;
      float wx1 = ((unsigned)(x0 + 1) < (unsigned)Wd) ? lx          : 0.0f;
      float wy0 = (((unsigned)y0       < (unsigned)Wd) ? (1.0f - ly) : 0.0f) * wgt;
      float wy1 = (((unsigned)(y0 + 1) < (unsigned)Wd) ? ly          : 0.0f) * wgt;
      int4 ii;
      ii.x = (headbase + yc0 * Wd + xc0) * 96;
      ii.y = (headbase + yc0 * Wd + xc1) * 96;
      ii.z = (headbase + yc1 * Wd + xc0) * 96;
      ii.w = (headbase + yc1 * Wd + xc1) * 96;
      float4 ww = {wx0 * wy0, wx1 * wy0, wx0 * wy1, wx1 * wy1};
      *(int4*)(dpb + pt * 128) = ii;
      *(float4*)(dpb + pt * 128 + 16) = ww;
    }
  }
  __syncthreads();

  const int qi = t / 96, r = t - qi * 96;
  const int h = r / 6, d8 = r - h * 6;
  const int bq = bq0 + qi;
  const int hd = d8 * 16;
  const uint8_t* vB = (const uint8_t*)value;
  const uint8_t* dp = sdesc + (qi * 16 + h) * 528;

  f32x2 acc0[4] = {}, acc1[4] = {};
  #pragma unroll
  for (int p = 0; p < 16; ++p) {
    int4 ii = *(const int4*)(dp + p * 32);
    float4 ww = *(const float4*)(dp + p * 32 + 16);
    uint4 u00 = *(const uint4*)(vB + (ii.x + hd));
    uint4 u01 = *(const uint4*)(vB + (ii.y + hd));
    uint4 u10 = *(const uint4*)(vB + (ii.z + hd));
    uint4 u11 = *(const uint4*)(vB + (ii.w + hd));
    fma8p(acc0, u00, ww.x);
    fma8p(acc1, u01, ww.y);
    fma8p(acc0, u10, ww.z);
    fma8p(acc1, u11, ww.w);
  }
  u16x8 o;
  #pragma unroll
  for (int j = 0; j < 4; ++j) {
    o[2*j]   = f2b(acc0[j][0] + acc1[j][0]);
    o[2*j+1] = f2b(acc0[j][1] + acc1[j][1]);
  }
  *(u16x8*)(out + (size_t)bq * 768 + h * 48 + d8 * 8) = o;
}

// self-attn sampling: offa (bf16) row = [128 off | 64 logits | 64 pad], stride 256.
// value layout: [b][16][9216][48]. 2 queries/block, 192 threads.
__global__ __launch_bounds__(192, 6) void samp_s_kernel(const u16* __restrict__ value,
    const u16* __restrict__ offa, u16* __restrict__ out) {
  __shared__ uint8_t sdesc[2 * 16 * 144];   // 4608 B
  const int orig = blockIdx.x;
  const int cpx = gridDim.x >> 3;
  const int bq0 = ((orig & 7) * cpx + (orig >> 3)) * 2;
  const int t = threadIdx.x;

  if (t < 32) {
    const int qi = t >> 4, h = t & 15;
    const int bq = bq0 + qi;
    const int b = bq / 9216, q = bq - b * 9216;
    const u16* rw = offa + (size_t)bq * 256;
    u16x4 Lv = *(const u16x4*)(rw + 128 + h * 4);
    float lg[4] = {b2f(Lv[0]), b2f(Lv[1]), b2f(Lv[2]), b2f(Lv[3])};
    float mx = fmaxf(fmaxf(lg[0], lg[1]), fmaxf(lg[2], lg[3]));
    float sum = __expf(lg[0] - mx) + __expf(lg[1] - mx) + __expf(lg[2] - mx) + __expf(lg[3] - mx);
    const float rs = 1.0f / sum;
    const float rx = ((q % 96) + 0.5f) * (1.0f / 96.0f);
    const float ry = ((q / 96) + 0.5f) * (1.0f / 96.0f);
    const int headbase = (b * 16 + h) * 9216;
    u16x8 O = *(const u16x8*)(rw + h * 8);
    float oxs[4] = {b2f(O[0]), b2f(O[2]), b2f(O[4]), b2f(O[6])};
    float oys[4] = {b2f(O[1]), b2f(O[3]), b2f(O[5]), b2f(O[7])};
    uint8_t* dpb = sdesc + (qi * 16 + h) * 144;
    #pragma unroll
    for (int pt = 0; pt < 4; ++pt) {
      float px = rx * 96.0f + oxs[pt] - 0.5f;
      float py = ry * 96.0f + oys[pt] - 0.5f;
      float wgt = __expf(lg[pt] - mx) * rs;
      float x0f = floorf(px), y0f = floorf(py);
      float lx = px - x0f, ly = py - y0f;
      int x0 = (int)x0f, y0 = (int)y0f;
      int xc0 = min(max(x0, 0), 95), xc1 = min(max(x0 + 1, 0), 95);
      int yc0 = min(max(y0, 0), 95), yc1 = min(max(y0 + 1, 0), 95);
      float wx0 = ((unsigned)x0       < 96u) ? (1.0f - lx) : 0.0f;
      float wx1 = ((unsigned)(x0 + 1) < 96u) ? lx          : 0.0f;
      float wy0 = (((unsigned)y0       < 96u) ? (1.0f - ly) : 0.0f) * wgt;
      float wy1 = (((unsigned)(y0 + 1) < 96u) ? ly          : 0.0f) * wgt;
      int4 ii;
      ii.x = (headbase + yc0 * 96 + xc0) * 96;
      ii.y = (headbase + yc0 * 96 + xc1) * 96;
      ii.z = (headbase + yc1 * 96 + xc0) * 96;
      ii.w = (headbase + yc1 * 96 + xc1) * 96;
      float4 ww = {wx0 * wy0, wx1 * wy0, wx0 * wy1, wx1 * wy1};
      *(int4*)(dpb + pt * 32) = ii;
      *(float4*)(dpb + pt * 32 + 16) = ww;
    }
  }
  __syncthreads();

  const int qi = t / 96, r = t - qi * 96;
  const int h = r / 6, d8 = r - h * 6;
  const int bq = bq0 + qi;
  const int hd = d8 * 16;
  const uint8_t* vB = (const uint8_t*)value;
  const uint8_t* dp = sdesc + (qi * 16 + h) * 144;

  f32x2 acc0[4] = {}, acc1[4] = {};
  #pragma unroll
  for (int p = 0; p < 4; ++p) {
    int4 ii = *(const int4*)(dp + p * 32);
    float4 ww = *(const float4*)(dp + p * 32 + 16);
    uint4 u00 = *(const uint4*)(vB + (ii.x + hd));
    uint4 u01 = *(const uint4*)(vB + (ii.y + hd));
    uint4 u10 = *(const uint4*)(vB + (ii.z + hd));
    uint4 u11 = *(const uint4*)(vB + (ii.w + hd));
    fma8p(acc0, u00, ww.x);
    fma8p(acc1, u01, ww.y);
    fma8p(acc0, u10, ww.z);
    fma8p(acc1, u11, ww.w);
  }
  u16x8 o;
  #pragma unroll
  for (int j = 0; j < 4; ++j) {
    o[2*j]   = f2b(acc0[j][0] + acc1[j][0]);
    o[2*j+1] = f2b(acc0[j][1] + acc1[j][1]);
  }
  *(u16x8*)(out + (size_t)bq * 768 + h * 48 + d8 * 8) = o;
}

// ---------------- launch ----------------
extern "C" void kernel_launch(void* const* d_in, const int* in_sizes, int n_in,
                              void* d_out, int out_size, void* d_ws, size_t ws_size,
                              hipStream_t stream) {
  (void)in_sizes; (void)n_in; (void)out_size; (void)ws_size;
  const float* src0 = (const float*)d_in[0];
  const float* src1 = (const float*)d_in[1];
  const float* src2 = (const float*)d_in[2];
  const float* src3 = (const float*)d_in[3];
  const float* qn_g = (const float*)d_in[4];
  const float* qn_b = (const float*)d_in[5];
  const float* fn_g = (const float*)d_in[6];
  const float* fn_b = (const float*)d_in[7];
  const float* n1_g = (const float*)d_in[8];
  const float* n1_b = (const float*)d_in[9];
  const float* gamma1 = (const float*)d_in[10];
  const float* gamma2 = (const float*)d_in[11];
  const float* c_Wv  = (const float*)d_in[12]; const float* c_bv   = (const float*)d_in[13];
  const float* c_Woff= (const float*)d_in[14]; const float* c_boff = (const float*)d_in[15];
  const float* c_Wa  = (const float*)d_in[16]; const float* c_ba   = (const float*)d_in[17];
  const float* c_Wo  = (const float*)d_in[18]; const float* c_bo   = (const float*)d_in[19];
  const float* s_Wv  = (const float*)d_in[20]; const float* s_bv   = (const float*)d_in[21];
  const float* s_Woff= (const float*)d_in[22]; const float* s_boff = (const float*)d_in[23];
  const float* s_Wa  = (const float*)d_in[24]; const float* s_ba   = (const float*)d_in[25];
  const float* s_Wo  = (const float*)d_in[26]; const float* s_bo   = (const float*)d_in[27];

  constexpr int Lq = 9216;
  constexpr int Mq = 2 * Lq;      // 18432
  constexpr int Mf = 2 * 14592;   // 29184

  constexpr size_t O_qln   = 8u << 20;
  constexpr size_t O_fln   = O_qln   + (size_t)Mq * 768 * 2;
  constexpr size_t O_valc  = O_fln   + (size_t)Mf * 768 * 2;   // bf16, head-major
  constexpr size_t O_offac = O_valc  + (size_t)Mf * 768 * 2;   // bf16 [Mq][768]
  constexpr size_t O_sampc = O_qln;                            // reuse
  constexpr size_t O_attn  = O_fln;                            // reuse, bf16
  constexpr size_t O_attn1 = O_attn  + (size_t)Mq * 768 * 2;   // bf16
  constexpr size_t O_vals  = O_attn1 + (size_t)Mq * 768 * 2;   // bf16, head-major
  constexpr size_t O_offas = O_vals  + (size_t)Mq * 768 * 2;   // bf16 [Mq][256]
  constexpr size_t O_samps = O_offas + (size_t)Mq * 256 * 2;   // bf16

  uint8_t* ws = (uint8_t*)d_ws;
  u16* Wbase = (u16*)ws;
  auto Wrow = [&](int r) { return Wbase + (size_t)r * 768; };
  auto Wp = [&](size_t o) { return (u16*)(ws + o); };

  wconv_kernel<<<3072, 256, 0, stream>>>(c_Wv, c_Woff, c_Wa, c_Wo, s_Wv, s_Woff, s_Wa, s_Wo, Wbase);

  ln_rows_kernel<<<Mq, 192, 0, stream>>>(src3, qn_g, qn_b, Wp(O_qln));
  ln_feat_kernel<<<Mf, 192, 0, stream>>>(src0, src1, src2, src3, fn_g, fn_b, Wp(O_fln));

  // value projection (cross): Mf x 768 -> head-major [b][16][14592][48]
  gemm_kernel<MODE_BF16T, 6, 14592><<<(Mf / 128) * 6, 256, 0, stream>>>(
      Wp(O_fln), Wrow(0), c_bv, nullptr, 768, 768, Wp(O_valc), 768,
      nullptr, nullptr, nullptr, nullptr);
  // offsets + attn logits (cross, merged): Mq x 768 bf16
  gemm_kernel<MODE_BF16, 6><<<(Mq / 128) * 6, 256, 0, stream>>>(
      Wp(O_qln), Wrow(768), c_boff, c_ba, 512, 768, Wp(O_offac), 768,
      nullptr, nullptr, nullptr, nullptr);

  samp_c_kernel<<<Mq / 2, 192, 0, stream>>>(Wp(O_valc), Wp(O_offac), Wp(O_sampc));

  // output proj (cross) -> attn (bf16)
  gemm_kernel<MODE_BF16, 6><<<(Mq / 128) * 6, 256, 0, stream>>>(
      Wp(O_sampc), Wrow(1536), c_bo, nullptr, 768, 768, Wp(O_attn), 768,
      nullptr, nullptr, nullptr, nullptr);

  ln_rows_b16_kernel<<<Mq, 192, 0, stream>>>(Wp(O_attn), n1_g, n1_b, Wp(O_attn1));

  // value projection (self) -> head-major [b][16][9216][48]
  gemm_kernel<MODE_BF16T, 6, 9216><<<(Mq / 128) * 6, 256, 0, stream>>>(
      Wp(O_attn1), Wrow(2304), s_bv, nullptr, 768, 768, Wp(O_vals), 768,
      nullptr, nullptr, nullptr, nullptr);
  // offsets + attn logits (self, merged): Mq x 256 bf16
  gemm_kernel<MODE_BF16, 2><<<(Mq / 128) * 2, 256, 0, stream>>>(
      Wp(O_attn1), Wrow(3072), s_boff, s_ba, 128, 192, Wp(O_offas), 256,
      nullptr, nullptr, nullptr, nullptr);

  samp_s_kernel<<<Mq / 2, 192, 0, stream>>>(Wp(O_vals), Wp(O_offas), Wp(O_samps));

  // final: out = src3 + g1*(attn + g2*(samp_s @ s_Wo + s_bo))
  gemm_kernel<MODE_FINAL, 6><<<(Mq / 128) * 6, 256, 0, stream>>>(
      Wp(O_samps), Wrow(3328), s_bo, nullptr, 768, 768, (float*)d_out, 768,
      Wp(O_attn), src3, gamma1, gamma2);
}

// Round 8
// 377.008 us; speedup vs baseline: 3.5737x; 1.0058x over previous
//
#include <hip/hip_runtime.h>
#include <stdint.h>

typedef unsigned short u16;
typedef __attribute__((ext_vector_type(8))) __bf16 bf16x8;
typedef __attribute__((ext_vector_type(4))) float f32x4;
typedef __attribute__((ext_vector_type(2))) float f32x2;
typedef __attribute__((ext_vector_type(8))) u16 u16x8;
typedef __attribute__((ext_vector_type(4))) u16 u16x4;

#define DEV __device__ __forceinline__

DEV u16 f2b(float f) {
  union { float f; uint32_t u; } v; v.f = f;
  uint32_t u = v.u;
  return (u16)((u + 0x7fffu + ((u >> 16) & 1u)) >> 16);
}
DEV float b2f(u16 h) {
  union { uint32_t u; float f; } v; v.u = ((uint32_t)h) << 16;
  return v.f;
}
DEV float u2f(uint32_t u) {
  union { uint32_t u; float f; } v; v.u = u;
  return v.f;
}

// packed gather-convert-FMA of 8 bf16 channels
DEV void fma8p(f32x2* acc, uint4 v, float w) {
  const uint32_t* pv = (const uint32_t*)&v;
  f32x2 wv = {w, w};
  #pragma unroll
  for (int j = 0; j < 4; ++j) {
    uint32_t u = pv[j];
    f32x2 x = {u2f(u << 16), u2f(u & 0xffff0000u)};
    acc[j] += wv * x;
  }
}

// ---------------- fused weight transpose: 8 regions, tiled 32x32 via LDS ----
__global__ __launch_bounds__(256) void wconv_kernel(
    const float* __restrict__ W0, const float* __restrict__ W1,
    const float* __restrict__ W2, const float* __restrict__ W3,
    const float* __restrict__ W4, const float* __restrict__ W5,
    const float* __restrict__ W6, const float* __restrict__ W7,
    u16* __restrict__ dst) {
  __shared__ float s[32][33];
  int bx = blockIdx.x;            // 0..3071
  int ct = bx / 24;               // column-tile 0..127
  int kt = bx - ct * 24;          // k-tile 0..23
  const float* Wsrc; int N; int rowbase; int c0;
  if (ct < 24)       { Wsrc = W0; N = 768; rowbase = 0;    c0 = ct; }
  else if (ct < 40)  { Wsrc = W1; N = 512; rowbase = 768;  c0 = ct - 24; }
  else if (ct < 48)  { Wsrc = W2; N = 256; rowbase = 1280; c0 = ct - 40; }
  else if (ct < 72)  { Wsrc = W3; N = 768; rowbase = 1536; c0 = ct - 48; }
  else if (ct < 96)  { Wsrc = W4; N = 768; rowbase = 2304; c0 = ct - 72; }
  else if (ct < 100) { Wsrc = W5; N = 128; rowbase = 3072; c0 = ct - 96; }
  else if (ct < 104) { Wsrc = W6; N = 64;  rowbase = 3200; c0 = ct - 100; }
  else               { Wsrc = W7; N = 768; rowbase = 3328; c0 = ct - 104; }
  const int tx = threadIdx.x & 31, ty = threadIdx.x >> 5;
  const int n = c0 * 32 + tx;
  const int k0 = kt * 32;
  #pragma unroll
  for (int j = 0; j < 4; ++j) {
    int k = k0 + ty + j * 8;
    s[ty + j * 8][tx] = (n < N) ? Wsrc[(size_t)k * N + n] : 0.0f;
  }
  __syncthreads();
  #pragma unroll
  for (int j = 0; j < 4; ++j) {
    int nr = c0 * 32 + ty + j * 8;
    dst[(size_t)(rowbase + nr) * 768 + k0 + tx] = f2b(s[tx][ty + j * 8]);
  }
}

// ---------------- layernorm (row of 768), 192 threads, float4 ----------------
DEV void ln_core(float4 v, const float* __restrict__ g, const float* __restrict__ b,
                 u16* __restrict__ o, int t, float* red) {
  float s = v.x + v.y + v.z + v.w;
  float s2 = v.x * v.x + v.y * v.y + v.z * v.z + v.w * v.w;
  #pragma unroll
  for (int m = 1; m < 64; m <<= 1) { s += __shfl_xor(s, m); s2 += __shfl_xor(s2, m); }
  if ((t & 63) == 0) { red[t >> 6] = s; red[3 + (t >> 6)] = s2; }
  __syncthreads();
  float S = red[0] + red[1] + red[2];
  float S2 = red[3] + red[4] + red[5];
  float mean = S * (1.0f / 768.0f);
  float var = S2 * (1.0f / 768.0f) - mean * mean;
  float rstd = rsqrtf(var + 1e-6f);
  float4 gv = ((const float4*)g)[t], bv = ((const float4*)b)[t];
  u16x4 ov;
  ov[0] = f2b((v.x - mean) * rstd * gv.x + bv.x);
  ov[1] = f2b((v.y - mean) * rstd * gv.y + bv.y);
  ov[2] = f2b((v.z - mean) * rstd * gv.z + bv.z);
  ov[3] = f2b((v.w - mean) * rstd * gv.w + bv.w);
  *(u16x4*)(o + t * 4) = ov;
}

__global__ __launch_bounds__(192) void ln_rows_kernel(const float* __restrict__ in,
    const float* __restrict__ g, const float* __restrict__ b, u16* __restrict__ out) {
  __shared__ float red[6];
  size_t row = blockIdx.x;
  int t = threadIdx.x;
  ln_core(((const float4*)(in + row * 768))[t], g, b, out + row * 768, t, red);
}

__global__ __launch_bounds__(192) void ln_rows_b16_kernel(const u16* __restrict__ in,
    const float* __restrict__ g, const float* __restrict__ b, u16* __restrict__ out) {
  __shared__ float red[6];
  size_t row = blockIdx.x;
  int t = threadIdx.x;
  u16x4 r = *(const u16x4*)(in + row * 768 + t * 4);
  float4 v = {b2f(r[0]), b2f(r[1]), b2f(r[2]), b2f(r[3])};
  ln_core(v, g, b, out + row * 768, t, red);
}

__global__ __launch_bounds__(192) void ln_feat_kernel(const float* __restrict__ s0,
    const float* __restrict__ s1, const float* __restrict__ s2, const float* __restrict__ s3,
    const float* __restrict__ g, const float* __restrict__ b, u16* __restrict__ out) {
  __shared__ float red[6];
  int row = blockIdx.x;
  int bb = row / 14592, pos = row - bb * 14592;
  const float* x;
  if (pos < 256)       x = s0 + ((size_t)bb * 256  + pos) * 768;
  else if (pos < 1280) x = s1 + ((size_t)bb * 1024 + (pos - 256)) * 768;
  else if (pos < 5376) x = s2 + ((size_t)bb * 4096 + (pos - 1280)) * 768;
  else                 x = s3 + ((size_t)bb * 9216 + (pos - 5376)) * 768;
  int t = threadIdx.x;
  ln_core(((const float4*)x)[t], g, b, out + (size_t)row * 768, t, red);
}

// ---------------- bf16 MFMA GEMM, 2-phase double-buffered prefetch ----------
enum { MODE_F32 = 0, MODE_BF16 = 1, MODE_FINAL = 2, MODE_BF16T = 3 };

template <int MODE, int NT, int LROW = 1>
__global__ __launch_bounds__(256) void gemm_kernel(
    const u16* __restrict__ A, const u16* __restrict__ Wt,
    const float* __restrict__ bias1, const float* __restrict__ bias2,
    int split, int nb, void* __restrict__ Cout, int N,
    const u16* __restrict__ attnb, const float* __restrict__ resid,
    const float* __restrict__ g1, const float* __restrict__ g2) {
  constexpr int K = 768;
  __shared__ u16 smem[4 * 128 * 64];
  const int t = threadIdx.x;
  const int lane = t & 63;
  const int w = t >> 6;
  const int wr = w >> 1, wc = w & 1;
  const int chunk = gridDim.x >> 3;
  const int tile = (blockIdx.x & 7) * chunk + (blockIdx.x >> 3);
  const int tm = tile / NT, tn = tile - tm * NT;
  const size_t m0 = (size_t)tm * 128;
  const int n0 = tn * 128;

  f32x4 acc[4][4] = {};

  auto STAGE = [&](int buf, int kt) {
    u16* sA = smem + buf * 16384;
    u16* sB = sA + 8192;
    #pragma unroll
    for (int i = 0; i < 4; ++i) {
      int ci = i * 256 + t;
      int row = ci >> 3, c8 = ci & 7;
      int kc = c8 ^ (row & 7);
      const u16* ga = A + (m0 + row) * K + kt + kc * 8;
      const u16* gb = Wt + ((size_t)n0 + row) * K + kt + kc * 8;
      __builtin_amdgcn_global_load_lds((const __attribute__((address_space(1))) void*)ga,
          (__attribute__((address_space(3))) void*)(sA + ci * 8), 16, 0, 0);
      __builtin_amdgcn_global_load_lds((const __attribute__((address_space(1))) void*)gb,
          (__attribute__((address_space(3))) void*)(sB + ci * 8), 16, 0, 0);
    }
  };

  STAGE(0, 0);
  __syncthreads();
  int cur = 0;
  for (int kt = 0; kt < K; kt += 64) {
    if (kt + 64 < K) STAGE(cur ^ 1, kt + 64);
    const u16* sA = smem + cur * 16384;
    const u16* sB = sA + 8192;
    #pragma unroll
    for (int ks = 0; ks < 2; ++ks) {
      bf16x8 af[4], bfr[4];
      #pragma unroll
      for (int m = 0; m < 4; ++m) {
        int row = wr * 64 + m * 16 + (lane & 15);
        int pc = (ks * 4 + (lane >> 4)) ^ (row & 7);
        af[m] = *(const bf16x8*)(sA + row * 64 + pc * 8);
      }
      #pragma unroll
      for (int n = 0; n < 4; ++n) {
        int row = wc * 64 + n * 16 + (lane & 15);
        int pc = (ks * 4 + (lane >> 4)) ^ (row & 7);
        bfr[n] = *(const bf16x8*)(sB + row * 64 + pc * 8);
      }
      #pragma unroll
      for (int m = 0; m < 4; ++m)
        #pragma unroll
        for (int n = 0; n < 4; ++n)
          acc[m][n] = __builtin_amdgcn_mfma_f32_16x16x32_bf16(af[m], bfr[n], acc[m][n], 0, 0, 0);
    }
    __syncthreads();
    cur ^= 1;
  }

  if constexpr (MODE == MODE_BF16 || MODE == MODE_BF16T) {
    #pragma unroll
    for (int m = 0; m < 4; ++m) {
      #pragma unroll
      for (int n = 0; n < 4; ++n) {
        int lcol = wc * 64 + n * 16 + (lane & 15);
        int gcol = n0 + lcol;
        float bv = (gcol < split) ? bias1[gcol] : ((gcol < nb) ? bias2[gcol - split] : 0.0f);
        #pragma unroll
        for (int r = 0; r < 4; ++r) {
          int lrow = wr * 64 + m * 16 + (lane >> 4) * 4 + r;
          smem[lrow * 136 + lcol] = f2b(acc[m][n][r] + bv);
        }
      }
    }
    __syncthreads();
    #pragma unroll
    for (int i = 0; i < 8; ++i) {
      int c = t + 256 * i;                 // 0..2047
      int lrow = c >> 4, col8 = (c & 15) * 8;
      u16x8 vv = *(const u16x8*)(smem + lrow * 136 + col8);
      int gcol = n0 + col8;
      size_t grow = m0 + (size_t)lrow;
      if constexpr (MODE == MODE_BF16T) {
        int gi = (int)grow;
        int bb = gi / LROW, pos = gi - bb * LROW;
        int hh = gcol / 48, dd = gcol - hh * 48;
        *(u16x8*)((u16*)Cout + (((size_t)bb * 16 + hh) * LROW + pos) * 48 + dd) = vv;
      } else {
        *(u16x8*)((u16*)Cout + grow * (size_t)N + gcol) = vv;
      }
    }
  } else {
    #pragma unroll
    for (int m = 0; m < 4; ++m) {
      #pragma unroll
      for (int n = 0; n < 4; ++n) {
        int col = n0 + wc * 64 + n * 16 + (lane & 15);
        float bv = (col < split) ? bias1[col] : ((col < nb) ? bias2[col - split] : 0.0f);
        #pragma unroll
        for (int r = 0; r < 4; ++r) {
          size_t grow = m0 + (size_t)(wr * 64 + m * 16 + (lane >> 4) * 4 + r);
          float v = acc[m][n][r] + bv;
          size_t idx = grow * (size_t)N + col;
          if constexpr (MODE == MODE_F32) {
            ((float*)Cout)[idx] = v;
          } else {
            ((float*)Cout)[idx] = resid[idx] + g1[col] * (b2f(attnb[idx]) + g2[col] * v);
          }
        }
      }
    }
  }
}

// ---------------- deformable sampling: 2-phase descriptor scheme -------------
// value: [b][16 heads][LROW][48] bf16 head-major; offa bf16.
// Phase 2: straight-line batches of 4 points -> 16 named gathers in flight.
#define GATHER4(ga, gb, gc, gd, ii) \
  uint4 ga = *(const uint4*)(vB + ((ii).x + hd)); \
  uint4 gb = *(const uint4*)(vB + ((ii).y + hd)); \
  uint4 gc = *(const uint4*)(vB + ((ii).z + hd)); \
  uint4 gd = *(const uint4*)(vB + ((ii).w + hd));
#define FMA4(ga, gb, gc, gd, ww) \
  fma8p(acc0, ga, (ww).x); fma8p(acc1, gb, (ww).y); \
  fma8p(acc0, gc, (ww).z); fma8p(acc1, gd, (ww).w);

__global__ __launch_bounds__(192, 4) void samp_c_kernel(const u16* __restrict__ value,
    const u16* __restrict__ offa, u16* __restrict__ out) {
  __shared__ uint8_t sdesc[2 * 16 * 528];   // 16896 B
  const int orig = blockIdx.x;
  const int cpx = gridDim.x >> 3;
  const int bq0 = ((orig & 7) * cpx + (orig >> 3)) * 2;
  const int t = threadIdx.x;

  if (t < 128) {
    const int qi = t >> 6, h = (t >> 2) & 15, l = t & 3;
    const int bq = bq0 + qi;
    const int b = bq / 9216, q = bq - b * 9216;
    const u16* rw = offa + (size_t)bq * 768;
    u16x8 A0 = *(const u16x8*)(rw + 512 + h * 16);
    u16x8 A1 = *(const u16x8*)(rw + 512 + h * 16 + 8);
    float lg[16];
    #pragma unroll
    for (int i = 0; i < 8; ++i) { lg[i] = b2f(A0[i]); lg[8 + i] = b2f(A1[i]); }
    float mx = lg[0];
    #pragma unroll
    for (int i = 1; i < 16; ++i) mx = fmaxf(mx, lg[i]);
    float sum = 0.0f;
    #pragma unroll
    for (int i = 0; i < 16; ++i) sum += __expf(lg[i] - mx);
    const float rs = 1.0f / sum;
    float w0 = (l == 0) ? lg[0] : ((l == 1) ? lg[4] : ((l == 2) ? lg[8]  : lg[12]));
    float w1 = (l == 0) ? lg[1] : ((l == 1) ? lg[5] : ((l == 2) ? lg[9]  : lg[13]));
    float w2 = (l == 0) ? lg[2] : ((l == 1) ? lg[6] : ((l == 2) ? lg[10] : lg[14]));
    float w3 = (l == 0) ? lg[3] : ((l == 1) ? lg[7] : ((l == 2) ? lg[11] : lg[15]));

    const int Wd = (l == 3) ? 96 : (16 << l);
    const int STl = (l == 0) ? 0 : ((l == 1) ? 256 : ((l == 2) ? 1280 : 5376));
    const float fW = (float)Wd;
    const float rx = ((q % 96) + 0.5f) * (1.0f / 96.0f);
    const float ry = ((q / 96) + 0.5f) * (1.0f / 96.0f);
    const int headbase = (b * 16 + h) * 14592 + STl;

    u16x8 O = *(const u16x8*)(rw + h * 32 + l * 8);
    float oxs[4] = {b2f(O[0]), b2f(O[2]), b2f(O[4]), b2f(O[6])};
    float oys[4] = {b2f(O[1]), b2f(O[3]), b2f(O[5]), b2f(O[7])};
    float wgs[4] = {w0, w1, w2, w3};
    uint8_t* dpb = sdesc + (qi * 16 + h) * 528 + l * 32;   // slot = pt*4 + l
    #pragma unroll
    for (int pt = 0; pt < 4; ++pt) {
      float px = rx * fW + oxs[pt] - 0.5f;
      float py = ry * fW + oys[pt] - 0.5f;
      float wgt = __expf(wgs[pt] - mx) * rs;
      float x0f = floorf(px), y0f = floorf(py);
      float lx = px - x0f, ly = py - y0f;
      int x0 = (int)x0f, y0 = (int)y0f;
      int xc0 = min(max(x0, 0), Wd - 1), xc1 = min(max(x0 + 1, 0), Wd - 1);
      int yc0 = min(max(y0, 0), Wd - 1), yc1 = min(max(y0 + 1, 0), Wd - 1);
      float wx0 = ((unsigned)x0       < (unsigned)Wd) ? (1.0f - lx) : 0.0f;
      float wx1 = ((unsigned)(x0 + 1) < (unsigned)Wd) ? lx          : 0.0f;
      float wy0 = (((unsigned)y0       < (unsigned)Wd) ? (1.0f - ly) : 0.0f) * wgt;
      float wy1 = (((unsigned)(y0 + 1) < (unsigned)Wd) ? ly          : 0.0f) * wgt;
      int4 ii;
      ii.x = (headbase + yc0 * Wd + xc0) * 96;
      ii.y = (headbase + yc0 * Wd + xc1) * 96;
      ii.z = (headbase + yc1 * Wd + xc0) * 96;
      ii.w = (headbase + yc1 * Wd + xc1) * 96;
      float4 ww = {wx0 * wy0, wx1 * wy0, wx0 * wy1, wx1 * wy1};
      *(int4*)(dpb + pt * 128) = ii;
      *(float4*)(dpb + pt * 128 + 16) = ww;
    }
  }
  __syncthreads();

  const int qi = t / 96, r = t - qi * 96;
  const int h = r / 6, d8 = r - h * 6;
  const int bq = bq0 + qi;
  const int hd = d8 * 16;
  const uint8_t* vB = (const uint8_t*)value;
  const uint8_t* dp = sdesc + (qi * 16 + h) * 528;

  f32x2 acc0[4] = {}, acc1[4] = {};
  #pragma unroll
  for (int pb = 0; pb < 4; ++pb) {
    const uint8_t* dpp = dp + pb * 128;
    int4   i0 = *(const int4*)(dpp);
    float4 w0 = *(const float4*)(dpp + 16);
    int4   i1 = *(const int4*)(dpp + 32);
    float4 w1 = *(const float4*)(dpp + 48);
    int4   i2 = *(const int4*)(dpp + 64);
    float4 w2 = *(const float4*)(dpp + 80);
    int4   i3 = *(const int4*)(dpp + 96);
    float4 w3 = *(const float4*)(dpp + 112);
    GATHER4(g00, g01, g02, g03, i0)
    GATHER4(g10, g11, g12, g13, i1)
    GATHER4(g20, g21, g22, g23, i2)
    GATHER4(g30, g31, g32, g33, i3)
    FMA4(g00, g01, g02, g03, w0)
    FMA4(g10, g11, g12, g13, w1)
    FMA4(g20, g21, g22, g23, w2)
    FMA4(g30, g31, g32, g33, w3)
  }
  u16x8 o;
  #pragma unroll
  for (int j = 0; j < 4; ++j) {
    o[2*j]   = f2b(acc0[j][0] + acc1[j][0]);
    o[2*j+1] = f2b(acc0[j][1] + acc1[j][1]);
  }
  *(u16x8*)(out + (size_t)bq * 768 + h * 48 + d8 * 8) = o;
}

// self-attn sampling: offa (bf16) row = [128 off | 64 logits | 64 pad], stride 256.
__global__ __launch_bounds__(192, 4) void samp_s_kernel(const u16* __restrict__ value,
    const u16* __restrict__ offa, u16* __restrict__ out) {
  __shared__ uint8_t sdesc[2 * 16 * 144];   // 4608 B
  const int orig = blockIdx.x;
  const int cpx = gridDim.x >> 3;
  const int bq0 = ((orig & 7) * cpx + (orig >> 3)) * 2;
  const int t = threadIdx.x;

  if (t < 32) {
    const int qi = t >> 4, h = t & 15;
    const int bq = bq0 + qi;
    const int b = bq / 9216, q = bq - b * 9216;
    const u16* rw = offa + (size_t)bq * 256;
    u16x4 Lv = *(const u16x4*)(rw + 128 + h * 4);
    float lg[4] = {b2f(Lv[0]), b2f(Lv[1]), b2f(Lv[2]), b2f(Lv[3])};
    float mx = fmaxf(fmaxf(lg[0], lg[1]), fmaxf(lg[2], lg[3]));
    float sum = __expf(lg[0] - mx) + __expf(lg[1] - mx) + __expf(lg[2] - mx) + __expf(lg[3] - mx);
    const float rs = 1.0f / sum;
    const float rx = ((q % 96) + 0.5f) * (1.0f / 96.0f);
    const float ry = ((q / 96) + 0.5f) * (1.0f / 96.0f);
    const int headbase = (b * 16 + h) * 9216;
    u16x8 O = *(const u16x8*)(rw + h * 8);
    float oxs[4] = {b2f(O[0]), b2f(O[2]), b2f(O[4]), b2f(O[6])};
    float oys[4] = {b2f(O[1]), b2f(O[3]), b2f(O[5]), b2f(O[7])};
    uint8_t* dpb = sdesc + (qi * 16 + h) * 144;
    #pragma unroll
    for (int pt = 0; pt < 4; ++pt) {
      float px = rx * 96.0f + oxs[pt] - 0.5f;
      float py = ry * 96.0f + oys[pt] - 0.5f;
      float wgt = __expf(lg[pt] - mx) * rs;
      float x0f = floorf(px), y0f = floorf(py);
      float lx = px - x0f, ly = py - y0f;
      int x0 = (int)x0f, y0 = (int)y0f;
      int xc0 = min(max(x0, 0), 95), xc1 = min(max(x0 + 1, 0), 95);
      int yc0 = min(max(y0, 0), 95), yc1 = min(max(y0 + 1, 0), 95);
      float wx0 = ((unsigned)x0       < 96u) ? (1.0f - lx) : 0.0f;
      float wx1 = ((unsigned)(x0 + 1) < 96u) ? lx          : 0.0f;
      float wy0 = (((unsigned)y0       < 96u) ? (1.0f - ly) : 0.0f) * wgt;
      float wy1 = (((unsigned)(y0 + 1) < 96u) ? ly          : 0.0f) * wgt;
      int4 ii;
      ii.x = (headbase + yc0 * 96 + xc0) * 96;
      ii.y = (headbase + yc0 * 96 + xc1) * 96;
      ii.z = (headbase + yc1 * 96 + xc0) * 96;
      ii.w = (headbase + yc1 * 96 + xc1) * 96;
      float4 ww = {wx0 * wy0, wx1 * wy0, wx0 * wy1, wx1 * wy1};
      *(int4*)(dpb + pt * 32) = ii;
      *(float4*)(dpb + pt * 32 + 16) = ww;
    }
  }
  __syncthreads();

  const int qi = t / 96, r = t - qi * 96;
  const int h = r / 6, d8 = r - h * 6;
  const int bq = bq0 + qi;
  const int hd = d8 * 16;
  const uint8_t* vB = (const uint8_t*)value;
  const uint8_t* dp = sdesc + (qi * 16 + h) * 144;

  f32x2 acc0[4] = {}, acc1[4] = {};
  {
    int4   i0 = *(const int4*)(dp);
    float4 w0 = *(const float4*)(dp + 16);
    int4   i1 = *(const int4*)(dp + 32);
    float4 w1 = *(const float4*)(dp + 48);
    int4   i2 = *(const int4*)(dp + 64);
    float4 w2 = *(const float4*)(dp + 80);
    int4   i3 = *(const int4*)(dp + 96);
    float4 w3 = *(const float4*)(dp + 112);
    GATHER4(g00, g01, g02, g03, i0)
    GATHER4(g10, g11, g12, g13, i1)
    GATHER4(g20, g21, g22, g23, i2)
    GATHER4(g30, g31, g32, g33, i3)
    FMA4(g00, g01, g02, g03, w0)
    FMA4(g10, g11, g12, g13, w1)
    FMA4(g20, g21, g22, g23, w2)
    FMA4(g30, g31, g32, g33, w3)
  }
  u16x8 o;
  #pragma unroll
  for (int j = 0; j < 4; ++j) {
    o[2*j]   = f2b(acc0[j][0] + acc1[j][0]);
    o[2*j+1] = f2b(acc0[j][1] + acc1[j][1]);
  }
  *(u16x8*)(out + (size_t)bq * 768 + h * 48 + d8 * 8) = o;
}

// ---------------- launch ----------------
extern "C" void kernel_launch(void* const* d_in, const int* in_sizes, int n_in,
                              void* d_out, int out_size, void* d_ws, size_t ws_size,
                              hipStream_t stream) {
  (void)in_sizes; (void)n_in; (void)out_size; (void)ws_size;
  const float* src0 = (const float*)d_in[0];
  const float* src1 = (const float*)d_in[1];
  const float* src2 = (const float*)d_in[2];
  const float* src3 = (const float*)d_in[3];
  const float* qn_g = (const float*)d_in[4];
  const float* qn_b = (const float*)d_in[5];
  const float* fn_g = (const float*)d_in[6];
  const float* fn_b = (const float*)d_in[7];
  const float* n1_g = (const float*)d_in[8];
  const float* n1_b = (const float*)d_in[9];
  const float* gamma1 = (const float*)d_in[10];
  const float* gamma2 = (const float*)d_in[11];
  const float* c_Wv  = (const float*)d_in[12]; const float* c_bv   = (const float*)d_in[13];
  const float* c_Woff= (const float*)d_in[14]; const float* c_boff = (const float*)d_in[15];
  const float* c_Wa  = (const float*)d_in[16]; const float* c_ba   = (const float*)d_in[17];
  const float* c_Wo  = (const float*)d_in[18]; const float* c_bo   = (const float*)d_in[19];
  const float* s_Wv  = (const float*)d_in[20]; const float* s_bv   = (const float*)d_in[21];
  const float* s_Woff= (const float*)d_in[22]; const float* s_boff = (const float*)d_in[23];
  const float* s_Wa  = (const float*)d_in[24]; const float* s_ba   = (const float*)d_in[25];
  const float* s_Wo  = (const float*)d_in[26]; const float* s_bo   = (const float*)d_in[27];

  constexpr int Lq = 9216;
  constexpr int Mq = 2 * Lq;      // 18432
  constexpr int Mf = 2 * 14592;   // 29184

  constexpr size_t O_qln   = 8u << 20;
  constexpr size_t O_fln   = O_qln   + (size_t)Mq * 768 * 2;
  constexpr size_t O_valc  = O_fln   + (size_t)Mf * 768 * 2;   // bf16, head-major
  constexpr size_t O_offac = O_valc  + (size_t)Mf * 768 * 2;   // bf16 [Mq][768]
  constexpr size_t O_sampc = O_qln;                            // reuse
  constexpr size_t O_attn  = O_fln;                            // reuse, bf16
  constexpr size_t O_attn1 = O_attn  + (size_t)Mq * 768 * 2;   // bf16
  constexpr size_t O_vals  = O_attn1 + (size_t)Mq * 768 * 2;   // bf16, head-major
  constexpr size_t O_offas = O_vals  + (size_t)Mq * 768 * 2;   // bf16 [Mq][256]
  constexpr size_t O_samps = O_offas + (size_t)Mq * 256 * 2;   // bf16

  uint8_t* ws = (uint8_t*)d_ws;
  u16* Wbase = (u16*)ws;
  auto Wrow = [&](int r) { return Wbase + (size_t)r * 768; };
  auto Wp = [&](size_t o) { return (u16*)(ws + o); };

  wconv_kernel<<<3072, 256, 0, stream>>>(c_Wv, c_Woff, c_Wa, c_Wo, s_Wv, s_Woff, s_Wa, s_Wo, Wbase);

  ln_rows_kernel<<<Mq, 192, 0, stream>>>(src3, qn_g, qn_b, Wp(O_qln));
  ln_feat_kernel<<<Mf, 192, 0, stream>>>(src0, src1, src2, src3, fn_g, fn_b, Wp(O_fln));

  // value projection (cross): Mf x 768 -> head-major [b][16][14592][48]
  gemm_kernel<MODE_BF16T, 6, 14592><<<(Mf / 128) * 6, 256, 0, stream>>>(
      Wp(O_fln), Wrow(0), c_bv, nullptr, 768, 768, Wp(O_valc), 768,
      nullptr, nullptr, nullptr, nullptr);
  // offsets + attn logits (cross, merged): Mq x 768 bf16
  gemm_kernel<MODE_BF16, 6><<<(Mq / 128) * 6, 256, 0, stream>>>(
      Wp(O_qln), Wrow(768), c_boff, c_ba, 512, 768, Wp(O_offac), 768,
      nullptr, nullptr, nullptr, nullptr);

  samp_c_kernel<<<Mq / 2, 192, 0, stream>>>(Wp(O_valc), Wp(O_offac), Wp(O_sampc));

  // output proj (cross) -> attn (bf16)
  gemm_kernel<MODE_BF16, 6><<<(Mq / 128) * 6, 256, 0, stream>>>(
      Wp(O_sampc), Wrow(1536), c_bo, nullptr, 768, 768, Wp(O_attn), 768,
      nullptr, nullptr, nullptr, nullptr);

  ln_rows_b16_kernel<<<Mq, 192, 0, stream>>>(Wp(O_attn), n1_g, n1_b, Wp(O_attn1));

  // value projection (self) -> head-major [b][16][9216][48]
  gemm_kernel<MODE_BF16T, 6, 9216><<<(Mq / 128) * 6, 256, 0, stream>>>(
      Wp(O_attn1), Wrow(2304), s_bv, nullptr, 768, 768, Wp(O_vals), 768,
      nullptr, nullptr, nullptr, nullptr);
  // offsets + attn logits (self, merged): Mq x 256 bf16
  gemm_kernel<MODE_BF16, 2><<<(Mq / 128) * 2, 256, 0, stream>>>(
      Wp(O_attn1), Wrow(3072), s_boff, s_ba, 128, 192, Wp(O_offas), 256,
      nullptr, nullptr, nullptr, nullptr);

  samp_s_kernel<<<Mq / 2, 192, 0, stream>>>(Wp(O_vals), Wp(O_offas), Wp(O_samps));

  // final: out = src3 + g1*(attn + g2*(samp_s @ s_Wo + s_bo))
  gemm_kernel<MODE_FINAL, 6><<<(Mq / 128) * 6, 256, 0, stream>>>(
      Wp(O_samps), Wrow(3328), s_bo, nullptr, 768, 768, (float*)d_out, 768,
      Wp(O_attn), src3, gamma1, gamma2);
}

// Round 9
// 341.575 us; speedup vs baseline: 3.9444x; 1.1037x over previous
//
#include <hip/hip_runtime.h>
#include <stdint.h>

typedef unsigned short u16;
typedef __attribute__((ext_vector_type(8))) __bf16 bf16x8;
typedef __attribute__((ext_vector_type(4))) float f32x4;
typedef __attribute__((ext_vector_type(2))) float f32x2;
typedef __attribute__((ext_vector_type(8))) u16 u16x8;
typedef __attribute__((ext_vector_type(4))) u16 u16x4;

#define DEV __device__ __forceinline__

DEV u16 f2b(float f) {
  union { float f; uint32_t u; } v; v.f = f;
  uint32_t u = v.u;
  return (u16)((u + 0x7fffu + ((u >> 16) & 1u)) >> 16);
}
DEV float b2f(u16 h) {
  union { uint32_t u; float f; } v; v.u = ((uint32_t)h) << 16;
  return v.f;
}
DEV float u2f(uint32_t u) {
  union { uint32_t u; float f; } v; v.u = u;
  return v.f;
}
// f32 -> fp8 e4m3 (OCP), single value via pk-convert
DEV uint8_t f2fp8(float f) {
  return (uint8_t)(__builtin_amdgcn_cvt_pk_fp8_f32(f, f, 0, false) & 0xff);
}
// fused fp8x8 gather-convert-FMA (4 cvt + 4 packed fma)
DEV void fma8f8(f32x2* acc, uint2 v, float w) {
  f32x2 wv = {w, w};
  f32x2 x0 = __builtin_amdgcn_cvt_pk_f32_fp8(v.x, false);
  f32x2 x1 = __builtin_amdgcn_cvt_pk_f32_fp8(v.x, true);
  f32x2 x2 = __builtin_amdgcn_cvt_pk_f32_fp8(v.y, false);
  f32x2 x3 = __builtin_amdgcn_cvt_pk_f32_fp8(v.y, true);
  acc[0] += wv * x0;
  acc[1] += wv * x1;
  acc[2] += wv * x2;
  acc[3] += wv * x3;
}

// ---------------- fused weight transpose: 8 regions, tiled 32x32 via LDS ----
__global__ __launch_bounds__(256) void wconv_kernel(
    const float* __restrict__ W0, const float* __restrict__ W1,
    const float* __restrict__ W2, const float* __restrict__ W3,
    const float* __restrict__ W4, const float* __restrict__ W5,
    const float* __restrict__ W6, const float* __restrict__ W7,
    u16* __restrict__ dst) {
  __shared__ float s[32][33];
  int bx = blockIdx.x;            // 0..3071
  int ct = bx / 24;               // column-tile 0..127
  int kt = bx - ct * 24;          // k-tile 0..23
  const float* Wsrc; int N; int rowbase; int c0;
  if (ct < 24)       { Wsrc = W0; N = 768; rowbase = 0;    c0 = ct; }
  else if (ct < 40)  { Wsrc = W1; N = 512; rowbase = 768;  c0 = ct - 24; }
  else if (ct < 48)  { Wsrc = W2; N = 256; rowbase = 1280; c0 = ct - 40; }
  else if (ct < 72)  { Wsrc = W3; N = 768; rowbase = 1536; c0 = ct - 48; }
  else if (ct < 96)  { Wsrc = W4; N = 768; rowbase = 2304; c0 = ct - 72; }
  else if (ct < 100) { Wsrc = W5; N = 128; rowbase = 3072; c0 = ct - 96; }
  else if (ct < 104) { Wsrc = W6; N = 64;  rowbase = 3200; c0 = ct - 100; }
  else               { Wsrc = W7; N = 768; rowbase = 3328; c0 = ct - 104; }
  const int tx = threadIdx.x & 31, ty = threadIdx.x >> 5;
  const int n = c0 * 32 + tx;
  const int k0 = kt * 32;
  #pragma unroll
  for (int j = 0; j < 4; ++j) {
    int k = k0 + ty + j * 8;
    s[ty + j * 8][tx] = (n < N) ? Wsrc[(size_t)k * N + n] : 0.0f;
  }
  __syncthreads();
  #pragma unroll
  for (int j = 0; j < 4; ++j) {
    int nr = c0 * 32 + ty + j * 8;
    dst[(size_t)(rowbase + nr) * 768 + k0 + tx] = f2b(s[tx][ty + j * 8]);
  }
}

// ---------------- layernorm (row of 768), 192 threads, float4 ----------------
DEV void ln_core(float4 v, const float* __restrict__ g, const float* __restrict__ b,
                 u16* __restrict__ o, int t, float* red) {
  float s = v.x + v.y + v.z + v.w;
  float s2 = v.x * v.x + v.y * v.y + v.z * v.z + v.w * v.w;
  #pragma unroll
  for (int m = 1; m < 64; m <<= 1) { s += __shfl_xor(s, m); s2 += __shfl_xor(s2, m); }
  if ((t & 63) == 0) { red[t >> 6] = s; red[3 + (t >> 6)] = s2; }
  __syncthreads();
  float S = red[0] + red[1] + red[2];
  float S2 = red[3] + red[4] + red[5];
  float mean = S * (1.0f / 768.0f);
  float var = S2 * (1.0f / 768.0f) - mean * mean;
  float rstd = rsqrtf(var + 1e-6f);
  float4 gv = ((const float4*)g)[t], bv = ((const float4*)b)[t];
  u16x4 ov;
  ov[0] = f2b((v.x - mean) * rstd * gv.x + bv.x);
  ov[1] = f2b((v.y - mean) * rstd * gv.y + bv.y);
  ov[2] = f2b((v.z - mean) * rstd * gv.z + bv.z);
  ov[3] = f2b((v.w - mean) * rstd * gv.w + bv.w);
  *(u16x4*)(o + t * 4) = ov;
}

__global__ __launch_bounds__(192) void ln_rows_kernel(const float* __restrict__ in,
    const float* __restrict__ g, const float* __restrict__ b, u16* __restrict__ out) {
  __shared__ float red[6];
  size_t row = blockIdx.x;
  int t = threadIdx.x;
  ln_core(((const float4*)(in + row * 768))[t], g, b, out + row * 768, t, red);
}

__global__ __launch_bounds__(192) void ln_rows_b16_kernel(const u16* __restrict__ in,
    const float* __restrict__ g, const float* __restrict__ b, u16* __restrict__ out) {
  __shared__ float red[6];
  size_t row = blockIdx.x;
  int t = threadIdx.x;
  u16x4 r = *(const u16x4*)(in + row * 768 + t * 4);
  float4 v = {b2f(r[0]), b2f(r[1]), b2f(r[2]), b2f(r[3])};
  ln_core(v, g, b, out + row * 768, t, red);
}

__global__ __launch_bounds__(192) void ln_feat_kernel(const float* __restrict__ s0,
    const float* __restrict__ s1, const float* __restrict__ s2, const float* __restrict__ s3,
    const float* __restrict__ g, const float* __restrict__ b, u16* __restrict__ out) {
  __shared__ float red[6];
  int row = blockIdx.x;
  int bb = row / 14592, pos = row - bb * 14592;
  const float* x;
  if (pos < 256)       x = s0 + ((size_t)bb * 256  + pos) * 768;
  else if (pos < 1280) x = s1 + ((size_t)bb * 1024 + (pos - 256)) * 768;
  else if (pos < 5376) x = s2 + ((size_t)bb * 4096 + (pos - 1280)) * 768;
  else                 x = s3 + ((size_t)bb * 9216 + (pos - 5376)) * 768;
  int t = threadIdx.x;
  ln_core(((const float4*)x)[t], g, b, out + (size_t)row * 768, t, red);
}

// ---------------- bf16 MFMA GEMM, 2-phase double-buffered prefetch ----------
// MODE_FP8T writes C transposed as fp8 e4m3 into head-major [b][16][LROW][48].
enum { MODE_F32 = 0, MODE_BF16 = 1, MODE_FINAL = 2, MODE_FP8T = 3 };

template <int MODE, int NT, int LROW = 1>
__global__ __launch_bounds__(256) void gemm_kernel(
    const u16* __restrict__ A, const u16* __restrict__ Wt,
    const float* __restrict__ bias1, const float* __restrict__ bias2,
    int split, int nb, void* __restrict__ Cout, int N,
    const u16* __restrict__ attnb, const float* __restrict__ resid,
    const float* __restrict__ g1, const float* __restrict__ g2) {
  constexpr int K = 768;
  __shared__ u16 smem[4 * 128 * 64];
  const int t = threadIdx.x;
  const int lane = t & 63;
  const int w = t >> 6;
  const int wr = w >> 1, wc = w & 1;
  const int chunk = gridDim.x >> 3;
  const int tile = (blockIdx.x & 7) * chunk + (blockIdx.x >> 3);
  const int tm = tile / NT, tn = tile - tm * NT;
  const size_t m0 = (size_t)tm * 128;
  const int n0 = tn * 128;

  f32x4 acc[4][4] = {};

  auto STAGE = [&](int buf, int kt) {
    u16* sA = smem + buf * 16384;
    u16* sB = sA + 8192;
    #pragma unroll
    for (int i = 0; i < 4; ++i) {
      int ci = i * 256 + t;
      int row = ci >> 3, c8 = ci & 7;
      int kc = c8 ^ (row & 7);
      const u16* ga = A + (m0 + row) * K + kt + kc * 8;
      const u16* gb = Wt + ((size_t)n0 + row) * K + kt + kc * 8;
      __builtin_amdgcn_global_load_lds((const __attribute__((address_space(1))) void*)ga,
          (__attribute__((address_space(3))) void*)(sA + ci * 8), 16, 0, 0);
      __builtin_amdgcn_global_load_lds((const __attribute__((address_space(1))) void*)gb,
          (__attribute__((address_space(3))) void*)(sB + ci * 8), 16, 0, 0);
    }
  };

  STAGE(0, 0);
  __syncthreads();
  int cur = 0;
  for (int kt = 0; kt < K; kt += 64) {
    if (kt + 64 < K) STAGE(cur ^ 1, kt + 64);
    const u16* sA = smem + cur * 16384;
    const u16* sB = sA + 8192;
    #pragma unroll
    for (int ks = 0; ks < 2; ++ks) {
      bf16x8 af[4], bfr[4];
      #pragma unroll
      for (int m = 0; m < 4; ++m) {
        int row = wr * 64 + m * 16 + (lane & 15);
        int pc = (ks * 4 + (lane >> 4)) ^ (row & 7);
        af[m] = *(const bf16x8*)(sA + row * 64 + pc * 8);
      }
      #pragma unroll
      for (int n = 0; n < 4; ++n) {
        int row = wc * 64 + n * 16 + (lane & 15);
        int pc = (ks * 4 + (lane >> 4)) ^ (row & 7);
        bfr[n] = *(const bf16x8*)(sB + row * 64 + pc * 8);
      }
      #pragma unroll
      for (int m = 0; m < 4; ++m)
        #pragma unroll
        for (int n = 0; n < 4; ++n)
          acc[m][n] = __builtin_amdgcn_mfma_f32_16x16x32_bf16(af[m], bfr[n], acc[m][n], 0, 0, 0);
    }
    __syncthreads();
    cur ^= 1;
  }

  if constexpr (MODE == MODE_BF16) {
    #pragma unroll
    for (int m = 0; m < 4; ++m) {
      #pragma unroll
      for (int n = 0; n < 4; ++n) {
        int lcol = wc * 64 + n * 16 + (lane & 15);
        int gcol = n0 + lcol;
        float bv = (gcol < split) ? bias1[gcol] : ((gcol < nb) ? bias2[gcol - split] : 0.0f);
        #pragma unroll
        for (int r = 0; r < 4; ++r) {
          int lrow = wr * 64 + m * 16 + (lane >> 4) * 4 + r;
          smem[lrow * 136 + lcol] = f2b(acc[m][n][r] + bv);
        }
      }
    }
    __syncthreads();
    #pragma unroll
    for (int i = 0; i < 8; ++i) {
      int c = t + 256 * i;                 // 0..2047
      int lrow = c >> 4, col8 = (c & 15) * 8;
      u16x8 vv = *(const u16x8*)(smem + lrow * 136 + col8);
      int gcol = n0 + col8;
      size_t grow = m0 + (size_t)lrow;
      *(u16x8*)((u16*)Cout + grow * (size_t)N + gcol) = vv;
    }
  } else if constexpr (MODE == MODE_FP8T) {
    uint8_t* s8 = (uint8_t*)smem;          // 128 rows x 144B stride
    #pragma unroll
    for (int m = 0; m < 4; ++m) {
      #pragma unroll
      for (int n = 0; n < 4; ++n) {
        int lcol = wc * 64 + n * 16 + (lane & 15);
        int gcol = n0 + lcol;
        float bv = (gcol < split) ? bias1[gcol] : ((gcol < nb) ? bias2[gcol - split] : 0.0f);
        #pragma unroll
        for (int r = 0; r < 4; ++r) {
          int lrow = wr * 64 + m * 16 + (lane >> 4) * 4 + r;
          s8[lrow * 144 + lcol] = f2fp8(acc[m][n][r] + bv);
        }
      }
    }
    __syncthreads();
    #pragma unroll
    for (int i = 0; i < 4; ++i) {
      int c = t + 256 * i;                 // 0..1023
      int lrow = c >> 3, col16 = (c & 7) * 16;
      uint4 vv = *(const uint4*)(s8 + lrow * 144 + col16);
      int gcol = n0 + col16;
      size_t grow = m0 + (size_t)lrow;
      int gi = (int)grow;
      int bb = gi / LROW, pos = gi - bb * LROW;
      int hh = gcol / 48, dd = gcol - hh * 48;   // 16 | 48: never crosses a head
      *(uint4*)((uint8_t*)Cout + (((size_t)bb * 16 + hh) * LROW + pos) * 48 + dd) = vv;
    }
  } else {
    #pragma unroll
    for (int m = 0; m < 4; ++m) {
      #pragma unroll
      for (int n = 0; n < 4; ++n) {
        int col = n0 + wc * 64 + n * 16 + (lane & 15);
        float bv = (col < split) ? bias1[col] : ((col < nb) ? bias2[col - split] : 0.0f);
        #pragma unroll
        for (int r = 0; r < 4; ++r) {
          size_t grow = m0 + (size_t)(wr * 64 + m * 16 + (lane >> 4) * 4 + r);
          float v = acc[m][n][r] + bv;
          size_t idx = grow * (size_t)N + col;
          if constexpr (MODE == MODE_F32) {
            ((float*)Cout)[idx] = v;
          } else {
            ((float*)Cout)[idx] = resid[idx] + g1[col] * (b2f(attnb[idx]) + g2[col] * v);
          }
        }
      }
    }
  }
}

// ---------------- deformable sampling: fp8 values, 2-phase descriptors ------
// value: [b][16 heads][LROW][48] fp8 e4m3 head-major; offa bf16.
// Phase 2 per corner: 8B load + 4 cvt_pk_f32_fp8 + 4 packed FMA.
#define GATHER4F8(ga, gb, gc, gd, ii) \
  uint2 ga = *(const uint2*)(vB + ((ii).x + hd)); \
  uint2 gb = *(const uint2*)(vB + ((ii).y + hd)); \
  uint2 gc = *(const uint2*)(vB + ((ii).z + hd)); \
  uint2 gd = *(const uint2*)(vB + ((ii).w + hd));
#define FMA4F8(ga, gb, gc, gd, ww) \
  fma8f8(acc0, ga, (ww).x); fma8f8(acc1, gb, (ww).y); \
  fma8f8(acc0, gc, (ww).z); fma8f8(acc1, gd, (ww).w);

__global__ __launch_bounds__(192, 4) void samp_c_kernel(const uint8_t* __restrict__ value,
    const u16* __restrict__ offa, u16* __restrict__ out) {
  __shared__ uint8_t sdesc[2 * 16 * 528];   // 16896 B
  const int orig = blockIdx.x;
  const int cpx = gridDim.x >> 3;
  const int bq0 = ((orig & 7) * cpx + (orig >> 3)) * 2;
  const int t = threadIdx.x;

  if (t < 128) {
    const int qi = t >> 6, h = (t >> 2) & 15, l = t & 3;
    const int bq = bq0 + qi;
    const int b = bq / 9216, q = bq - b * 9216;
    const u16* rw = offa + (size_t)bq * 768;
    u16x8 A0 = *(const u16x8*)(rw + 512 + h * 16);
    u16x8 A1 = *(const u16x8*)(rw + 512 + h * 16 + 8);
    float lg[16];
    #pragma unroll
    for (int i = 0; i < 8; ++i) { lg[i] = b2f(A0[i]); lg[8 + i] = b2f(A1[i]); }
    float mx = lg[0];
    #pragma unroll
    for (int i = 1; i < 16; ++i) mx = fmaxf(mx, lg[i]);
    float sum = 0.0f;
    #pragma unroll
    for (int i = 0; i < 16; ++i) sum += __expf(lg[i] - mx);
    const float rs = 1.0f / sum;
    float w0 = (l == 0) ? lg[0] : ((l == 1) ? lg[4] : ((l == 2) ? lg[8]  : lg[12]));
    float w1 = (l == 0) ? lg[1] : ((l == 1) ? lg[5] : ((l == 2) ? lg[9]  : lg[13]));
    float w2 = (l == 0) ? lg[2] : ((l == 1) ? lg[6] : ((l == 2) ? lg[10] : lg[14]));
    float w3 = (l == 0) ? lg[3] : ((l == 1) ? lg[7] : ((l == 2) ? lg[11] : lg[15]));

    const int Wd = (l == 3) ? 96 : (16 << l);
    const int STl = (l == 0) ? 0 : ((l == 1) ? 256 : ((l == 2) ? 1280 : 5376));
    const float fW = (float)Wd;
    const float rx = ((q % 96) + 0.5f) * (1.0f / 96.0f);
    const float ry = ((q / 96) + 0.5f) * (1.0f / 96.0f);
    const int headbase = (b * 16 + h) * 14592 + STl;

    u16x8 O = *(const u16x8*)(rw + h * 32 + l * 8);
    float oxs[4] = {b2f(O[0]), b2f(O[2]), b2f(O[4]), b2f(O[6])};
    float oys[4] = {b2f(O[1]), b2f(O[3]), b2f(O[5]), b2f(O[7])};
    float wgs[4] = {w0, w1, w2, w3};
    uint8_t* dpb = sdesc + (qi * 16 + h) * 528 + l * 32;   // slot = pt*4 + l
    #pragma unroll
    for (int pt = 0; pt < 4; ++pt) {
      float px = rx * fW + oxs[pt] - 0.5f;
      float py = ry * fW + oys[pt] - 0.5f;
      float wgt = __expf(wgs[pt] - mx) * rs;
      float x0f = floorf(px), y0f = floorf(py);
      float lx = px - x0f, ly = py - y0f;
      int x0 = (int)x0f, y0 = (int)y0f;
      int xc0 = min(max(x0, 0), Wd - 1), xc1 = min(max(x0 + 1, 0), Wd - 1);
      int yc0 = min(max(y0, 0), Wd - 1), yc1 = min(max(y0 + 1, 0), Wd - 1);
      float wx0 = ((unsigned)x0       < (unsigned)Wd) ? (1.0f - lx) : 0.0f;
      float wx1 = ((unsigned)(x0 + 1) < (unsigned)Wd) ? lx          : 0.0f;
      float wy0 = (((unsigned)y0       < (unsigned)Wd) ? (1.0f - ly) : 0.0f) * wgt;
      float wy1 = (((unsigned)(y0 + 1) < (unsigned)Wd) ? ly          : 0.0f) * wgt;
      int4 ii;
      ii.x = (headbase + yc0 * Wd + xc0) * 48;
      ii.y = (headbase + yc0 * Wd + xc1) * 48;
      ii.z = (headbase + yc1 * Wd + xc0) * 48;
      ii.w = (headbase + yc1 * Wd + xc1) * 48;
      float4 ww = {wx0 * wy0, wx1 * wy0, wx0 * wy1, wx1 * wy1};
      *(int4*)(dpb + pt * 128) = ii;
      *(float4*)(dpb + pt * 128 + 16) = ww;
    }
  }
  __syncthreads();

  const int qi = t / 96, r = t - qi * 96;
  const int h = r / 6, d8 = r - h * 6;
  const int bq = bq0 + qi;
  const int hd = d8 * 8;
  const uint8_t* vB = value;
  const uint8_t* dp = sdesc + (qi * 16 + h) * 528;

  f32x2 acc0[4] = {}, acc1[4] = {};
  #pragma unroll
  for (int pb = 0; pb < 4; ++pb) {
    const uint8_t* dpp = dp + pb * 128;
    int4   i0 = *(const int4*)(dpp);
    float4 w0 = *(const float4*)(dpp + 16);
    int4   i1 = *(const int4*)(dpp + 32);
    float4 w1 = *(const float4*)(dpp + 48);
    int4   i2 = *(const int4*)(dpp + 64);
    float4 w2 = *(const float4*)(dpp + 80);
    int4   i3 = *(const int4*)(dpp + 96);
    float4 w3 = *(const float4*)(dpp + 112);
    GATHER4F8(g00, g01, g02, g03, i0)
    GATHER4F8(g10, g11, g12, g13, i1)
    GATHER4F8(g20, g21, g22, g23, i2)
    GATHER4F8(g30, g31, g32, g33, i3)
    FMA4F8(g00, g01, g02, g03, w0)
    FMA4F8(g10, g11, g12, g13, w1)
    FMA4F8(g20, g21, g22, g23, w2)
    FMA4F8(g30, g31, g32, g33, w3)
  }
  u16x8 o;
  #pragma unroll
  for (int j = 0; j < 4; ++j) {
    o[2*j]   = f2b(acc0[j][0] + acc1[j][0]);
    o[2*j+1] = f2b(acc0[j][1] + acc1[j][1]);
  }
  *(u16x8*)(out + (size_t)bq * 768 + h * 48 + d8 * 8) = o;
}

// self-attn sampling: offa (bf16) row = [128 off | 64 logits | 64 pad], stride 256.
// value: [b][16][9216][48] fp8.
__global__ __launch_bounds__(192, 4) void samp_s_kernel(const uint8_t* __restrict__ value,
    const u16* __restrict__ offa, u16* __restrict__ out) {
  __shared__ uint8_t sdesc[2 * 16 * 144];   // 4608 B
  const int orig = blockIdx.x;
  const int cpx = gridDim.x >> 3;
  const int bq0 = ((orig & 7) * cpx + (orig >> 3)) * 2;
  const int t = threadIdx.x;

  if (t < 32) {
    const int qi = t >> 4, h = t & 15;
    const int bq = bq0 + qi;
    const int b = bq / 9216, q = bq - b * 9216;
    const u16* rw = offa + (size_t)bq * 256;
    u16x4 Lv = *(const u16x4*)(rw + 128 + h * 4);
    float lg[4] = {b2f(Lv[0]), b2f(Lv[1]), b2f(Lv[2]), b2f(Lv[3])};
    float mx = fmaxf(fmaxf(lg[0], lg[1]), fmaxf(lg[2], lg[3]));
    float sum = __expf(lg[0] - mx) + __expf(lg[1] - mx) + __expf(lg[2] - mx) + __expf(lg[3] - mx);
    const float rs = 1.0f / sum;
    const float rx = ((q % 96) + 0.5f) * (1.0f / 96.0f);
    const float ry = ((q / 96) + 0.5f) * (1.0f / 96.0f);
    const int headbase = (b * 16 + h) * 9216;
    u16x8 O = *(const u16x8*)(rw + h * 8);
    float oxs[4] = {b2f(O[0]), b2f(O[2]), b2f(O[4]), b2f(O[6])};
    float oys[4] = {b2f(O[1]), b2f(O[3]), b2f(O[5]), b2f(O[7])};
    uint8_t* dpb = sdesc + (qi * 16 + h) * 144;
    #pragma unroll
    for (int pt = 0; pt < 4; ++pt) {
      float px = rx * 96.0f + oxs[pt] - 0.5f;
      float py = ry * 96.0f + oys[pt] - 0.5f;
      float wgt = __expf(lg[pt] - mx) * rs;
      float x0f = floorf(px), y0f = floorf(py);
      float lx = px - x0f, ly = py - y0f;
      int x0 = (int)x0f, y0 = (int)y0f;
      int xc0 = min(max(x0, 0), 95), xc1 = min(max(x0 + 1, 0), 95);
      int yc0 = min(max(y0, 0), 95), yc1 = min(max(y0 + 1, 0), 95);
      float wx0 = ((unsigned)x0       < 96u) ? (1.0f - lx) : 0.0f;
      float wx1 = ((unsigned)(x0 + 1) < 96u) ? lx          : 0.0f;
      float wy0 = (((unsigned)y0       < 96u) ? (1.0f - ly) : 0.0f) * wgt;
      float wy1 = (((unsigned)(y0 + 1) < 96u) ? ly          : 0.0f) * wgt;
      int4 ii;
      ii.x = (headbase + yc0 * 96 + xc0) * 48;
      ii.y = (headbase + yc0 * 96 + xc1) * 48;
      ii.z = (headbase + yc1 * 96 + xc0) * 48;
      ii.w = (headbase + yc1 * 96 + xc1) * 48;
      float4 ww = {wx0 * wy0, wx1 * wy0, wx0 * wy1, wx1 * wy1};
      *(int4*)(dpb + pt * 32) = ii;
      *(float4*)(dpb + pt * 32 + 16) = ww;
    }
  }
  __syncthreads();

  const int qi = t / 96, r = t - qi * 96;
  const int h = r / 6, d8 = r - h * 6;
  const int bq = bq0 + qi;
  const int hd = d8 * 8;
  const uint8_t* vB = value;
  const uint8_t* dp = sdesc + (qi * 16 + h) * 144;

  f32x2 acc0[4] = {}, acc1[4] = {};
  {
    int4   i0 = *(const int4*)(dp);
    float4 w0 = *(const float4*)(dp + 16);
    int4   i1 = *(const int4*)(dp + 32);
    float4 w1 = *(const float4*)(dp + 48);
    int4   i2 = *(const int4*)(dp + 64);
    float4 w2 = *(const float4*)(dp + 80);
    int4   i3 = *(const int4*)(dp + 96);
    float4 w3 = *(const float4*)(dp + 112);
    GATHER4F8(g00, g01, g02, g03, i0)
    GATHER4F8(g10, g11, g12, g13, i1)
    GATHER4F8(g20, g21, g22, g23, i2)
    GATHER4F8(g30, g31, g32, g33, i3)
    FMA4F8(g00, g01, g02, g03, w0)
    FMA4F8(g10, g11, g12, g13, w1)
    FMA4F8(g20, g21, g22, g23, w2)
    FMA4F8(g30, g31, g32, g33, w3)
  }
  u16x8 o;
  #pragma unroll
  for (int j = 0; j < 4; ++j) {
    o[2*j]   = f2b(acc0[j][0] + acc1[j][0]);
    o[2*j+1] = f2b(acc0[j][1] + acc1[j][1]);
  }
  *(u16x8*)(out + (size_t)bq * 768 + h * 48 + d8 * 8) = o;
}

// ---------------- launch ----------------
extern "C" void kernel_launch(void* const* d_in, const int* in_sizes, int n_in,
                              void* d_out, int out_size, void* d_ws, size_t ws_size,
                              hipStream_t stream) {
  (void)in_sizes; (void)n_in; (void)out_size; (void)ws_size;
  const float* src0 = (const float*)d_in[0];
  const float* src1 = (const float*)d_in[1];
  const float* src2 = (const float*)d_in[2];
  const float* src3 = (const float*)d_in[3];
  const float* qn_g = (const float*)d_in[4];
  const float* qn_b = (const float*)d_in[5];
  const float* fn_g = (const float*)d_in[6];
  const float* fn_b = (const float*)d_in[7];
  const float* n1_g = (const float*)d_in[8];
  const float* n1_b = (const float*)d_in[9];
  const float* gamma1 = (const float*)d_in[10];
  const float* gamma2 = (const float*)d_in[11];
  const float* c_Wv  = (const float*)d_in[12]; const float* c_bv   = (const float*)d_in[13];
  const float* c_Woff= (const float*)d_in[14]; const float* c_boff = (const float*)d_in[15];
  const float* c_Wa  = (const float*)d_in[16]; const float* c_ba   = (const float*)d_in[17];
  const float* c_Wo  = (const float*)d_in[18]; const float* c_bo   = (const float*)d_in[19];
  const float* s_Wv  = (const float*)d_in[20]; const float* s_bv   = (const float*)d_in[21];
  const float* s_Woff= (const float*)d_in[22]; const float* s_boff = (const float*)d_in[23];
  const float* s_Wa  = (const float*)d_in[24]; const float* s_ba   = (const float*)d_in[25];
  const float* s_Wo  = (const float*)d_in[26]; const float* s_bo   = (const float*)d_in[27];

  constexpr int Lq = 9216;
  constexpr int Mq = 2 * Lq;      // 18432
  constexpr int Mf = 2 * 14592;   // 29184

  constexpr size_t O_qln   = 8u << 20;
  constexpr size_t O_fln   = O_qln   + (size_t)Mq * 768 * 2;
  constexpr size_t O_valc  = O_fln   + (size_t)Mf * 768 * 2;   // fp8, head-major
  constexpr size_t O_offac = O_valc  + (size_t)Mf * 768;       // bf16 [Mq][768]
  constexpr size_t O_sampc = O_qln;                            // reuse
  constexpr size_t O_attn  = O_fln;                            // reuse, bf16
  constexpr size_t O_attn1 = O_attn  + (size_t)Mq * 768 * 2;   // bf16
  constexpr size_t O_vals  = O_attn1 + (size_t)Mq * 768 * 2;   // fp8, head-major
  constexpr size_t O_offas = O_vals  + (size_t)Mq * 768;       // bf16 [Mq][256]
  constexpr size_t O_samps = O_offas + (size_t)Mq * 256 * 2;   // bf16

  uint8_t* ws = (uint8_t*)d_ws;
  u16* Wbase = (u16*)ws;
  auto Wrow = [&](int r) { return Wbase + (size_t)r * 768; };
  auto Wp = [&](size_t o) { return (u16*)(ws + o); };

  wconv_kernel<<<3072, 256, 0, stream>>>(c_Wv, c_Woff, c_Wa, c_Wo, s_Wv, s_Woff, s_Wa, s_Wo, Wbase);

  ln_rows_kernel<<<Mq, 192, 0, stream>>>(src3, qn_g, qn_b, Wp(O_qln));
  ln_feat_kernel<<<Mf, 192, 0, stream>>>(src0, src1, src2, src3, fn_g, fn_b, Wp(O_fln));

  // value projection (cross): Mf x 768 -> head-major fp8 [b][16][14592][48]
  gemm_kernel<MODE_FP8T, 6, 14592><<<(Mf / 128) * 6, 256, 0, stream>>>(
      Wp(O_fln), Wrow(0), c_bv, nullptr, 768, 768, ws + O_valc, 768,
      nullptr, nullptr, nullptr, nullptr);
  // offsets + attn logits (cross, merged): Mq x 768 bf16
  gemm_kernel<MODE_BF16, 6><<<(Mq / 128) * 6, 256, 0, stream>>>(
      Wp(O_qln), Wrow(768), c_boff, c_ba, 512, 768, Wp(O_offac), 768,
      nullptr, nullptr, nullptr, nullptr);

  samp_c_kernel<<<Mq / 2, 192, 0, stream>>>(ws + O_valc, Wp(O_offac), Wp(O_sampc));

  // output proj (cross) -> attn (bf16)
  gemm_kernel<MODE_BF16, 6><<<(Mq / 128) * 6, 256, 0, stream>>>(
      Wp(O_sampc), Wrow(1536), c_bo, nullptr, 768, 768, Wp(O_attn), 768,
      nullptr, nullptr, nullptr, nullptr);

  ln_rows_b16_kernel<<<Mq, 192, 0, stream>>>(Wp(O_attn), n1_g, n1_b, Wp(O_attn1));

  // value projection (self) -> head-major fp8 [b][16][9216][48]
  gemm_kernel<MODE_FP8T, 6, 9216><<<(Mq / 128) * 6, 256, 0, stream>>>(
      Wp(O_attn1), Wrow(2304), s_bv, nullptr, 768, 768, ws + O_vals, 768,
      nullptr, nullptr, nullptr, nullptr);
  // offsets + attn logits (self, merged): Mq x 256 bf16
  gemm_kernel<MODE_BF16, 2><<<(Mq / 128) * 2, 256, 0, stream>>>(
      Wp(O_attn1), Wrow(3072), s_boff, s_ba, 128, 192, Wp(O_offas), 256,
      nullptr, nullptr, nullptr, nullptr);

  samp_s_kernel<<<Mq / 2, 192, 0, stream>>>(ws + O_vals, Wp(O_offas), Wp(O_samps));

  // final: out = src3 + g1*(attn + g2*(samp_s @ s_Wo + s_bo))
  gemm_kernel<MODE_FINAL, 6><<<(Mq / 128) * 6, 256, 0, stream>>>(
      Wp(O_samps), Wrow(3328), s_bo, nullptr, 768, 768, (float*)d_out, 768,
      Wp(O_attn), src3, gamma1, gamma2);
}

// Round 10
// 333.812 us; speedup vs baseline: 4.0362x; 1.0233x over previous
//
#include <hip/hip_runtime.h>
#include <stdint.h>

typedef unsigned short u16;
typedef __attribute__((ext_vector_type(8))) __bf16 bf16x8;
typedef __attribute__((ext_vector_type(4))) float f32x4;
typedef __attribute__((ext_vector_type(2))) float f32x2;
typedef __attribute__((ext_vector_type(8))) u16 u16x8;
typedef __attribute__((ext_vector_type(4))) u16 u16x4;

#define DEV __device__ __forceinline__

DEV u16 f2b(float f) {
  union { float f; uint32_t u; } v; v.f = f;
  uint32_t u = v.u;
  return (u16)((u + 0x7fffu + ((u >> 16) & 1u)) >> 16);
}
DEV float b2f(u16 h) {
  union { uint32_t u; float f; } v; v.u = ((uint32_t)h) << 16;
  return v.f;
}
DEV float u2f(uint32_t u) {
  union { uint32_t u; float f; } v; v.u = u;
  return v.f;
}
// f32 -> fp8 e4m3 (OCP), single value via pk-convert
DEV uint8_t f2fp8(float f) {
  return (uint8_t)(__builtin_amdgcn_cvt_pk_fp8_f32(f, f, 0, false) & 0xff);
}
// fused fp8x16 gather-convert-FMA (8 cvt + 8 packed fma) into an 8x f32x2 bank
DEV void fma16f8(f32x2* acc, uint4 v, float w) {
  f32x2 wv = {w, w};
  const uint32_t* pv = (const uint32_t*)&v;
  #pragma unroll
  for (int j = 0; j < 4; ++j) {
    f32x2 lo = __builtin_amdgcn_cvt_pk_f32_fp8(pv[j], false);
    f32x2 hi = __builtin_amdgcn_cvt_pk_f32_fp8(pv[j], true);
    acc[2 * j]     += wv * lo;
    acc[2 * j + 1] += wv * hi;
  }
}

// ---------------- fused weight transpose: 8 regions, tiled 32x32 via LDS ----
__global__ __launch_bounds__(256) void wconv_kernel(
    const float* __restrict__ W0, const float* __restrict__ W1,
    const float* __restrict__ W2, const float* __restrict__ W3,
    const float* __restrict__ W4, const float* __restrict__ W5,
    const float* __restrict__ W6, const float* __restrict__ W7,
    u16* __restrict__ dst) {
  __shared__ float s[32][33];
  int bx = blockIdx.x;            // 0..3071
  int ct = bx / 24;               // column-tile 0..127
  int kt = bx - ct * 24;          // k-tile 0..23
  const float* Wsrc; int N; int rowbase; int c0;
  if (ct < 24)       { Wsrc = W0; N = 768; rowbase = 0;    c0 = ct; }
  else if (ct < 40)  { Wsrc = W1; N = 512; rowbase = 768;  c0 = ct - 24; }
  else if (ct < 48)  { Wsrc = W2; N = 256; rowbase = 1280; c0 = ct - 40; }
  else if (ct < 72)  { Wsrc = W3; N = 768; rowbase = 1536; c0 = ct - 48; }
  else if (ct < 96)  { Wsrc = W4; N = 768; rowbase = 2304; c0 = ct - 72; }
  else if (ct < 100) { Wsrc = W5; N = 128; rowbase = 3072; c0 = ct - 96; }
  else if (ct < 104) { Wsrc = W6; N = 64;  rowbase = 3200; c0 = ct - 100; }
  else               { Wsrc = W7; N = 768; rowbase = 3328; c0 = ct - 104; }
  const int tx = threadIdx.x & 31, ty = threadIdx.x >> 5;
  const int n = c0 * 32 + tx;
  const int k0 = kt * 32;
  #pragma unroll
  for (int j = 0; j < 4; ++j) {
    int k = k0 + ty + j * 8;
    s[ty + j * 8][tx] = (n < N) ? Wsrc[(size_t)k * N + n] : 0.0f;
  }
  __syncthreads();
  #pragma unroll
  for (int j = 0; j < 4; ++j) {
    int nr = c0 * 32 + ty + j * 8;
    dst[(size_t)(rowbase + nr) * 768 + k0 + tx] = f2b(s[tx][ty + j * 8]);
  }
}

// ---------------- layernorm (row of 768), 192 threads, float4 ----------------
DEV void ln_core(float4 v, const float* __restrict__ g, const float* __restrict__ b,
                 u16* __restrict__ o, int t, float* red) {
  float s = v.x + v.y + v.z + v.w;
  float s2 = v.x * v.x + v.y * v.y + v.z * v.z + v.w * v.w;
  #pragma unroll
  for (int m = 1; m < 64; m <<= 1) { s += __shfl_xor(s, m); s2 += __shfl_xor(s2, m); }
  if ((t & 63) == 0) { red[t >> 6] = s; red[3 + (t >> 6)] = s2; }
  __syncthreads();
  float S = red[0] + red[1] + red[2];
  float S2 = red[3] + red[4] + red[5];
  float mean = S * (1.0f / 768.0f);
  float var = S2 * (1.0f / 768.0f) - mean * mean;
  float rstd = rsqrtf(var + 1e-6f);
  float4 gv = ((const float4*)g)[t], bv = ((const float4*)b)[t];
  u16x4 ov;
  ov[0] = f2b((v.x - mean) * rstd * gv.x + bv.x);
  ov[1] = f2b((v.y - mean) * rstd * gv.y + bv.y);
  ov[2] = f2b((v.z - mean) * rstd * gv.z + bv.z);
  ov[3] = f2b((v.w - mean) * rstd * gv.w + bv.w);
  *(u16x4*)(o + t * 4) = ov;
}

__global__ __launch_bounds__(192) void ln_rows_kernel(const float* __restrict__ in,
    const float* __restrict__ g, const float* __restrict__ b, u16* __restrict__ out) {
  __shared__ float red[6];
  size_t row = blockIdx.x;
  int t = threadIdx.x;
  ln_core(((const float4*)(in + row * 768))[t], g, b, out + row * 768, t, red);
}

__global__ __launch_bounds__(192) void ln_rows_b16_kernel(const u16* __restrict__ in,
    const float* __restrict__ g, const float* __restrict__ b, u16* __restrict__ out) {
  __shared__ float red[6];
  size_t row = blockIdx.x;
  int t = threadIdx.x;
  u16x4 r = *(const u16x4*)(in + row * 768 + t * 4);
  float4 v = {b2f(r[0]), b2f(r[1]), b2f(r[2]), b2f(r[3])};
  ln_core(v, g, b, out + row * 768, t, red);
}

__global__ __launch_bounds__(192) void ln_feat_kernel(const float* __restrict__ s0,
    const float* __restrict__ s1, const float* __restrict__ s2, const float* __restrict__ s3,
    const float* __restrict__ g, const float* __restrict__ b, u16* __restrict__ out) {
  __shared__ float red[6];
  int row = blockIdx.x;
  int bb = row / 14592, pos = row - bb * 14592;
  const float* x;
  if (pos < 256)       x = s0 + ((size_t)bb * 256  + pos) * 768;
  else if (pos < 1280) x = s1 + ((size_t)bb * 1024 + (pos - 256)) * 768;
  else if (pos < 5376) x = s2 + ((size_t)bb * 4096 + (pos - 1280)) * 768;
  else                 x = s3 + ((size_t)bb * 9216 + (pos - 5376)) * 768;
  int t = threadIdx.x;
  ln_core(((const float4*)x)[t], g, b, out + (size_t)row * 768, t, red);
}

// ---------------- bf16 MFMA GEMM, 2-phase double-buffered prefetch ----------
// MODE_FP8T writes C transposed as fp8 e4m3 into head-major [b][16][LROW][48].
enum { MODE_F32 = 0, MODE_BF16 = 1, MODE_FINAL = 2, MODE_FP8T = 3 };

template <int MODE, int NT, int LROW = 1>
__global__ __launch_bounds__(256) void gemm_kernel(
    const u16* __restrict__ A, const u16* __restrict__ Wt,
    const float* __restrict__ bias1, const float* __restrict__ bias2,
    int split, int nb, void* __restrict__ Cout, int N,
    const u16* __restrict__ attnb, const float* __restrict__ resid,
    const float* __restrict__ g1, const float* __restrict__ g2) {
  constexpr int K = 768;
  __shared__ u16 smem[4 * 128 * 64];
  const int t = threadIdx.x;
  const int lane = t & 63;
  const int w = t >> 6;
  const int wr = w >> 1, wc = w & 1;
  const int chunk = gridDim.x >> 3;
  const int tile = (blockIdx.x & 7) * chunk + (blockIdx.x >> 3);
  const int tm = tile / NT, tn = tile - tm * NT;
  const size_t m0 = (size_t)tm * 128;
  const int n0 = tn * 128;

  f32x4 acc[4][4] = {};

  auto STAGE = [&](int buf, int kt) {
    u16* sA = smem + buf * 16384;
    u16* sB = sA + 8192;
    #pragma unroll
    for (int i = 0; i < 4; ++i) {
      int ci = i * 256 + t;
      int row = ci >> 3, c8 = ci & 7;
      int kc = c8 ^ (row & 7);
      const u16* ga = A + (m0 + row) * K + kt + kc * 8;
      const u16* gb = Wt + ((size_t)n0 + row) * K + kt + kc * 8;
      __builtin_amdgcn_global_load_lds((const __attribute__((address_space(1))) void*)ga,
          (__attribute__((address_space(3))) void*)(sA + ci * 8), 16, 0, 0);
      __builtin_amdgcn_global_load_lds((const __attribute__((address_space(1))) void*)gb,
          (__attribute__((address_space(3))) void*)(sB + ci * 8), 16, 0, 0);
    }
  };

  STAGE(0, 0);
  __syncthreads();
  int cur = 0;
  for (int kt = 0; kt < K; kt += 64) {
    if (kt + 64 < K) STAGE(cur ^ 1, kt + 64);
    const u16* sA = smem + cur * 16384;
    const u16* sB = sA + 8192;
    #pragma unroll
    for (int ks = 0; ks < 2; ++ks) {
      bf16x8 af[4], bfr[4];
      #pragma unroll
      for (int m = 0; m < 4; ++m) {
        int row = wr * 64 + m * 16 + (lane & 15);
        int pc = (ks * 4 + (lane >> 4)) ^ (row & 7);
        af[m] = *(const bf16x8*)(sA + row * 64 + pc * 8);
      }
      #pragma unroll
      for (int n = 0; n < 4; ++n) {
        int row = wc * 64 + n * 16 + (lane & 15);
        int pc = (ks * 4 + (lane >> 4)) ^ (row & 7);
        bfr[n] = *(const bf16x8*)(sB + row * 64 + pc * 8);
      }
      #pragma unroll
      for (int m = 0; m < 4; ++m)
        #pragma unroll
        for (int n = 0; n < 4; ++n)
          acc[m][n] = __builtin_amdgcn_mfma_f32_16x16x32_bf16(af[m], bfr[n], acc[m][n], 0, 0, 0);
    }
    __syncthreads();
    cur ^= 1;
  }

  if constexpr (MODE == MODE_BF16) {
    #pragma unroll
    for (int m = 0; m < 4; ++m) {
      #pragma unroll
      for (int n = 0; n < 4; ++n) {
        int lcol = wc * 64 + n * 16 + (lane & 15);
        int gcol = n0 + lcol;
        float bv = (gcol < split) ? bias1[gcol] : ((gcol < nb) ? bias2[gcol - split] : 0.0f);
        #pragma unroll
        for (int r = 0; r < 4; ++r) {
          int lrow = wr * 64 + m * 16 + (lane >> 4) * 4 + r;
          smem[lrow * 136 + lcol] = f2b(acc[m][n][r] + bv);
        }
      }
    }
    __syncthreads();
    #pragma unroll
    for (int i = 0; i < 8; ++i) {
      int c = t + 256 * i;                 // 0..2047
      int lrow = c >> 4, col8 = (c & 15) * 8;
      u16x8 vv = *(const u16x8*)(smem + lrow * 136 + col8);
      int gcol = n0 + col8;
      size_t grow = m0 + (size_t)lrow;
      *(u16x8*)((u16*)Cout + grow * (size_t)N + gcol) = vv;
    }
  } else if constexpr (MODE == MODE_FP8T) {
    uint8_t* s8 = (uint8_t*)smem;          // 128 rows x 144B stride
    #pragma unroll
    for (int m = 0; m < 4; ++m) {
      #pragma unroll
      for (int n = 0; n < 4; ++n) {
        int lcol = wc * 64 + n * 16 + (lane & 15);
        int gcol = n0 + lcol;
        float bv = (gcol < split) ? bias1[gcol] : ((gcol < nb) ? bias2[gcol - split] : 0.0f);
        #pragma unroll
        for (int r = 0; r < 4; ++r) {
          int lrow = wr * 64 + m * 16 + (lane >> 4) * 4 + r;
          s8[lrow * 144 + lcol] = f2fp8(acc[m][n][r] + bv);
        }
      }
    }
    __syncthreads();
    #pragma unroll
    for (int i = 0; i < 4; ++i) {
      int c = t + 256 * i;                 // 0..1023
      int lrow = c >> 3, col16 = (c & 7) * 16;
      uint4 vv = *(const uint4*)(s8 + lrow * 144 + col16);
      int gcol = n0 + col16;
      size_t grow = m0 + (size_t)lrow;
      int gi = (int)grow;
      int bb = gi / LROW, pos = gi - bb * LROW;
      int hh = gcol / 48, dd = gcol - hh * 48;   // 16 | 48: never crosses a head
      *(uint4*)((uint8_t*)Cout + (((size_t)bb * 16 + hh) * LROW + pos) * 48 + dd) = vv;
    }
  } else {
    #pragma unroll
    for (int m = 0; m < 4; ++m) {
      #pragma unroll
      for (int n = 0; n < 4; ++n) {
        int col = n0 + wc * 64 + n * 16 + (lane & 15);
        float bv = (col < split) ? bias1[col] : ((col < nb) ? bias2[col - split] : 0.0f);
        #pragma unroll
        for (int r = 0; r < 4; ++r) {
          size_t grow = m0 + (size_t)(wr * 64 + m * 16 + (lane >> 4) * 4 + r);
          float v = acc[m][n][r] + bv;
          size_t idx = grow * (size_t)N + col;
          if constexpr (MODE == MODE_F32) {
            ((float*)Cout)[idx] = v;
          } else {
            ((float*)Cout)[idx] = resid[idx] + g1[col] * (b2f(attnb[idx]) + g2[col] * v);
          }
        }
      }
    }
  }
}

// ---------------- deformable sampling: fp8 values, d16 threads --------------
// value: [b][16 heads][LROW][48] fp8 e4m3 head-major; offa bf16.
// 4 queries/block, 256 threads. Phase 1 (t<256, thread=(q,h,l)): descriptors.
// Phase 2 (t<192, thread=(q,h,d16)): 16 channels/thread -> per corner one
// 16B load + 8 cvt_pk_f32_fp8 + 8 packed FMA; dual accumulator banks.
__global__ __launch_bounds__(256, 4) void samp_c_kernel(const uint8_t* __restrict__ value,
    const u16* __restrict__ offa, u16* __restrict__ out) {
  __shared__ uint8_t sdesc[4 * 16 * 528];   // 33792 B
  const int orig = blockIdx.x;
  const int cpx = gridDim.x >> 3;
  const int bq0 = ((orig & 7) * cpx + (orig >> 3)) * 4;
  const int t = threadIdx.x;

  {
    const int qi = t >> 6, h = (t >> 2) & 15, l = t & 3;
    const int bq = bq0 + qi;
    const int b = bq / 9216, q = bq - b * 9216;
    const u16* rw = offa + (size_t)bq * 768;
    u16x8 A0 = *(const u16x8*)(rw + 512 + h * 16);
    u16x8 A1 = *(const u16x8*)(rw + 512 + h * 16 + 8);
    float lg[16];
    #pragma unroll
    for (int i = 0; i < 8; ++i) { lg[i] = b2f(A0[i]); lg[8 + i] = b2f(A1[i]); }
    float mx = lg[0];
    #pragma unroll
    for (int i = 1; i < 16; ++i) mx = fmaxf(mx, lg[i]);
    float sum = 0.0f;
    #pragma unroll
    for (int i = 0; i < 16; ++i) sum += __expf(lg[i] - mx);
    const float rs = 1.0f / sum;
    float w0 = (l == 0) ? lg[0] : ((l == 1) ? lg[4] : ((l == 2) ? lg[8]  : lg[12]));
    float w1 = (l == 0) ? lg[1] : ((l == 1) ? lg[5] : ((l == 2) ? lg[9]  : lg[13]));
    float w2 = (l == 0) ? lg[2] : ((l == 1) ? lg[6] : ((l == 2) ? lg[10] : lg[14]));
    float w3 = (l == 0) ? lg[3] : ((l == 1) ? lg[7] : ((l == 2) ? lg[11] : lg[15]));

    const int Wd = (l == 3) ? 96 : (16 << l);
    const int STl = (l == 0) ? 0 : ((l == 1) ? 256 : ((l == 2) ? 1280 : 5376));
    const float fW = (float)Wd;
    const float rx = ((q % 96) + 0.5f) * (1.0f / 96.0f);
    const float ry = ((q / 96) + 0.5f) * (1.0f / 96.0f);
    const int headbase = (b * 16 + h) * 14592 + STl;

    u16x8 O = *(const u16x8*)(rw + h * 32 + l * 8);
    float oxs[4] = {b2f(O[0]), b2f(O[2]), b2f(O[4]), b2f(O[6])};
    float oys[4] = {b2f(O[1]), b2f(O[3]), b2f(O[5]), b2f(O[7])};
    float wgs[4] = {w0, w1, w2, w3};
    uint8_t* dpb = sdesc + (qi * 16 + h) * 528 + l * 32;   // slot = pt*4 + l
    #pragma unroll
    for (int pt = 0; pt < 4; ++pt) {
      float px = rx * fW + oxs[pt] - 0.5f;
      float py = ry * fW + oys[pt] - 0.5f;
      float wgt = __expf(wgs[pt] - mx) * rs;
      float x0f = floorf(px), y0f = floorf(py);
      float lx = px - x0f, ly = py - y0f;
      int x0 = (int)x0f, y0 = (int)y0f;
      int xc0 = min(max(x0, 0), Wd - 1), xc1 = min(max(x0 + 1, 0), Wd - 1);
      int yc0 = min(max(y0, 0), Wd - 1), yc1 = min(max(y0 + 1, 0), Wd - 1);
      float wx0 = ((unsigned)x0       < (unsigned)Wd) ? (1.0f - lx) : 0.0f;
      float wx1 = ((unsigned)(x0 + 1) < (unsigned)Wd) ? lx          : 0.0f;
      float wy0 = (((unsigned)y0       < (unsigned)Wd) ? (1.0f - ly) : 0.0f) * wgt;
      float wy1 = (((unsigned)(y0 + 1) < (unsigned)Wd) ? ly          : 0.0f) * wgt;
      int4 ii;
      ii.x = (headbase + yc0 * Wd + xc0) * 48;
      ii.y = (headbase + yc0 * Wd + xc1) * 48;
      ii.z = (headbase + yc1 * Wd + xc0) * 48;
      ii.w = (headbase + yc1 * Wd + xc1) * 48;
      float4 ww = {wx0 * wy0, wx1 * wy0, wx0 * wy1, wx1 * wy1};
      *(int4*)(dpb + pt * 128) = ii;
      *(float4*)(dpb + pt * 128 + 16) = ww;
    }
  }
  __syncthreads();
  if (t >= 192) return;

  const int qi = t / 48, r = t - qi * 48;
  const int h = r / 3, d16 = r - h * 3;
  const int bq = bq0 + qi;
  const int hd = d16 * 16;
  const uint8_t* vB = value;
  const uint8_t* dp = sdesc + (qi * 16 + h) * 528;

  f32x2 acc0[8] = {}, acc1[8] = {};
  #pragma unroll
  for (int p = 0; p < 16; ++p) {
    const uint8_t* dpp = dp + p * 32;
    int4   ii = *(const int4*)(dpp);
    float4 ww = *(const float4*)(dpp + 16);
    uint4 g0 = *(const uint4*)(vB + (ii.x + hd));
    uint4 g1 = *(const uint4*)(vB + (ii.y + hd));
    uint4 g2 = *(const uint4*)(vB + (ii.z + hd));
    uint4 g3 = *(const uint4*)(vB + (ii.w + hd));
    fma16f8(acc0, g0, ww.x);
    fma16f8(acc1, g1, ww.y);
    fma16f8(acc0, g2, ww.z);
    fma16f8(acc1, g3, ww.w);
  }
  u16x8 o0, o1;
  #pragma unroll
  for (int j = 0; j < 4; ++j) {
    o0[2*j]   = f2b(acc0[j][0] + acc1[j][0]);
    o0[2*j+1] = f2b(acc0[j][1] + acc1[j][1]);
    o1[2*j]   = f2b(acc0[4+j][0] + acc1[4+j][0]);
    o1[2*j+1] = f2b(acc0[4+j][1] + acc1[4+j][1]);
  }
  u16* op = out + (size_t)bq * 768 + h * 48 + d16 * 16;
  *(u16x8*)op = o0;
  *(u16x8*)(op + 8) = o1;
}

// self-attn sampling: offa (bf16) row = [128 off | 64 logits | 64 pad], stride 256.
// value: [b][16][9216][48] fp8. 4 queries/block, 256 threads, d16 phase 2.
__global__ __launch_bounds__(256, 4) void samp_s_kernel(const uint8_t* __restrict__ value,
    const u16* __restrict__ offa, u16* __restrict__ out) {
  __shared__ uint8_t sdesc[4 * 16 * 144];   // 9216 B
  const int orig = blockIdx.x;
  const int cpx = gridDim.x >> 3;
  const int bq0 = ((orig & 7) * cpx + (orig >> 3)) * 4;
  const int t = threadIdx.x;

  if (t < 64) {
    const int qi = t >> 4, h = t & 15;
    const int bq = bq0 + qi;
    const int b = bq / 9216, q = bq - b * 9216;
    const u16* rw = offa + (size_t)bq * 256;
    u16x4 Lv = *(const u16x4*)(rw + 128 + h * 4);
    float lg[4] = {b2f(Lv[0]), b2f(Lv[1]), b2f(Lv[2]), b2f(Lv[3])};
    float mx = fmaxf(fmaxf(lg[0], lg[1]), fmaxf(lg[2], lg[3]));
    float sum = __expf(lg[0] - mx) + __expf(lg[1] - mx) + __expf(lg[2] - mx) + __expf(lg[3] - mx);
    const float rs = 1.0f / sum;
    const float rx = ((q % 96) + 0.5f) * (1.0f / 96.0f);
    const float ry = ((q / 96) + 0.5f) * (1.0f / 96.0f);
    const int headbase = (b * 16 + h) * 9216;
    u16x8 O = *(const u16x8*)(rw + h * 8);
    float oxs[4] = {b2f(O[0]), b2f(O[2]), b2f(O[4]), b2f(O[6])};
    float oys[4] = {b2f(O[1]), b2f(O[3]), b2f(O[5]), b2f(O[7])};
    uint8_t* dpb = sdesc + (qi * 16 + h) * 144;
    #pragma unroll
    for (int pt = 0; pt < 4; ++pt) {
      float px = rx * 96.0f + oxs[pt] - 0.5f;
      float py = ry * 96.0f + oys[pt] - 0.5f;
      float wgt = __expf(lg[pt] - mx) * rs;
      float x0f = floorf(px), y0f = floorf(py);
      float lx = px - x0f, ly = py - y0f;
      int x0 = (int)x0f, y0 = (int)y0f;
      int xc0 = min(max(x0, 0), 95), xc1 = min(max(x0 + 1, 0), 95);
      int yc0 = min(max(y0, 0), 95), yc1 = min(max(y0 + 1, 0), 95);
      float wx0 = ((unsigned)x0       < 96u) ? (1.0f - lx) : 0.0f;
      float wx1 = ((unsigned)(x0 + 1) < 96u) ? lx          : 0.0f;
      float wy0 = (((unsigned)y0       < 96u) ? (1.0f - ly) : 0.0f) * wgt;
      float wy1 = (((unsigned)(y0 + 1) < 96u) ? ly          : 0.0f) * wgt;
      int4 ii;
      ii.x = (headbase + yc0 * 96 + xc0) * 48;
      ii.y = (headbase + yc0 * 96 + xc1) * 48;
      ii.z = (headbase + yc1 * 96 + xc0) * 48;
      ii.w = (headbase + yc1 * 96 + xc1) * 48;
      float4 ww = {wx0 * wy0, wx1 * wy0, wx0 * wy1, wx1 * wy1};
      *(int4*)(dpb + pt * 32) = ii;
      *(float4*)(dpb + pt * 32 + 16) = ww;
    }
  }
  __syncthreads();
  if (t >= 192) return;

  const int qi = t / 48, r = t - qi * 48;
  const int h = r / 3, d16 = r - h * 3;
  const int bq = bq0 + qi;
  const int hd = d16 * 16;
  const uint8_t* vB = value;
  const uint8_t* dp = sdesc + (qi * 16 + h) * 144;

  f32x2 acc0[8] = {}, acc1[8] = {};
  #pragma unroll
  for (int p = 0; p < 4; ++p) {
    const uint8_t* dpp = dp + p * 32;
    int4   ii = *(const int4*)(dpp);
    float4 ww = *(const float4*)(dpp + 16);
    uint4 g0 = *(const uint4*)(vB + (ii.x + hd));
    uint4 g1 = *(const uint4*)(vB + (ii.y + hd));
    uint4 g2 = *(const uint4*)(vB + (ii.z + hd));
    uint4 g3 = *(const uint4*)(vB + (ii.w + hd));
    fma16f8(acc0, g0, ww.x);
    fma16f8(acc1, g1, ww.y);
    fma16f8(acc0, g2, ww.z);
    fma16f8(acc1, g3, ww.w);
  }
  u16x8 o0, o1;
  #pragma unroll
  for (int j = 0; j < 4; ++j) {
    o0[2*j]   = f2b(acc0[j][0] + acc1[j][0]);
    o0[2*j+1] = f2b(acc0[j][1] + acc1[j][1]);
    o1[2*j]   = f2b(acc0[4+j][0] + acc1[4+j][0]);
    o1[2*j+1] = f2b(acc0[4+j][1] + acc1[4+j][1]);
  }
  u16* op = out + (size_t)bq * 768 + h * 48 + d16 * 16;
  *(u16x8*)op = o0;
  *(u16x8*)(op + 8) = o1;
}

// ---------------- launch ----------------
extern "C" void kernel_launch(void* const* d_in, const int* in_sizes, int n_in,
                              void* d_out, int out_size, void* d_ws, size_t ws_size,
                              hipStream_t stream) {
  (void)in_sizes; (void)n_in; (void)out_size; (void)ws_size;
  const float* src0 = (const float*)d_in[0];
  const float* src1 = (const float*)d_in[1];
  const float* src2 = (const float*)d_in[2];
  const float* src3 = (const float*)d_in[3];
  const float* qn_g = (const float*)d_in[4];
  const float* qn_b = (const float*)d_in[5];
  const float* fn_g = (const float*)d_in[6];
  const float* fn_b = (const float*)d_in[7];
  const float* n1_g = (const float*)d_in[8];
  const float* n1_b = (const float*)d_in[9];
  const float* gamma1 = (const float*)d_in[10];
  const float* gamma2 = (const float*)d_in[11];
  const float* c_Wv  = (const float*)d_in[12]; const float* c_bv   = (const float*)d_in[13];
  const float* c_Woff= (const float*)d_in[14]; const float* c_boff = (const float*)d_in[15];
  const float* c_Wa  = (const float*)d_in[16]; const float* c_ba   = (const float*)d_in[17];
  const float* c_Wo  = (const float*)d_in[18]; const float* c_bo   = (const float*)d_in[19];
  const float* s_Wv  = (const float*)d_in[20]; const float* s_bv   = (const float*)d_in[21];
  const float* s_Woff= (const float*)d_in[22]; const float* s_boff = (const float*)d_in[23];
  const float* s_Wa  = (const float*)d_in[24]; const float* s_ba   = (const float*)d_in[25];
  const float* s_Wo  = (const float*)d_in[26]; const float* s_bo   = (const float*)d_in[27];

  constexpr int Lq = 9216;
  constexpr int Mq = 2 * Lq;      // 18432
  constexpr int Mf = 2 * 14592;   // 29184

  constexpr size_t O_qln   = 8u << 20;
  constexpr size_t O_fln   = O_qln   + (size_t)Mq * 768 * 2;
  constexpr size_t O_valc  = O_fln   + (size_t)Mf * 768 * 2;   // fp8, head-major
  constexpr size_t O_offac = O_valc  + (size_t)Mf * 768;       // bf16 [Mq][768]
  constexpr size_t O_sampc = O_qln;                            // reuse
  constexpr size_t O_attn  = O_fln;                            // reuse, bf16
  constexpr size_t O_attn1 = O_attn  + (size_t)Mq * 768 * 2;   // bf16
  constexpr size_t O_vals  = O_attn1 + (size_t)Mq * 768 * 2;   // fp8, head-major
  constexpr size_t O_offas = O_vals  + (size_t)Mq * 768;       // bf16 [Mq][256]
  constexpr size_t O_samps = O_offas + (size_t)Mq * 256 * 2;   // bf16

  uint8_t* ws = (uint8_t*)d_ws;
  u16* Wbase = (u16*)ws;
  auto Wrow = [&](int r) { return Wbase + (size_t)r * 768; };
  auto Wp = [&](size_t o) { return (u16*)(ws + o); };

  wconv_kernel<<<3072, 256, 0, stream>>>(c_Wv, c_Woff, c_Wa, c_Wo, s_Wv, s_Woff, s_Wa, s_Wo, Wbase);

  ln_rows_kernel<<<Mq, 192, 0, stream>>>(src3, qn_g, qn_b, Wp(O_qln));
  ln_feat_kernel<<<Mf, 192, 0, stream>>>(src0, src1, src2, src3, fn_g, fn_b, Wp(O_fln));

  // value projection (cross): Mf x 768 -> head-major fp8 [b][16][14592][48]
  gemm_kernel<MODE_FP8T, 6, 14592><<<(Mf / 128) * 6, 256, 0, stream>>>(
      Wp(O_fln), Wrow(0), c_bv, nullptr, 768, 768, ws + O_valc, 768,
      nullptr, nullptr, nullptr, nullptr);
  // offsets + attn logits (cross, merged): Mq x 768 bf16
  gemm_kernel<MODE_BF16, 6><<<(Mq / 128) * 6, 256, 0, stream>>>(
      Wp(O_qln), Wrow(768), c_boff, c_ba, 512, 768, Wp(O_offac), 768,
      nullptr, nullptr, nullptr, nullptr);

  samp_c_kernel<<<Mq / 4, 256, 0, stream>>>(ws + O_valc, Wp(O_offac), Wp(O_sampc));

  // output proj (cross) -> attn (bf16)
  gemm_kernel<MODE_BF16, 6><<<(Mq / 128) * 6, 256, 0, stream>>>(
      Wp(O_sampc), Wrow(1536), c_bo, nullptr, 768, 768, Wp(O_attn), 768,
      nullptr, nullptr, nullptr, nullptr);

  ln_rows_b16_kernel<<<Mq, 192, 0, stream>>>(Wp(O_attn), n1_g, n1_b, Wp(O_attn1));

  // value projection (self) -> head-major fp8 [b][16][9216][48]
  gemm_kernel<MODE_FP8T, 6, 9216><<<(Mq / 128) * 6, 256, 0, stream>>>(
      Wp(O_attn1), Wrow(2304), s_bv, nullptr, 768, 768, ws + O_vals, 768,
      nullptr, nullptr, nullptr, nullptr);
  // offsets + attn logits (self, merged): Mq x 256 bf16
  gemm_kernel<MODE_BF16, 2><<<(Mq / 128) * 2, 256, 0, stream>>>(
      Wp(O_attn1), Wrow(3072), s_boff, s_ba, 128, 192, Wp(O_offas), 256,
      nullptr, nullptr, nullptr, nullptr);

  samp_s_kernel<<<Mq / 4, 256, 0, stream>>>(ws + O_vals, Wp(O_offas), Wp(O_samps));

  // final: out = src3 + g1*(attn + g2*(samp_s @ s_Wo + s_bo))
  gemm_kernel<MODE_FINAL, 6><<<(Mq / 128) * 6, 256, 0, stream>>>(
      Wp(O_samps), Wrow(3328), s_bo, nullptr, 768, 768, (float*)d_out, 768,
      Wp(O_attn), src3, gamma1, gamma2);
}